// Round 15
// baseline (2890.366 us; speedup 1.0000x reference)
//
#include <hip/hip_runtime.h>
#include <hip/hip_bf16.h>

constexpr int B_ = 2, N_ = 4096, M_ = 4096, C_ = 128;

// ---------------- KNN: 16-NN replicating XLA f32 arithmetic -----------------
// d = (s1 - 2*e) + s2 ; e via llvm.fmuladd chain (XLA dot emitter, k-ascending)
// s1,s2 via plain mul/add (XLA elementwise+reduce). Tie -> lower index.
__global__ __launch_bounds__(256) void knn_kernel(const float* __restrict__ pos1,
                                                  const float* __restrict__ pos2,
                                                  int* __restrict__ idx) {
  __shared__ float tX[512], tY[512], tZ[512], tS[512];
  __shared__ float bdL[16 * 256];
  __shared__ int biL[16 * 256];
  int tid = threadIdx.x;
  int bn = blockIdx.x * 256 + tid;
  int b = bn >> 12, n = bn & 4095;
  const float* p1 = pos1 + (long)b * 3 * N_;
  float qx = p1[n], qy = p1[N_ + n], qz = p1[2 * N_ + n];
  float s1 = __fadd_rn(__fadd_rn(__fmul_rn(qx, qx), __fmul_rn(qy, qy)), __fmul_rn(qz, qz));
  for (int k = 0; k < 16; k++) { bdL[k * 256 + tid] = 3.0e38f; biL[k * 256 + tid] = 0; }
  float thr = 3.0e38f;
  const float* p2 = pos2 + (long)b * 3 * M_;
  for (int m0 = 0; m0 < M_; m0 += 512) {
    __syncthreads();
    for (int mm = tid; mm < 512; mm += 256) {
      float x = p2[m0 + mm];
      float y = p2[M_ + m0 + mm];
      float z = p2[2 * M_ + m0 + mm];
      tX[mm] = x; tY[mm] = y; tZ[mm] = z;
      tS[mm] = __fadd_rn(__fadd_rn(__fmul_rn(x, x), __fmul_rn(y, y)), __fmul_rn(z, z));
    }
    __syncthreads();
    for (int mm = 0; mm < 512; mm++) {
      float e = __fmaf_rn(qz, tZ[mm], __fmaf_rn(qy, tY[mm], __fmul_rn(qx, tX[mm])));
      float d = __fadd_rn(__fsub_rn(s1, __fadd_rn(e, e)), tS[mm]);
      if (d < thr) {
        int j = 15;
        while (j > 0 && bdL[(j - 1) * 256 + tid] > d) {
          bdL[j * 256 + tid] = bdL[(j - 1) * 256 + tid];
          biL[j * 256 + tid] = biL[(j - 1) * 256 + tid];
          j--;
        }
        bdL[j * 256 + tid] = d;
        biL[j * 256 + tid] = m0 + mm;
        thr = bdL[15 * 256 + tid];
      }
    }
  }
  for (int k = 0; k < 16; k++) idx[(long)bn * 16 + k] = biL[k * 256 + tid];
}

// ------------- layer0 decomposition: 131-wide GEMM over points --------------
__global__ __launch_bounds__(128) void g131_kernel(const float* __restrict__ pos,
                                                   const float* __restrict__ feat,
                                                   const float* __restrict__ w0,
                                                   float* __restrict__ out,
                                                   float sign, int woff) {
  __shared__ float Xs[131 * 16];
  int tid = threadIdx.x;
  long b = blockIdx.x >> 8;
  int i0 = (blockIdx.x & 255) * 16;
  for (int e = tid; e < 131 * 16; e += 128) {
    int r = e & 15, c = e >> 4;
    float v = (c < 3) ? sign * pos[b * 3 * N_ + (long)c * N_ + i0 + r]
                      : feat[b * C_ * N_ + (long)(c - 3) * N_ + i0 + r];
    Xs[c * 16 + r] = v;
  }
  __syncthreads();
  int o = tid;
  float acc[16];
#pragma unroll
  for (int r = 0; r < 16; r++) acc[r] = 0.f;
  for (int c = 0; c < 131; c++) {
    float wv = w0[(long)o * 259 + (c < 3 ? c : (woff + c - 3))];
    const float* xr = &Xs[c * 16];
#pragma unroll
    for (int r = 0; r < 16; r++) acc[r] = fmaf(xr[r], wv, acc[r]);
  }
#pragma unroll
  for (int r = 0; r < 16; r++) out[((b << 12) + i0 + r) * 128 + o] = acc[r];
}

// ------------- BN0 stats from (idx, A1, A2), no z0 store --------------------
__global__ __launch_bounds__(256) void z0stats_kernel(const int* __restrict__ idx,
                                                      const float* __restrict__ A1,
                                                      const float* __restrict__ A2,
                                                      double* __restrict__ st) {
  int tid = threadIdx.x;
  int o = tid & 127, half = tid >> 7;
  float sum = 0.f, sq = 0.f;
  int g0 = blockIdx.x * 32;
  for (int gi = 0; gi < 32; gi++) {
    int bn = g0 + gi;
    long b = bn >> 12;
    float a1 = A1[(long)bn * 128 + o];
    for (int k = half; k < 16; k += 2) {
      int m = idx[bn * 16 + k];
      float v = A2[(b * 4096 + m) * 128 + o] + a1;
      sum += v;
      sq += v * v;
    }
  }
  __shared__ float ls[256], lq[256];
  ls[tid] = sum; lq[tid] = sq;
  __syncthreads();
  if (tid < 128) {
    atomicAdd(&st[o], (double)(ls[tid] + ls[tid + 128]));
    atomicAdd(&st[128 + o], (double)(lq[tid] + lq[tid + 128]));
  }
}

// ------------- per-channel stats over bf16 (nrows x 128) --------------------
__global__ __launch_bounds__(256) void statsb_kernel(const __hip_bfloat16* __restrict__ Z,
                                                     long nrows, double* __restrict__ st) {
  int tid = threadIdx.x;
  int c = tid & 127, sub = tid >> 7;
  long slot = (long)blockIdx.x * 2 + sub;
  long stride = (long)gridDim.x * 2;
  float sum = 0.f, sq = 0.f;
  for (long r = slot; r < nrows; r += stride) {
    float v = __bfloat162float(Z[r * 128 + c]);
    sum += v;
    sq += v * v;
  }
  __shared__ float ls[256], lq[256];
  ls[tid] = sum; lq[tid] = sq;
  __syncthreads();
  if (tid < 128) {
    atomicAdd(&st[c], (double)(ls[tid] + ls[tid + 128]));
    atomicAdd(&st[128 + c], (double)(lq[tid] + lq[tid + 128]));
  }
}

// ------------- BN finalize: fold mean/var/g/b into scale+shift --------------
__global__ void bnfin_kernel(const double* __restrict__ st, const float* __restrict__ g,
                             const float* __restrict__ bb, float* __restrict__ sc,
                             float* __restrict__ sh, int CO, double inv) {
  int c = threadIdx.x;
  if (c < CO) {
    double mu = st[c] * inv;
    double var = st[CO + c] * inv - mu * mu;
    double rstd = 1.0 / sqrt(var + 1e-5);
    double scv = (double)g[c] * rstd;
    sc[c] = (float)scv;
    sh[c] = (float)((double)bb[c] - mu * scv);
  }
}

// ------------- tiled GEMM: out = act(X) * W^T (+epilogues), f32 accum -------
// XM: 0 = f32 row-major, 1 = f32 (B,K,4096) channel-first, 2 = bf16 row-major,
//     3 = gather: X=A2 base, row g -> A2[(g>>16)*4096+idx[g]] + A1[g>>4]
// EPI: 1 = +bias, scatter f32 to (b,h,n,64) attn layout
//      2 = +bias +res(f32) -> f32
//      3 = +bias -> f32 TRANSPOSED (B,CO,4096)   [final output]
//      4 = channel stats of raw acc -> f64 atomics, no store
//      5 = BN2(bias=sc2,res=sh2)+ReLU then max/mean pool over k=16 -> feat
//      6 = bf16 row-major store (z1)
template <int EPI, int XM, bool BN>
__global__ __launch_bounds__(256) void gemm_kernel(
    const void* __restrict__ Xv, const float* __restrict__ W, float* __restrict__ out,
    int K, int CO, const float* __restrict__ bias, const float* __restrict__ sc,
    const float* __restrict__ sh, const float* __restrict__ res,
    __hip_bfloat16* __restrict__ obf, const float* __restrict__ A1,
    const int* __restrict__ idxp, double* __restrict__ st) {
  __shared__ float S[2][32 * 68];
  int tid = threadIdx.x;
  int tx = tid & 15, ty = tid >> 4;
  int cb = blockIdx.x;
  long r0 = (long)blockIdx.y * 64;
  int c0 = cb * 64;
  float acc[4][4];
#pragma unroll
  for (int i = 0; i < 4; i++)
#pragma unroll
    for (int j = 0; j < 4; j++) acc[i][j] = 0.f;

  for (int k0 = 0; k0 < K; k0 += 32) {
    if (XM != 1) {
      int c = tid & 31, rr = tid >> 5;
      float scv = 0.f, shv = 0.f;
      if (BN) { scv = sc[k0 + c]; shv = sh[k0 + c]; }
#pragma unroll
      for (int i = 0; i < 8; i++) {
        int r = rr + i * 8;
        long g = r0 + r;
        float v;
        if (XM == 0) {
          v = ((const float*)Xv)[g * K + k0 + c];
        } else if (XM == 2) {
          v = __bfloat162float(((const __hip_bfloat16*)Xv)[g * K + k0 + c]);
        } else {
          const float* A2 = (const float*)Xv;
          int m = idxp[g];
          v = A2[(((g >> 16) << 12) + m) * 128 + k0 + c] + A1[(g >> 4) * 128 + k0 + c];
        }
        if (BN) v = fmaxf(0.f, fmaf(v, scv, shv));
        S[0][c * 68 + r] = v;
      }
    } else {
      int m = tid & 63, cc = tid >> 6;
      long b = r0 >> 12;
      long mg = (r0 & 4095) + m;
#pragma unroll
      for (int i = 0; i < 8; i++) {
        int c = cc + i * 4;
        S[0][c * 68 + m] = ((const float*)Xv)[(b * K + k0 + c) * 4096 + mg];
      }
    }
    {
      int c = tid & 31, oo = tid >> 5;
#pragma unroll
      for (int i = 0; i < 8; i++) {
        int o = oo + i * 8;
        S[1][c * 68 + o] = W[(long)(c0 + o) * K + k0 + c];
      }
    }
    __syncthreads();
#pragma unroll
    for (int kk = 0; kk < 32; kk++) {
      float4 a = *reinterpret_cast<const float4*>(&S[0][kk * 68 + ty * 4]);
      float4 bv = *reinterpret_cast<const float4*>(&S[1][kk * 68 + tx * 4]);
      float av[4] = {a.x, a.y, a.z, a.w};
      float bw[4] = {bv.x, bv.y, bv.z, bv.w};
#pragma unroll
      for (int i = 0; i < 4; i++)
#pragma unroll
        for (int j = 0; j < 4; j++) acc[i][j] = fmaf(av[i], bw[j], acc[i][j]);
    }
    __syncthreads();
  }

  if (EPI == 1) {
    long b = r0 >> 12;
    long nn = (r0 & 4095) + ty * 4;
    const float4 b4 = *reinterpret_cast<const float4*>(&bias[c0 + tx * 4]);
    float* Ob = out + ((b * (CO >> 6) + cb) * 4096L) * 64;
#pragma unroll
    for (int i = 0; i < 4; i++) {
      float4 o4 = make_float4(acc[i][0] + b4.x, acc[i][1] + b4.y, acc[i][2] + b4.z,
                              acc[i][3] + b4.w);
      *reinterpret_cast<float4*>(&Ob[(nn + i) * 64 + tx * 4]) = o4;
    }
  } else if (EPI == 2) {
    const float4 b4 = *reinterpret_cast<const float4*>(&bias[c0 + tx * 4]);
#pragma unroll
    for (int i = 0; i < 4; i++) {
      long r = r0 + ty * 4 + i;
      float4 f4 = *reinterpret_cast<const float4*>(&res[r * CO + c0 + tx * 4]);
      float4 o4 = make_float4(acc[i][0] + b4.x + f4.x, acc[i][1] + b4.y + f4.y,
                              acc[i][2] + b4.z + f4.z, acc[i][3] + b4.w + f4.w);
      *reinterpret_cast<float4*>(&out[r * CO + c0 + tx * 4]) = o4;
    }
  } else if (EPI == 3) {
    float* Sf = &S[0][0];
#pragma unroll
    for (int j = 0; j < 4; j++) {
      float bj = bias[c0 + tx * 4 + j];
      float4 colv = make_float4(acc[0][j] + bj, acc[1][j] + bj, acc[2][j] + bj,
                                acc[3][j] + bj);
      *reinterpret_cast<float4*>(&Sf[(tx * 4 + j) * 68 + ty * 4]) = colv;
    }
    __syncthreads();
    long b = r0 >> 12;
    long n0 = (r0 & 4095);
    int n = tid & 63, oo = tid >> 6;
#pragma unroll
    for (int i = 0; i < 16; i++) {
      int o = oo + i * 4;
      out[(b * CO + c0 + o) * 4096L + n0 + n] = Sf[o * 68 + n];   // f32 store
    }
  } else if (EPI == 4) {
    float* rs = &S[0][0];
    float* rq = &S[0][1024];
#pragma unroll
    for (int j = 0; j < 4; j++) {
      float s = 0.f, q = 0.f;
#pragma unroll
      for (int i = 0; i < 4; i++) {
        s += acc[i][j];
        q += acc[i][j] * acc[i][j];
      }
      rs[ty * 64 + tx * 4 + j] = s;
      rq[ty * 64 + tx * 4 + j] = q;
    }
    __syncthreads();
    if (tid < 128) {
      int col = tid & 63;
      bool isq = tid >= 64;
      const float* src = isq ? rq : rs;
      float a = 0.f;
#pragma unroll
      for (int t = 0; t < 16; t++) a += src[t * 64 + col];
      atomicAdd(&st[(isq ? CO : 0) + c0 + col], (double)a);
    }
  } else if (EPI == 5) {
    float* pm = &S[0][0];
    float* ps = &S[0][1024];
#pragma unroll
    for (int j = 0; j < 4; j++) {
      int c = c0 + tx * 4 + j;
      float scv = bias[c];          // sc2
      float shv = res[c];           // sh2
      float mx = -1e30f, sm = 0.f;
#pragma unroll
      for (int i = 0; i < 4; i++) {
        float v = fmaxf(0.f, fmaf(acc[i][j], scv, shv));
        mx = fmaxf(mx, v);
        sm += v;
      }
      pm[ty * 64 + tx * 4 + j] = mx;
      ps[ty * 64 + tx * 4 + j] = sm;
    }
    __syncthreads();
    int g = tid >> 6, col = tid & 63;
    float mx = pm[(g * 4 + 0) * 64 + col];
    float sm = ps[(g * 4 + 0) * 64 + col];
#pragma unroll
    for (int t = 1; t < 4; t++) {
      mx = fmaxf(mx, pm[(g * 4 + t) * 64 + col]);
      sm += ps[(g * 4 + t) * 64 + col];
    }
    long bn = (r0 >> 4) + g;
    out[bn * 512 + c0 + col] = mx;
    out[bn * 512 + 256 + c0 + col] = sm * (1.f / 16.f);
  } else if (EPI == 6) {
#pragma unroll
    for (int i = 0; i < 4; i++) {
      long r = r0 + ty * 4 + i;
      __hip_bfloat162 p0, p1;
      p0.x = __float2bfloat16(acc[i][0]);
      p0.y = __float2bfloat16(acc[i][1]);
      p1.x = __float2bfloat16(acc[i][2]);
      p1.y = __float2bfloat16(acc[i][3]);
      __hip_bfloat162* dst = reinterpret_cast<__hip_bfloat162*>(&obf[r * CO + c0 + tx * 4]);
      dst[0] = p0;
      dst[1] = p1;
    }
  }
}

// ------------- f32 flash attention: 64-row Q tile, 4 lanes per row ----------
__global__ __launch_bounds__(256) void flash_kernel(const float* __restrict__ Q,
                                                    const float* __restrict__ Kb,
                                                    const float* __restrict__ Vb,
                                                    float* __restrict__ O) {
  __shared__ float Ks[64 * 68];
  __shared__ float Vs[64 * 68];
  int tid = threadIdx.x;
  int row = tid >> 2, seg = tid & 3;
  int bh = blockIdx.x >> 6;
  int qt = blockIdx.x & 63;
  long base = (long)bh * 4096 * 64;
  int n = qt * 64 + row;
  float4 q4[4];
#pragma unroll
  for (int i = 0; i < 4; i++)
    q4[i] = *reinterpret_cast<const float4*>(&Q[base + (long)n * 64 + seg * 16 + i * 4]);
  float4 a4[4];
#pragma unroll
  for (int i = 0; i < 4; i++) a4[i] = make_float4(0.f, 0.f, 0.f, 0.f);
  float m_run = -3.0e38f, l_run = 0.f;

  for (int m0 = 0; m0 < 4096; m0 += 64) {
    __syncthreads();
    {
      int d = tid & 63, jj = tid >> 6;
#pragma unroll
      for (int i = 0; i < 16; i++) {
        int j = jj + i * 4;
        Ks[j * 68 + d] = Kb[base + (long)(m0 + j) * 64 + d];
        Vs[j * 68 + d] = Vb[base + (long)(m0 + j) * 64 + d];
      }
    }
    __syncthreads();
    for (int cj = 0; cj < 64; cj += 16) {
      float s[16];
#pragma unroll
      for (int jj = 0; jj < 16; jj++) {
        const float* kp = &Ks[(cj + jj) * 68 + seg * 16];
        float4 k0 = *reinterpret_cast<const float4*>(kp);
        float4 k1 = *reinterpret_cast<const float4*>(kp + 4);
        float4 k2 = *reinterpret_cast<const float4*>(kp + 8);
        float4 k3 = *reinterpret_cast<const float4*>(kp + 12);
        float p = q4[0].x * k0.x + q4[0].y * k0.y + q4[0].z * k0.z + q4[0].w * k0.w +
                  q4[1].x * k1.x + q4[1].y * k1.y + q4[1].z * k1.z + q4[1].w * k1.w +
                  q4[2].x * k2.x + q4[2].y * k2.y + q4[2].z * k2.z + q4[2].w * k2.w +
                  q4[3].x * k3.x + q4[3].y * k3.y + q4[3].z * k3.z + q4[3].w * k3.w;
        p += __shfl_xor(p, 1);
        p += __shfl_xor(p, 2);
        s[jj] = p * 0.125f;
      }
      float cm = s[0];
#pragma unroll
      for (int jj = 1; jj < 16; jj++) cm = fmaxf(cm, s[jj]);
      float mn = fmaxf(m_run, cm);
      float rsc = __expf(m_run - mn);
      float p16[16];
      float psum = 0.f;
#pragma unroll
      for (int jj = 0; jj < 16; jj++) {
        p16[jj] = __expf(s[jj] - mn);
        psum += p16[jj];
      }
      l_run = l_run * rsc + psum;
      m_run = mn;
#pragma unroll
      for (int i = 0; i < 4; i++) {
        a4[i].x *= rsc; a4[i].y *= rsc; a4[i].z *= rsc; a4[i].w *= rsc;
      }
#pragma unroll
      for (int jj = 0; jj < 16; jj++) {
        float p = p16[jj];
        const float* vp = &Vs[(cj + jj) * 68 + seg * 16];
#pragma unroll
        for (int i = 0; i < 4; i++) {
          float4 v = *reinterpret_cast<const float4*>(vp + i * 4);
          a4[i].x = fmaf(p, v.x, a4[i].x);
          a4[i].y = fmaf(p, v.y, a4[i].y);
          a4[i].z = fmaf(p, v.z, a4[i].z);
          a4[i].w = fmaf(p, v.w, a4[i].w);
        }
      }
    }
  }
  float inv = 1.f / l_run;
  long ob = ((long)(bh >> 2) * 4096 + n) * 256 + (bh & 3) * 64 + seg * 16;
#pragma unroll
  for (int i = 0; i < 4; i++) {
    float4 o4 = make_float4(a4[i].x * inv, a4[i].y * inv, a4[i].z * inv, a4[i].w * inv);
    *reinterpret_cast<float4*>(&O[ob + i * 4]) = o4;
  }
}

// ------------- LayerNorm over 512 (one row per block) -----------------------
__global__ __launch_bounds__(256) void ln_kernel(float* __restrict__ y,
                                                 const float* __restrict__ lng,
                                                 const float* __restrict__ lnb) {
  long r = blockIdx.x;
  int tid = threadIdx.x;
  float v0 = y[r * 512 + tid];
  float v1 = y[r * 512 + 256 + tid];
  float s = v0 + v1;
  float q = v0 * v0 + v1 * v1;
#pragma unroll
  for (int off = 1; off < 64; off <<= 1) {
    s += __shfl_xor(s, off);
    q += __shfl_xor(q, off);
  }
  __shared__ float red[8];
  __shared__ float mv[2];
  int w = tid >> 6;
  if ((tid & 63) == 0) { red[w] = s; red[4 + w] = q; }
  __syncthreads();
  if (tid == 0) {
    float S = red[0] + red[1] + red[2] + red[3];
    float Q2 = red[4] + red[5] + red[6] + red[7];
    float mu = S * (1.f / 512.f);
    float var = Q2 * (1.f / 512.f) - mu * mu;
    mv[0] = mu;
    mv[1] = rsqrtf(var + 1e-5f);
  }
  __syncthreads();
  float mu = mv[0], rstd = mv[1];
  y[r * 512 + tid] = (v0 - mu) * rstd * lng[tid] + lnb[tid];
  y[r * 512 + 256 + tid] = (v1 - mu) * rstd * lng[256 + tid] + lnb[256 + tid];
}

// ------------- output 0: pos1 passthrough, f32 -> f32 ------------------------
__global__ void poscopy_kernel(const float* __restrict__ p, float* __restrict__ o) {
  int i = blockIdx.x * 256 + threadIdx.x;
  o[i] = p[i];
}

extern "C" void kernel_launch(void* const* d_in, const int* in_sizes, int n_in,
                              void* d_out, int out_size, void* d_ws, size_t ws_size,
                              hipStream_t stream) {
  (void)in_sizes; (void)n_in; (void)out_size; (void)ws_size;
  // CONFIRMED: f32 in/out, dict order, channel-first (B,3,N)/(B,C,N);
  // out0 = pos1 (B,3,N) [passes], out1 = y (B,256,N).
  const float* pos1 = (const float*)d_in[0];
  const float* pos2 = (const float*)d_in[1];
  const float* f1 = (const float*)d_in[2];
  const float* f2 = (const float*)d_in[3];
  const float* w0 = (const float*)d_in[4];
  const float* g0 = (const float*)d_in[5];
  const float* b0 = (const float*)d_in[6];
  const float* w1 = (const float*)d_in[7];
  const float* g1 = (const float*)d_in[8];
  const float* b1 = (const float*)d_in[9];
  const float* w2 = (const float*)d_in[10];
  const float* g2 = (const float*)d_in[11];
  const float* b2 = (const float*)d_in[12];
  const float* qw = (const float*)d_in[13];
  const float* qb = (const float*)d_in[14];
  const float* kw = (const float*)d_in[15];
  const float* kb = (const float*)d_in[16];
  const float* vw = (const float*)d_in[17];
  const float* vb = (const float*)d_in[18];
  const float* ow = (const float*)d_in[19];
  const float* obv = (const float*)d_in[20];
  const float* lng = (const float*)d_in[21];
  const float* lnb = (const float*)d_in[22];
  const float* fw = (const float*)d_in[23];
  const float* fb = (const float*)d_in[24];

  // ---- workspace layout, peak 48 MB + 16 KB ----
  char* ws = (char*)d_ws;
  __hip_bfloat16* z1b = (__hip_bfloat16*)(ws);
  float* Qb = (float*)(ws);
  float* Kbuf = (float*)(ws + (8ull << 20));
  float* Vbuf = (float*)(ws + (16ull << 20));
  float* attno = (float*)(ws + (24ull << 20));
  float* y0 = (float*)(ws);
  int* idx = (int*)(ws + (32ull << 20));
  float* A1 = (float*)(ws + (33ull << 20));
  float* A2 = (float*)(ws + (37ull << 20));
  float* feat = (float*)(ws + (32ull << 20));
  char* statp = ws + (48ull << 20);
  double* st0 = (double*)(statp);
  double* st1 = (double*)(statp + 2048);
  double* st2 = (double*)(statp + 4096);
  float* sc0 = (float*)(statp + 8192);
  float* sh0 = (float*)(statp + 8704);
  float* sc1 = (float*)(statp + 9216);
  float* sh1 = (float*)(statp + 9728);
  float* sc2 = (float*)(statp + 10240);
  float* sh2 = (float*)(statp + 11264);

  float* out0 = (float*)d_out;
  float* out1 = out0 + 24576;

  hipMemsetAsync(statp, 0, 8192, stream);

  knn_kernel<<<32, 256, 0, stream>>>(pos1, pos2, idx);
  g131_kernel<<<512, 128, 0, stream>>>(pos2, f2, w0, A2, 1.f, 3);
  g131_kernel<<<512, 128, 0, stream>>>(pos1, f1, w0, A1, -1.f, 131);
  z0stats_kernel<<<256, 256, 0, stream>>>(idx, A1, A2, st0);
  bnfin_kernel<<<1, 256, 0, stream>>>(st0, g0, b0, sc0, sh0, 128, 1.0 / 131072.0);
  gemm_kernel<6, 3, true><<<dim3(2, 2048), 256, 0, stream>>>(
      A2, w1, nullptr, 128, 128, nullptr, sc0, sh0, nullptr, z1b, A1, idx, nullptr);
  statsb_kernel<<<512, 256, 0, stream>>>(z1b, 131072L, st1);
  bnfin_kernel<<<1, 256, 0, stream>>>(st1, g1, b1, sc1, sh1, 128, 1.0 / 131072.0);
  gemm_kernel<4, 2, true><<<dim3(4, 2048), 256, 0, stream>>>(
      z1b, w2, nullptr, 128, 256, nullptr, sc1, sh1, nullptr, nullptr, nullptr, nullptr, st2);
  bnfin_kernel<<<1, 256, 0, stream>>>(st2, g2, b2, sc2, sh2, 256, 1.0 / 131072.0);
  gemm_kernel<5, 2, true><<<dim3(4, 2048), 256, 0, stream>>>(
      z1b, w2, feat, 128, 256, sc2, sc1, sh1, sh2, nullptr, nullptr, nullptr, nullptr);
  gemm_kernel<1, 0, false><<<dim3(4, 128), 256, 0, stream>>>(
      feat, qw, Qb, 512, 256, qb, nullptr, nullptr, nullptr, nullptr, nullptr, nullptr, nullptr);
  gemm_kernel<1, 1, false><<<dim3(4, 128), 256, 0, stream>>>(
      f2, kw, Kbuf, 128, 256, kb, nullptr, nullptr, nullptr, nullptr, nullptr, nullptr, nullptr);
  gemm_kernel<1, 1, false><<<dim3(4, 128), 256, 0, stream>>>(
      f2, vw, Vbuf, 128, 256, vb, nullptr, nullptr, nullptr, nullptr, nullptr, nullptr, nullptr);
  flash_kernel<<<512, 256, 0, stream>>>(Qb, Kbuf, Vbuf, attno);
  gemm_kernel<2, 0, false><<<dim3(8, 128), 256, 0, stream>>>(
      attno, ow, y0, 256, 512, obv, nullptr, nullptr, feat, nullptr, nullptr, nullptr, nullptr);
  ln_kernel<<<8192, 256, 0, stream>>>(y0, lng, lnb);
  gemm_kernel<3, 0, false><<<dim3(4, 128), 256, 0, stream>>>(
      y0, fw, out1, 512, 256, fb, nullptr, nullptr, nullptr, nullptr, nullptr, nullptr, nullptr);
  poscopy_kernel<<<96, 256, 0, stream>>>(pos1, out0);
}

// Round 16
// 1879.619 us; speedup vs baseline: 1.5377x; 1.5377x over previous
//
#include <hip/hip_runtime.h>
#include <hip/hip_bf16.h>

constexpr int B_ = 2, N_ = 4096, M_ = 4096, C_ = 128;

// ---- KNN phase 1: per-(query, 256-candidate segment) register top-16 -------
// d = (s1 - 2*e) + s2 ; e via XLA fmuladd chain; s via plain mul/add.
// Bit-identical arithmetic to the round-15 passing kernel.
__global__ __launch_bounds__(256) void knn_part_kernel(const float* __restrict__ pos1,
                                                       const float* __restrict__ pos2,
                                                       float* __restrict__ pd,
                                                       int* __restrict__ pi) {
  __shared__ float tX[256], tY[256], tZ[256], tS[256];
  int tid = threadIdx.x;
  int bn = blockIdx.x * 256 + tid;
  int b = bn >> 12, n = bn & 4095;
  int seg = blockIdx.y;
  const float* p1 = pos1 + (long)b * 3 * N_;
  float qx = p1[n], qy = p1[N_ + n], qz = p1[2 * N_ + n];
  float s1 = __fadd_rn(__fadd_rn(__fmul_rn(qx, qx), __fmul_rn(qy, qy)), __fmul_rn(qz, qz));
  const float* p2 = pos2 + (long)b * 3 * M_ + seg * 256;
  {
    float x = p2[tid], y = p2[M_ + tid], z = p2[2 * M_ + tid];
    tX[tid] = x; tY[tid] = y; tZ[tid] = z;
    tS[tid] = __fadd_rn(__fadd_rn(__fmul_rn(x, x), __fmul_rn(y, y)), __fmul_rn(z, z));
  }
  __syncthreads();
  float rd[16]; int ri[16];
#pragma unroll
  for (int k = 0; k < 16; k++) { rd[k] = 3.0e38f; ri[k] = 0; }
  for (int mm = 0; mm < 256; mm++) {
    float e = __fmaf_rn(qz, tZ[mm], __fmaf_rn(qy, tY[mm], __fmul_rn(qx, tX[mm])));
    float d = __fadd_rn(__fsub_rn(s1, __fadd_rn(e, e)), tS[mm]);
    if (d < rd[15]) {
      float cd = d; int ci = seg * 256 + mm;
#pragma unroll
      for (int k = 0; k < 16; k++) {
        bool lt = cd < rd[k];
        float td = lt ? rd[k] : cd;
        int ti = lt ? ri[k] : ci;
        rd[k] = lt ? cd : rd[k];
        ri[k] = lt ? ci : ri[k];
        cd = td; ci = ti;
      }
    }
  }
  long base = (long)seg * 16 * 8192 + bn;
#pragma unroll
  for (int k = 0; k < 16; k++) {
    pd[base + (long)k * 8192] = rd[k];
    pi[base + (long)k * 8192] = ri[k];
  }
}

// ---- KNN phase 2: merge 16 sorted lists of 16 per query ---------------------
__global__ __launch_bounds__(256) void knn_merge_kernel(const float* __restrict__ pd,
                                                        const int* __restrict__ pi,
                                                        int* __restrict__ idx) {
  int bn = blockIdx.x * 256 + threadIdx.x;
  float rd[16]; int ri[16];
#pragma unroll
  for (int k = 0; k < 16; k++) { rd[k] = 3.0e38f; ri[k] = 0; }
  for (int seg = 0; seg < 16; seg++) {
    for (int k = 0; k < 16; k++) {
      float d = pd[((long)seg * 16 + k) * 8192 + bn];
      if (d >= rd[15]) break;  // segment list sorted ascending
      int ci = pi[((long)seg * 16 + k) * 8192 + bn];
      float cd = d;
#pragma unroll
      for (int j = 0; j < 16; j++) {
        bool lt = cd < rd[j];
        float td = lt ? rd[j] : cd;
        int ti = lt ? ri[j] : ci;
        rd[j] = lt ? cd : rd[j];
        ri[j] = lt ? ci : ri[j];
        cd = td; ci = ti;
      }
    }
  }
#pragma unroll
  for (int k = 0; k < 16; k++) idx[(long)bn * 16 + k] = ri[k];
}

// ------------- layer0 decomposition: 131-wide GEMM over points --------------
__global__ __launch_bounds__(128) void g131_kernel(const float* __restrict__ pos,
                                                   const float* __restrict__ feat,
                                                   const float* __restrict__ w0,
                                                   float* __restrict__ out,
                                                   float sign, int woff) {
  __shared__ float Xs[131 * 16];
  int tid = threadIdx.x;
  long b = blockIdx.x >> 8;
  int i0 = (blockIdx.x & 255) * 16;
  for (int e = tid; e < 131 * 16; e += 128) {
    int r = e & 15, c = e >> 4;
    float v = (c < 3) ? sign * pos[b * 3 * N_ + (long)c * N_ + i0 + r]
                      : feat[b * C_ * N_ + (long)(c - 3) * N_ + i0 + r];
    Xs[c * 16 + r] = v;
  }
  __syncthreads();
  int o = tid;
  float acc[16];
#pragma unroll
  for (int r = 0; r < 16; r++) acc[r] = 0.f;
  for (int c = 0; c < 131; c++) {
    float wv = w0[(long)o * 259 + (c < 3 ? c : (woff + c - 3))];
    const float* xr = &Xs[c * 16];
#pragma unroll
    for (int r = 0; r < 16; r++) acc[r] = fmaf(xr[r], wv, acc[r]);
  }
#pragma unroll
  for (int r = 0; r < 16; r++) out[((b << 12) + i0 + r) * 128 + o] = acc[r];
}

// ------------- BN0 stats from (idx, A1, A2), no z0 store --------------------
__global__ __launch_bounds__(256) void z0stats_kernel(const int* __restrict__ idx,
                                                      const float* __restrict__ A1,
                                                      const float* __restrict__ A2,
                                                      double* __restrict__ st) {
  int tid = threadIdx.x;
  int o = tid & 127, half = tid >> 7;
  float sum = 0.f, sq = 0.f;
  int g0 = blockIdx.x * 32;
  for (int gi = 0; gi < 32; gi++) {
    int bn = g0 + gi;
    long b = bn >> 12;
    float a1 = A1[(long)bn * 128 + o];
    for (int k = half; k < 16; k += 2) {
      int m = idx[bn * 16 + k];
      float v = A2[(b * 4096 + m) * 128 + o] + a1;
      sum += v;
      sq += v * v;
    }
  }
  __shared__ float ls[256], lq[256];
  ls[tid] = sum; lq[tid] = sq;
  __syncthreads();
  if (tid < 128) {
    atomicAdd(&st[o], (double)(ls[tid] + ls[tid + 128]));
    atomicAdd(&st[128 + o], (double)(lq[tid] + lq[tid + 128]));
  }
}

// ------------- per-channel stats over bf16 (nrows x 128) --------------------
__global__ __launch_bounds__(256) void statsb_kernel(const __hip_bfloat16* __restrict__ Z,
                                                     long nrows, double* __restrict__ st) {
  int tid = threadIdx.x;
  int c = tid & 127, sub = tid >> 7;
  long slot = (long)blockIdx.x * 2 + sub;
  long stride = (long)gridDim.x * 2;
  float sum = 0.f, sq = 0.f;
  for (long r = slot; r < nrows; r += stride) {
    float v = __bfloat162float(Z[r * 128 + c]);
    sum += v;
    sq += v * v;
  }
  __shared__ float ls[256], lq[256];
  ls[tid] = sum; lq[tid] = sq;
  __syncthreads();
  if (tid < 128) {
    atomicAdd(&st[c], (double)(ls[tid] + ls[tid + 128]));
    atomicAdd(&st[128 + c], (double)(lq[tid] + lq[tid + 128]));
  }
}

// ------------- BN finalize: fold mean/var/g/b into scale+shift --------------
__global__ void bnfin_kernel(const double* __restrict__ st, const float* __restrict__ g,
                             const float* __restrict__ bb, float* __restrict__ sc,
                             float* __restrict__ sh, int CO, double inv) {
  int c = threadIdx.x;
  if (c < CO) {
    double mu = st[c] * inv;
    double var = st[CO + c] * inv - mu * mu;
    double rstd = 1.0 / sqrt(var + 1e-5);
    double scv = (double)g[c] * rstd;
    sc[c] = (float)scv;
    sh[c] = (float)((double)bb[c] - mu * scv);
  }
}

// ------------- tiled GEMM: out = act(X) * W^T (+epilogues), f32 accum -------
template <int EPI, int XM, bool BN>
__global__ __launch_bounds__(256) void gemm_kernel(
    const void* __restrict__ Xv, const float* __restrict__ W, float* __restrict__ out,
    int K, int CO, const float* __restrict__ bias, const float* __restrict__ sc,
    const float* __restrict__ sh, const float* __restrict__ res,
    __hip_bfloat16* __restrict__ obf, const float* __restrict__ A1,
    const int* __restrict__ idxp, double* __restrict__ st) {
  __shared__ float S[2][32 * 68];
  int tid = threadIdx.x;
  int tx = tid & 15, ty = tid >> 4;
  int cb = blockIdx.x;
  long r0 = (long)blockIdx.y * 64;
  int c0 = cb * 64;
  float acc[4][4];
#pragma unroll
  for (int i = 0; i < 4; i++)
#pragma unroll
    for (int j = 0; j < 4; j++) acc[i][j] = 0.f;

  for (int k0 = 0; k0 < K; k0 += 32) {
    if (XM != 1) {
      int c = tid & 31, rr = tid >> 5;
      float scv = 0.f, shv = 0.f;
      if (BN) { scv = sc[k0 + c]; shv = sh[k0 + c]; }
#pragma unroll
      for (int i = 0; i < 8; i++) {
        int r = rr + i * 8;
        long g = r0 + r;
        float v;
        if (XM == 0) {
          v = ((const float*)Xv)[g * K + k0 + c];
        } else if (XM == 2) {
          v = __bfloat162float(((const __hip_bfloat16*)Xv)[g * K + k0 + c]);
        } else {
          const float* A2 = (const float*)Xv;
          int m = idxp[g];
          v = A2[(((g >> 16) << 12) + m) * 128 + k0 + c] + A1[(g >> 4) * 128 + k0 + c];
        }
        if (BN) v = fmaxf(0.f, fmaf(v, scv, shv));
        S[0][c * 68 + r] = v;
      }
    } else {
      int m = tid & 63, cc = tid >> 6;
      long b = r0 >> 12;
      long mg = (r0 & 4095) + m;
#pragma unroll
      for (int i = 0; i < 8; i++) {
        int c = cc + i * 4;
        S[0][c * 68 + m] = ((const float*)Xv)[(b * K + k0 + c) * 4096 + mg];
      }
    }
    {
      int c = tid & 31, oo = tid >> 5;
#pragma unroll
      for (int i = 0; i < 8; i++) {
        int o = oo + i * 8;
        S[1][c * 68 + o] = W[(long)(c0 + o) * K + k0 + c];
      }
    }
    __syncthreads();
#pragma unroll
    for (int kk = 0; kk < 32; kk++) {
      float4 a = *reinterpret_cast<const float4*>(&S[0][kk * 68 + ty * 4]);
      float4 bv = *reinterpret_cast<const float4*>(&S[1][kk * 68 + tx * 4]);
      float av[4] = {a.x, a.y, a.z, a.w};
      float bw[4] = {bv.x, bv.y, bv.z, bv.w};
#pragma unroll
      for (int i = 0; i < 4; i++)
#pragma unroll
        for (int j = 0; j < 4; j++) acc[i][j] = fmaf(av[i], bw[j], acc[i][j]);
    }
    __syncthreads();
  }

  if (EPI == 1) {
    long b = r0 >> 12;
    long nn = (r0 & 4095) + ty * 4;
    const float4 b4 = *reinterpret_cast<const float4*>(&bias[c0 + tx * 4]);
    float* Ob = out + ((b * (CO >> 6) + cb) * 4096L) * 64;
#pragma unroll
    for (int i = 0; i < 4; i++) {
      float4 o4 = make_float4(acc[i][0] + b4.x, acc[i][1] + b4.y, acc[i][2] + b4.z,
                              acc[i][3] + b4.w);
      *reinterpret_cast<float4*>(&Ob[(nn + i) * 64 + tx * 4]) = o4;
    }
  } else if (EPI == 2) {
    const float4 b4 = *reinterpret_cast<const float4*>(&bias[c0 + tx * 4]);
#pragma unroll
    for (int i = 0; i < 4; i++) {
      long r = r0 + ty * 4 + i;
      float4 f4 = *reinterpret_cast<const float4*>(&res[r * CO + c0 + tx * 4]);
      float4 o4 = make_float4(acc[i][0] + b4.x + f4.x, acc[i][1] + b4.y + f4.y,
                              acc[i][2] + b4.z + f4.z, acc[i][3] + b4.w + f4.w);
      *reinterpret_cast<float4*>(&out[r * CO + c0 + tx * 4]) = o4;
    }
  } else if (EPI == 3) {
    float* Sf = &S[0][0];
#pragma unroll
    for (int j = 0; j < 4; j++) {
      float bj = bias[c0 + tx * 4 + j];
      float4 colv = make_float4(acc[0][j] + bj, acc[1][j] + bj, acc[2][j] + bj,
                                acc[3][j] + bj);
      *reinterpret_cast<float4*>(&Sf[(tx * 4 + j) * 68 + ty * 4]) = colv;
    }
    __syncthreads();
    long b = r0 >> 12;
    long n0 = (r0 & 4095);
    int n = tid & 63, oo = tid >> 6;
#pragma unroll
    for (int i = 0; i < 16; i++) {
      int o = oo + i * 4;
      out[(b * CO + c0 + o) * 4096L + n0 + n] = Sf[o * 68 + n];
    }
  } else if (EPI == 4) {
    float* rs = &S[0][0];
    float* rq = &S[0][1024];
#pragma unroll
    for (int j = 0; j < 4; j++) {
      float s = 0.f, q = 0.f;
#pragma unroll
      for (int i = 0; i < 4; i++) {
        s += acc[i][j];
        q += acc[i][j] * acc[i][j];
      }
      rs[ty * 64 + tx * 4 + j] = s;
      rq[ty * 64 + tx * 4 + j] = q;
    }
    __syncthreads();
    if (tid < 128) {
      int col = tid & 63;
      bool isq = tid >= 64;
      const float* src = isq ? rq : rs;
      float a = 0.f;
#pragma unroll
      for (int t = 0; t < 16; t++) a += src[t * 64 + col];
      atomicAdd(&st[(isq ? CO : 0) + c0 + col], (double)a);
    }
  } else if (EPI == 5) {
    float* pm = &S[0][0];
    float* ps = &S[0][1024];
#pragma unroll
    for (int j = 0; j < 4; j++) {
      int c = c0 + tx * 4 + j;
      float scv = bias[c];          // sc2
      float shv = res[c];           // sh2
      float mx = -1e30f, sm = 0.f;
#pragma unroll
      for (int i = 0; i < 4; i++) {
        float v = fmaxf(0.f, fmaf(acc[i][j], scv, shv));
        mx = fmaxf(mx, v);
        sm += v;
      }
      pm[ty * 64 + tx * 4 + j] = mx;
      ps[ty * 64 + tx * 4 + j] = sm;
    }
    __syncthreads();
    int g = tid >> 6, col = tid & 63;
    float mx = pm[(g * 4 + 0) * 64 + col];
    float sm = ps[(g * 4 + 0) * 64 + col];
#pragma unroll
    for (int t = 1; t < 4; t++) {
      mx = fmaxf(mx, pm[(g * 4 + t) * 64 + col]);
      sm += ps[(g * 4 + t) * 64 + col];
    }
    long bn = (r0 >> 4) + g;
    out[bn * 512 + c0 + col] = mx;
    out[bn * 512 + 256 + c0 + col] = sm * (1.f / 16.f);
  } else if (EPI == 6) {
#pragma unroll
    for (int i = 0; i < 4; i++) {
      long r = r0 + ty * 4 + i;
      __hip_bfloat162 p0, p1;
      p0.x = __float2bfloat16(acc[i][0]);
      p0.y = __float2bfloat16(acc[i][1]);
      p1.x = __float2bfloat16(acc[i][2]);
      p1.y = __float2bfloat16(acc[i][3]);
      __hip_bfloat162* dst = reinterpret_cast<__hip_bfloat162*>(&obf[r * CO + c0 + tx * 4]);
      dst[0] = p0;
      dst[1] = p1;
    }
  }
}

// ------------- f32 flash attention: 64-row Q tile, 4 lanes per row ----------
__global__ __launch_bounds__(256) void flash_kernel(const float* __restrict__ Q,
                                                    const float* __restrict__ Kb,
                                                    const float* __restrict__ Vb,
                                                    float* __restrict__ O) {
  __shared__ float Ks[64 * 68];
  __shared__ float Vs[64 * 68];
  int tid = threadIdx.x;
  int row = tid >> 2, seg = tid & 3;
  int bh = blockIdx.x >> 6;
  int qt = blockIdx.x & 63;
  long base = (long)bh * 4096 * 64;
  int n = qt * 64 + row;
  float4 q4[4];
#pragma unroll
  for (int i = 0; i < 4; i++)
    q4[i] = *reinterpret_cast<const float4*>(&Q[base + (long)n * 64 + seg * 16 + i * 4]);
  float4 a4[4];
#pragma unroll
  for (int i = 0; i < 4; i++) a4[i] = make_float4(0.f, 0.f, 0.f, 0.f);
  float m_run = -3.0e38f, l_run = 0.f;

  for (int m0 = 0; m0 < 4096; m0 += 64) {
    __syncthreads();
    {
      int d = tid & 63, jj = tid >> 6;
#pragma unroll
      for (int i = 0; i < 16; i++) {
        int j = jj + i * 4;
        Ks[j * 68 + d] = Kb[base + (long)(m0 + j) * 64 + d];
        Vs[j * 68 + d] = Vb[base + (long)(m0 + j) * 64 + d];
      }
    }
    __syncthreads();
    for (int cj = 0; cj < 64; cj += 16) {
      float s[16];
#pragma unroll
      for (int jj = 0; jj < 16; jj++) {
        const float* kp = &Ks[(cj + jj) * 68 + seg * 16];
        float4 k0 = *reinterpret_cast<const float4*>(kp);
        float4 k1 = *reinterpret_cast<const float4*>(kp + 4);
        float4 k2 = *reinterpret_cast<const float4*>(kp + 8);
        float4 k3 = *reinterpret_cast<const float4*>(kp + 12);
        float p = q4[0].x * k0.x + q4[0].y * k0.y + q4[0].z * k0.z + q4[0].w * k0.w +
                  q4[1].x * k1.x + q4[1].y * k1.y + q4[1].z * k1.z + q4[1].w * k1.w +
                  q4[2].x * k2.x + q4[2].y * k2.y + q4[2].z * k2.z + q4[2].w * k2.w +
                  q4[3].x * k3.x + q4[3].y * k3.y + q4[3].z * k3.z + q4[3].w * k3.w;
        p += __shfl_xor(p, 1);
        p += __shfl_xor(p, 2);
        s[jj] = p * 0.125f;
      }
      float cm = s[0];
#pragma unroll
      for (int jj = 1; jj < 16; jj++) cm = fmaxf(cm, s[jj]);
      float mn = fmaxf(m_run, cm);
      float rsc = __expf(m_run - mn);
      float p16[16];
      float psum = 0.f;
#pragma unroll
      for (int jj = 0; jj < 16; jj++) {
        p16[jj] = __expf(s[jj] - mn);
        psum += p16[jj];
      }
      l_run = l_run * rsc + psum;
      m_run = mn;
#pragma unroll
      for (int i = 0; i < 4; i++) {
        a4[i].x *= rsc; a4[i].y *= rsc; a4[i].z *= rsc; a4[i].w *= rsc;
      }
#pragma unroll
      for (int jj = 0; jj < 16; jj++) {
        float p = p16[jj];
        const float* vp = &Vs[(cj + jj) * 68 + seg * 16];
#pragma unroll
        for (int i = 0; i < 4; i++) {
          float4 v = *reinterpret_cast<const float4*>(vp + i * 4);
          a4[i].x = fmaf(p, v.x, a4[i].x);
          a4[i].y = fmaf(p, v.y, a4[i].y);
          a4[i].z = fmaf(p, v.z, a4[i].z);
          a4[i].w = fmaf(p, v.w, a4[i].w);
        }
      }
    }
  }
  float inv = 1.f / l_run;
  long ob = ((long)(bh >> 2) * 4096 + n) * 256 + (bh & 3) * 64 + seg * 16;
#pragma unroll
  for (int i = 0; i < 4; i++) {
    float4 o4 = make_float4(a4[i].x * inv, a4[i].y * inv, a4[i].z * inv, a4[i].w * inv);
    *reinterpret_cast<float4*>(&O[ob + i * 4]) = o4;
  }
}

// ------------- LayerNorm over 512 (one row per block) -----------------------
__global__ __launch_bounds__(256) void ln_kernel(float* __restrict__ y,
                                                 const float* __restrict__ lng,
                                                 const float* __restrict__ lnb) {
  long r = blockIdx.x;
  int tid = threadIdx.x;
  float v0 = y[r * 512 + tid];
  float v1 = y[r * 512 + 256 + tid];
  float s = v0 + v1;
  float q = v0 * v0 + v1 * v1;
#pragma unroll
  for (int off = 1; off < 64; off <<= 1) {
    s += __shfl_xor(s, off);
    q += __shfl_xor(q, off);
  }
  __shared__ float red[8];
  __shared__ float mv[2];
  int w = tid >> 6;
  if ((tid & 63) == 0) { red[w] = s; red[4 + w] = q; }
  __syncthreads();
  if (tid == 0) {
    float S = red[0] + red[1] + red[2] + red[3];
    float Q2 = red[4] + red[5] + red[6] + red[7];
    float mu = S * (1.f / 512.f);
    float var = Q2 * (1.f / 512.f) - mu * mu;
    mv[0] = mu;
    mv[1] = rsqrtf(var + 1e-5f);
  }
  __syncthreads();
  float mu = mv[0], rstd = mv[1];
  y[r * 512 + tid] = (v0 - mu) * rstd * lng[tid] + lnb[tid];
  y[r * 512 + 256 + tid] = (v1 - mu) * rstd * lng[256 + tid] + lnb[256 + tid];
}

// ------------- output 0: pos1 passthrough, f32 -> f32 ------------------------
__global__ void poscopy_kernel(const float* __restrict__ p, float* __restrict__ o) {
  int i = blockIdx.x * 256 + threadIdx.x;
  o[i] = p[i];
}

extern "C" void kernel_launch(void* const* d_in, const int* in_sizes, int n_in,
                              void* d_out, int out_size, void* d_ws, size_t ws_size,
                              hipStream_t stream) {
  (void)in_sizes; (void)n_in; (void)out_size; (void)ws_size;
  const float* pos1 = (const float*)d_in[0];
  const float* pos2 = (const float*)d_in[1];
  const float* f1 = (const float*)d_in[2];
  const float* f2 = (const float*)d_in[3];
  const float* w0 = (const float*)d_in[4];
  const float* g0 = (const float*)d_in[5];
  const float* b0 = (const float*)d_in[6];
  const float* w1 = (const float*)d_in[7];
  const float* g1 = (const float*)d_in[8];
  const float* b1 = (const float*)d_in[9];
  const float* w2 = (const float*)d_in[10];
  const float* g2 = (const float*)d_in[11];
  const float* b2 = (const float*)d_in[12];
  const float* qw = (const float*)d_in[13];
  const float* qb = (const float*)d_in[14];
  const float* kw = (const float*)d_in[15];
  const float* kb = (const float*)d_in[16];
  const float* vw = (const float*)d_in[17];
  const float* vb = (const float*)d_in[18];
  const float* ow = (const float*)d_in[19];
  const float* obv = (const float*)d_in[20];
  const float* lng = (const float*)d_in[21];
  const float* lnb = (const float*)d_in[22];
  const float* fw = (const float*)d_in[23];
  const float* fb = (const float*)d_in[24];

  // ---- workspace layout ----
  // [0,32MB): z1 bf16 -> Q/K/V/attno f32 -> y0 ; [32,48MB): idx+A1+A2 -> feat
  // [48MB,+16KB): stats ; [56,72MB): knn partials (pd f32, pi i32)
  char* ws = (char*)d_ws;
  __hip_bfloat16* z1b = (__hip_bfloat16*)(ws);
  float* Qb = (float*)(ws);
  float* Kbuf = (float*)(ws + (8ull << 20));
  float* Vbuf = (float*)(ws + (16ull << 20));
  float* attno = (float*)(ws + (24ull << 20));
  float* y0 = (float*)(ws);
  int* idx = (int*)(ws + (32ull << 20));
  float* A1 = (float*)(ws + (33ull << 20));
  float* A2 = (float*)(ws + (37ull << 20));
  float* feat = (float*)(ws + (32ull << 20));
  char* statp = ws + (48ull << 20);
  float* pd = (float*)(ws + (56ull << 20));
  int* pi = (int*)(ws + (64ull << 20));
  double* st0 = (double*)(statp);
  double* st1 = (double*)(statp + 2048);
  double* st2 = (double*)(statp + 4096);
  float* sc0 = (float*)(statp + 8192);
  float* sh0 = (float*)(statp + 8704);
  float* sc1 = (float*)(statp + 9216);
  float* sh1 = (float*)(statp + 9728);
  float* sc2 = (float*)(statp + 10240);
  float* sh2 = (float*)(statp + 11264);

  float* out0 = (float*)d_out;
  float* out1 = out0 + 24576;

  hipMemsetAsync(statp, 0, 8192, stream);

  knn_part_kernel<<<dim3(32, 16), 256, 0, stream>>>(pos1, pos2, pd, pi);
  knn_merge_kernel<<<32, 256, 0, stream>>>(pd, pi, idx);
  g131_kernel<<<512, 128, 0, stream>>>(pos2, f2, w0, A2, 1.f, 3);
  g131_kernel<<<512, 128, 0, stream>>>(pos1, f1, w0, A1, -1.f, 131);
  z0stats_kernel<<<256, 256, 0, stream>>>(idx, A1, A2, st0);
  bnfin_kernel<<<1, 256, 0, stream>>>(st0, g0, b0, sc0, sh0, 128, 1.0 / 131072.0);
  gemm_kernel<6, 3, true><<<dim3(2, 2048), 256, 0, stream>>>(
      A2, w1, nullptr, 128, 128, nullptr, sc0, sh0, nullptr, z1b, A1, idx, nullptr);
  statsb_kernel<<<512, 256, 0, stream>>>(z1b, 131072L, st1);
  bnfin_kernel<<<1, 256, 0, stream>>>(st1, g1, b1, sc1, sh1, 128, 1.0 / 131072.0);
  gemm_kernel<4, 2, true><<<dim3(4, 2048), 256, 0, stream>>>(
      z1b, w2, nullptr, 128, 256, nullptr, sc1, sh1, nullptr, nullptr, nullptr, nullptr, st2);
  bnfin_kernel<<<1, 256, 0, stream>>>(st2, g2, b2, sc2, sh2, 256, 1.0 / 131072.0);
  gemm_kernel<5, 2, true><<<dim3(4, 2048), 256, 0, stream>>>(
      z1b, w2, feat, 128, 256, sc2, sc1, sh1, sh2, nullptr, nullptr, nullptr, nullptr);
  gemm_kernel<1, 0, false><<<dim3(4, 128), 256, 0, stream>>>(
      feat, qw, Qb, 512, 256, qb, nullptr, nullptr, nullptr, nullptr, nullptr, nullptr, nullptr);
  gemm_kernel<1, 1, false><<<dim3(4, 128), 256, 0, stream>>>(
      f2, kw, Kbuf, 128, 256, kb, nullptr, nullptr, nullptr, nullptr, nullptr, nullptr, nullptr);
  gemm_kernel<1, 1, false><<<dim3(4, 128), 256, 0, stream>>>(
      f2, vw, Vbuf, 128, 256, vb, nullptr, nullptr, nullptr, nullptr, nullptr, nullptr, nullptr);
  flash_kernel<<<512, 256, 0, stream>>>(Qb, Kbuf, Vbuf, attno);
  gemm_kernel<2, 0, false><<<dim3(8, 128), 256, 0, stream>>>(
      attno, ow, y0, 256, 512, obv, nullptr, nullptr, feat, nullptr, nullptr, nullptr, nullptr);
  ln_kernel<<<8192, 256, 0, stream>>>(y0, lng, lnb);
  gemm_kernel<3, 0, false><<<dim3(4, 128), 256, 0, stream>>>(
      y0, fw, out1, 512, 256, fb, nullptr, nullptr, nullptr, nullptr, nullptr, nullptr, nullptr);
  poscopy_kernel<<<96, 256, 0, stream>>>(pos1, out0);
}

// Round 17
// 1216.264 us; speedup vs baseline: 2.3764x; 1.5454x over previous
//
#include <hip/hip_runtime.h>
#include <hip/hip_bf16.h>

constexpr int B_ = 2, N_ = 4096, M_ = 4096, C_ = 128;

typedef __attribute__((ext_vector_type(8))) __bf16 bf16x8;
typedef __attribute__((ext_vector_type(4))) float f32x4;

// ---- KNN phase 1: per-(query, 256-candidate segment) register top-16 -------
__global__ __launch_bounds__(256) void knn_part_kernel(const float* __restrict__ pos1,
                                                       const float* __restrict__ pos2,
                                                       float* __restrict__ pd,
                                                       int* __restrict__ pi) {
  __shared__ float tX[256], tY[256], tZ[256], tS[256];
  int tid = threadIdx.x;
  int bn = blockIdx.x * 256 + tid;
  int b = bn >> 12, n = bn & 4095;
  int seg = blockIdx.y;
  const float* p1 = pos1 + (long)b * 3 * N_;
  float qx = p1[n], qy = p1[N_ + n], qz = p1[2 * N_ + n];
  float s1 = __fadd_rn(__fadd_rn(__fmul_rn(qx, qx), __fmul_rn(qy, qy)), __fmul_rn(qz, qz));
  const float* p2 = pos2 + (long)b * 3 * M_ + seg * 256;
  {
    float x = p2[tid], y = p2[M_ + tid], z = p2[2 * M_ + tid];
    tX[tid] = x; tY[tid] = y; tZ[tid] = z;
    tS[tid] = __fadd_rn(__fadd_rn(__fmul_rn(x, x), __fmul_rn(y, y)), __fmul_rn(z, z));
  }
  __syncthreads();
  float rd[16]; int ri[16];
#pragma unroll
  for (int k = 0; k < 16; k++) { rd[k] = 3.0e38f; ri[k] = 0; }
  for (int mm = 0; mm < 256; mm++) {
    float e = __fmaf_rn(qz, tZ[mm], __fmaf_rn(qy, tY[mm], __fmul_rn(qx, tX[mm])));
    float d = __fadd_rn(__fsub_rn(s1, __fadd_rn(e, e)), tS[mm]);
    if (d < rd[15]) {
      float cd = d; int ci = seg * 256 + mm;
#pragma unroll
      for (int k = 0; k < 16; k++) {
        bool lt = cd < rd[k];
        float td = lt ? rd[k] : cd;
        int ti = lt ? ri[k] : ci;
        rd[k] = lt ? cd : rd[k];
        ri[k] = lt ? ci : ri[k];
        cd = td; ci = ti;
      }
    }
  }
  long base = (long)seg * 16 * 8192 + bn;
#pragma unroll
  for (int k = 0; k < 16; k++) {
    pd[base + (long)k * 8192] = rd[k];
    pi[base + (long)k * 8192] = ri[k];
  }
}

// ---- KNN phase 2: merge 16 sorted lists of 16 per query ---------------------
__global__ __launch_bounds__(256) void knn_merge_kernel(const float* __restrict__ pd,
                                                        const int* __restrict__ pi,
                                                        int* __restrict__ idx) {
  int bn = blockIdx.x * 256 + threadIdx.x;
  float rd[16]; int ri[16];
#pragma unroll
  for (int k = 0; k < 16; k++) { rd[k] = 3.0e38f; ri[k] = 0; }
  for (int seg = 0; seg < 16; seg++) {
    for (int k = 0; k < 16; k++) {
      float d = pd[((long)seg * 16 + k) * 8192 + bn];
      if (d >= rd[15]) break;
      int ci = pi[((long)seg * 16 + k) * 8192 + bn];
      float cd = d;
#pragma unroll
      for (int j = 0; j < 16; j++) {
        bool lt = cd < rd[j];
        float td = lt ? rd[j] : cd;
        int ti = lt ? ri[j] : ci;
        rd[j] = lt ? cd : rd[j];
        ri[j] = lt ? ci : ri[j];
        cd = td; ci = ti;
      }
    }
  }
#pragma unroll
  for (int k = 0; k < 16; k++) idx[(long)bn * 16 + k] = ri[k];
}

// ------------- layer0 decomposition: 131-wide GEMM over points --------------
__global__ __launch_bounds__(128) void g131_kernel(const float* __restrict__ pos,
                                                   const float* __restrict__ feat,
                                                   const float* __restrict__ w0,
                                                   float* __restrict__ out,
                                                   float sign, int woff) {
  __shared__ float Xs[131 * 16];
  int tid = threadIdx.x;
  long b = blockIdx.x >> 8;
  int i0 = (blockIdx.x & 255) * 16;
  for (int e = tid; e < 131 * 16; e += 128) {
    int r = e & 15, c = e >> 4;
    float v = (c < 3) ? sign * pos[b * 3 * N_ + (long)c * N_ + i0 + r]
                      : feat[b * C_ * N_ + (long)(c - 3) * N_ + i0 + r];
    Xs[c * 16 + r] = v;
  }
  __syncthreads();
  int o = tid;
  float acc[16];
#pragma unroll
  for (int r = 0; r < 16; r++) acc[r] = 0.f;
  for (int c = 0; c < 131; c++) {
    float wv = w0[(long)o * 259 + (c < 3 ? c : (woff + c - 3))];
    const float* xr = &Xs[c * 16];
#pragma unroll
    for (int r = 0; r < 16; r++) acc[r] = fmaf(xr[r], wv, acc[r]);
  }
#pragma unroll
  for (int r = 0; r < 16; r++) out[((b << 12) + i0 + r) * 128 + o] = acc[r];
}

// ------------- BN0 stats from (idx, A1, A2), no z0 store --------------------
__global__ __launch_bounds__(256) void z0stats_kernel(const int* __restrict__ idx,
                                                      const float* __restrict__ A1,
                                                      const float* __restrict__ A2,
                                                      double* __restrict__ st) {
  int tid = threadIdx.x;
  int o = tid & 127, half = tid >> 7;
  float sum = 0.f, sq = 0.f;
  int g0 = blockIdx.x * 32;
  for (int gi = 0; gi < 32; gi++) {
    int bn = g0 + gi;
    long b = bn >> 12;
    float a1 = A1[(long)bn * 128 + o];
    for (int k = half; k < 16; k += 2) {
      int m = idx[bn * 16 + k];
      float v = A2[(b * 4096 + m) * 128 + o] + a1;
      sum += v;
      sq += v * v;
    }
  }
  __shared__ float ls[256], lq[256];
  ls[tid] = sum; lq[tid] = sq;
  __syncthreads();
  if (tid < 128) {
    atomicAdd(&st[o], (double)(ls[tid] + ls[tid + 128]));
    atomicAdd(&st[128 + o], (double)(lq[tid] + lq[tid + 128]));
  }
}

// ------------- per-channel stats over bf16 (nrows x 128) --------------------
__global__ __launch_bounds__(256) void statsb_kernel(const __hip_bfloat16* __restrict__ Z,
                                                     long nrows, double* __restrict__ st) {
  int tid = threadIdx.x;
  int c = tid & 127, sub = tid >> 7;
  long slot = (long)blockIdx.x * 2 + sub;
  long stride = (long)gridDim.x * 2;
  float sum = 0.f, sq = 0.f;
  for (long r = slot; r < nrows; r += stride) {
    float v = __bfloat162float(Z[r * 128 + c]);
    sum += v;
    sq += v * v;
  }
  __shared__ float ls[256], lq[256];
  ls[tid] = sum; lq[tid] = sq;
  __syncthreads();
  if (tid < 128) {
    atomicAdd(&st[c], (double)(ls[tid] + ls[tid + 128]));
    atomicAdd(&st[128 + c], (double)(lq[tid] + lq[tid + 128]));
  }
}

// ------------- BN finalize: fold mean/var/g/b into scale+shift --------------
__global__ void bnfin_kernel(const double* __restrict__ st, const float* __restrict__ g,
                             const float* __restrict__ bb, float* __restrict__ sc,
                             float* __restrict__ sh, int CO, double inv) {
  int c = threadIdx.x;
  if (c < CO) {
    double mu = st[c] * inv;
    double var = st[CO + c] * inv - mu * mu;
    double rstd = 1.0 / sqrt(var + 1e-5);
    double scv = (double)g[c] * rstd;
    sc[c] = (float)scv;
    sh[c] = (float)((double)bb[c] - mu * scv);
  }
}

// ------------- tiled GEMM: out = act(X) * W^T (+epilogues), f32 accum -------
template <int EPI, int XM, bool BN>
__global__ __launch_bounds__(256) void gemm_kernel(
    const void* __restrict__ Xv, const float* __restrict__ W, float* __restrict__ out,
    int K, int CO, const float* __restrict__ bias, const float* __restrict__ sc,
    const float* __restrict__ sh, const float* __restrict__ res,
    __hip_bfloat16* __restrict__ obf, const float* __restrict__ A1,
    const int* __restrict__ idxp, double* __restrict__ st) {
  __shared__ float S[2][32 * 68];
  int tid = threadIdx.x;
  int tx = tid & 15, ty = tid >> 4;
  int cb = blockIdx.x;
  long r0 = (long)blockIdx.y * 64;
  int c0 = cb * 64;
  float acc[4][4];
#pragma unroll
  for (int i = 0; i < 4; i++)
#pragma unroll
    for (int j = 0; j < 4; j++) acc[i][j] = 0.f;

  for (int k0 = 0; k0 < K; k0 += 32) {
    if (XM != 1) {
      int c = tid & 31, rr = tid >> 5;
      float scv = 0.f, shv = 0.f;
      if (BN) { scv = sc[k0 + c]; shv = sh[k0 + c]; }
#pragma unroll
      for (int i = 0; i < 8; i++) {
        int r = rr + i * 8;
        long g = r0 + r;
        float v;
        if (XM == 0) {
          v = ((const float*)Xv)[g * K + k0 + c];
        } else if (XM == 2) {
          v = __bfloat162float(((const __hip_bfloat16*)Xv)[g * K + k0 + c]);
        } else {
          const float* A2 = (const float*)Xv;
          int m = idxp[g];
          v = A2[(((g >> 16) << 12) + m) * 128 + k0 + c] + A1[(g >> 4) * 128 + k0 + c];
        }
        if (BN) v = fmaxf(0.f, fmaf(v, scv, shv));
        S[0][c * 68 + r] = v;
      }
    } else {
      int m = tid & 63, cc = tid >> 6;
      long b = r0 >> 12;
      long mg = (r0 & 4095) + m;
#pragma unroll
      for (int i = 0; i < 8; i++) {
        int c = cc + i * 4;
        S[0][c * 68 + m] = ((const float*)Xv)[(b * K + k0 + c) * 4096 + mg];
      }
    }
    {
      int c = tid & 31, oo = tid >> 5;
#pragma unroll
      for (int i = 0; i < 8; i++) {
        int o = oo + i * 8;
        S[1][c * 68 + o] = W[(long)(c0 + o) * K + k0 + c];
      }
    }
    __syncthreads();
#pragma unroll
    for (int kk = 0; kk < 32; kk++) {
      float4 a = *reinterpret_cast<const float4*>(&S[0][kk * 68 + ty * 4]);
      float4 bv = *reinterpret_cast<const float4*>(&S[1][kk * 68 + tx * 4]);
      float av[4] = {a.x, a.y, a.z, a.w};
      float bw[4] = {bv.x, bv.y, bv.z, bv.w};
#pragma unroll
      for (int i = 0; i < 4; i++)
#pragma unroll
        for (int j = 0; j < 4; j++) acc[i][j] = fmaf(av[i], bw[j], acc[i][j]);
    }
    __syncthreads();
  }

  if (EPI == 1) {
    long b = r0 >> 12;
    long nn = (r0 & 4095) + ty * 4;
    const float4 b4 = *reinterpret_cast<const float4*>(&bias[c0 + tx * 4]);
    float* Ob = out + ((b * (CO >> 6) + cb) * 4096L) * 64;
#pragma unroll
    for (int i = 0; i < 4; i++) {
      float4 o4 = make_float4(acc[i][0] + b4.x, acc[i][1] + b4.y, acc[i][2] + b4.z,
                              acc[i][3] + b4.w);
      *reinterpret_cast<float4*>(&Ob[(nn + i) * 64 + tx * 4]) = o4;
    }
  } else if (EPI == 2) {
    const float4 b4 = *reinterpret_cast<const float4*>(&bias[c0 + tx * 4]);
#pragma unroll
    for (int i = 0; i < 4; i++) {
      long r = r0 + ty * 4 + i;
      float4 f4 = *reinterpret_cast<const float4*>(&res[r * CO + c0 + tx * 4]);
      float4 o4 = make_float4(acc[i][0] + b4.x + f4.x, acc[i][1] + b4.y + f4.y,
                              acc[i][2] + b4.z + f4.z, acc[i][3] + b4.w + f4.w);
      *reinterpret_cast<float4*>(&out[r * CO + c0 + tx * 4]) = o4;
    }
  } else if (EPI == 3) {
    float* Sf = &S[0][0];
#pragma unroll
    for (int j = 0; j < 4; j++) {
      float bj = bias[c0 + tx * 4 + j];
      float4 colv = make_float4(acc[0][j] + bj, acc[1][j] + bj, acc[2][j] + bj,
                                acc[3][j] + bj);
      *reinterpret_cast<float4*>(&Sf[(tx * 4 + j) * 68 + ty * 4]) = colv;
    }
    __syncthreads();
    long b = r0 >> 12;
    long n0 = (r0 & 4095);
    int n = tid & 63, oo = tid >> 6;
#pragma unroll
    for (int i = 0; i < 16; i++) {
      int o = oo + i * 4;
      out[(b * CO + c0 + o) * 4096L + n0 + n] = Sf[o * 68 + n];
    }
  } else if (EPI == 4) {
    float* rs = &S[0][0];
    float* rq = &S[0][1024];
#pragma unroll
    for (int j = 0; j < 4; j++) {
      float s = 0.f, q = 0.f;
#pragma unroll
      for (int i = 0; i < 4; i++) {
        s += acc[i][j];
        q += acc[i][j] * acc[i][j];
      }
      rs[ty * 64 + tx * 4 + j] = s;
      rq[ty * 64 + tx * 4 + j] = q;
    }
    __syncthreads();
    if (tid < 128) {
      int col = tid & 63;
      bool isq = tid >= 64;
      const float* src = isq ? rq : rs;
      float a = 0.f;
#pragma unroll
      for (int t = 0; t < 16; t++) a += src[t * 64 + col];
      atomicAdd(&st[(isq ? CO : 0) + c0 + col], (double)a);
    }
  } else if (EPI == 5) {
    float* pm = &S[0][0];
    float* ps = &S[0][1024];
#pragma unroll
    for (int j = 0; j < 4; j++) {
      int c = c0 + tx * 4 + j;
      float scv = bias[c];          // sc2
      float shv = res[c];           // sh2
      float mx = -1e30f, sm = 0.f;
#pragma unroll
      for (int i = 0; i < 4; i++) {
        float v = fmaxf(0.f, fmaf(acc[i][j], scv, shv));
        mx = fmaxf(mx, v);
        sm += v;
      }
      pm[ty * 64 + tx * 4 + j] = mx;
      ps[ty * 64 + tx * 4 + j] = sm;
    }
    __syncthreads();
    int g = tid >> 6, col = tid & 63;
    float mx = pm[(g * 4 + 0) * 64 + col];
    float sm = ps[(g * 4 + 0) * 64 + col];
#pragma unroll
    for (int t = 1; t < 4; t++) {
      mx = fmaxf(mx, pm[(g * 4 + t) * 64 + col]);
      sm += ps[(g * 4 + t) * 64 + col];
    }
    long bn = (r0 >> 4) + g;
    out[bn * 512 + c0 + col] = mx;
    out[bn * 512 + 256 + c0 + col] = sm * (1.f / 16.f);
  } else if (EPI == 6) {
#pragma unroll
    for (int i = 0; i < 4; i++) {
      long r = r0 + ty * 4 + i;
      __hip_bfloat162 p0, p1;
      p0.x = __float2bfloat16(acc[i][0]);
      p0.y = __float2bfloat16(acc[i][1]);
      p1.x = __float2bfloat16(acc[i][2]);
      p1.y = __float2bfloat16(acc[i][3]);
      __hip_bfloat162* dst = reinterpret_cast<__hip_bfloat162*>(&obf[r * CO + c0 + tx * 4]);
      dst[0] = p0;
      dst[1] = p1;
    }
  }
}

// ------- MFMA flash attention: (b,h) x 64-row Q tile, 4 waves x 16 rows -----
// QK^T and PV via v_mfma_f32_16x16x32_bf16; softmax f32.
// A-frag (16xK tile, row-major src): lane l -> [l&15][(l>>4)*8 + j]
// C/D frag: col = lane&15, row = (lane>>4)*4 + reg.
__global__ __launch_bounds__(256) void flash_mfma_kernel(const float* __restrict__ Q,
                                                         const float* __restrict__ Kb,
                                                         const float* __restrict__ Vb,
                                                         float* __restrict__ O) {
  __shared__ unsigned short Ks[32 * 72];
  __shared__ unsigned short Vs[32 * 72];
  __shared__ unsigned short Ps[4][16 * 40];
  int tid = threadIdx.x;
  int lane = tid & 63, w = tid >> 6;
  int bh = blockIdx.x >> 6;
  int qt = blockIdx.x & 63;
  long base = (long)bh * 4096 * 64;
  int row0 = qt * 64 + w * 16;
  int fr = lane & 15;         // frag row/col index
  int fk = (lane >> 4) * 8;   // frag k base

  // Q A-frags: aq[kk] = Q[row0+fr][kk*32 + fk + j]
  bf16x8 aq[2];
#pragma unroll
  for (int kk = 0; kk < 2; kk++) {
    const float* qp = &Q[base + (long)(row0 + fr) * 64 + kk * 32 + fk];
#pragma unroll
    for (int j = 0; j < 8; j++) aq[kk][j] = (__bf16)qp[j];
  }

  f32x4 o[4];
#pragma unroll
  for (int i = 0; i < 4; i++) o[i] = (f32x4){0.f, 0.f, 0.f, 0.f};
  float m_run[4], l_run[4];
#pragma unroll
  for (int r = 0; r < 4; r++) { m_run[r] = -3.0e38f; l_run[r] = 0.f; }

  int skey = tid >> 3, sdc = (tid & 7) * 8;
  for (int m0 = 0; m0 < 4096; m0 += 32) {
    __syncthreads();
    {  // stage K,V tile (32x64) as bf16, row stride 72
      const float* kp = &Kb[base + (long)(m0 + skey) * 64 + sdc];
      const float* vp = &Vb[base + (long)(m0 + skey) * 64 + sdc];
      union { unsigned short u[8]; uint4 v; } pk, pv;
#pragma unroll
      for (int j = 0; j < 8; j++) {
        pk.u[j] = __bfloat16_as_ushort(__float2bfloat16(kp[j]));
        pv.u[j] = __bfloat16_as_ushort(__float2bfloat16(vp[j]));
      }
      *reinterpret_cast<uint4*>(&Ks[skey * 72 + sdc]) = pk.v;
      *reinterpret_cast<uint4*>(&Vs[skey * 72 + sdc]) = pv.v;
    }
    __syncthreads();

    // S = Q.K^T : 2 n-tiles x 2 k-chunks
    f32x4 s[2];
#pragma unroll
    for (int n = 0; n < 2; n++) {
      s[n] = (f32x4){0.f, 0.f, 0.f, 0.f};
#pragma unroll
      for (int kk = 0; kk < 2; kk++) {
        bf16x8 bk = *reinterpret_cast<const bf16x8*>(&Ks[(n * 16 + fr) * 72 + kk * 32 + fk]);
        s[n] = __builtin_amdgcn_mfma_f32_16x16x32_bf16(aq[kk], bk, s[n], 0, 0, 0);
      }
    }

    // online softmax (rows live on 16-lane groups; butterfly over low 4 bits)
    float p0[4], p1[4];
#pragma unroll
    for (int r = 0; r < 4; r++) {
      float sv0 = s[0][r] * 0.125f;
      float sv1 = s[1][r] * 0.125f;
      float mx = fmaxf(sv0, sv1);
      mx = fmaxf(mx, __shfl_xor(mx, 1));
      mx = fmaxf(mx, __shfl_xor(mx, 2));
      mx = fmaxf(mx, __shfl_xor(mx, 4));
      mx = fmaxf(mx, __shfl_xor(mx, 8));
      float mn = fmaxf(m_run[r], mx);
      float fac = __expf(m_run[r] - mn);
      p0[r] = __expf(sv0 - mn);
      p1[r] = __expf(sv1 - mn);
      float rs = p0[r] + p1[r];
      rs += __shfl_xor(rs, 1);
      rs += __shfl_xor(rs, 2);
      rs += __shfl_xor(rs, 4);
      rs += __shfl_xor(rs, 8);
      l_run[r] = l_run[r] * fac + rs;
      m_run[r] = mn;
#pragma unroll
      for (int n2 = 0; n2 < 4; n2++) o[n2][r] *= fac;
    }

    // P -> per-wave LDS scratch (row-major 16x32, stride 40) -> A-frag
    unsigned short* pw = &Ps[w][0];
#pragma unroll
    for (int r = 0; r < 4; r++) {
      int prow = (lane >> 4) * 4 + r;
      pw[prow * 40 + fr] = __bfloat16_as_ushort(__float2bfloat16(p0[r]));
      pw[prow * 40 + 16 + fr] = __bfloat16_as_ushort(__float2bfloat16(p1[r]));
    }
    bf16x8 ap = *reinterpret_cast<const bf16x8*>(&pw[fr * 40 + fk]);

    // O += P.V : 4 d-tiles, K=32
#pragma unroll
    for (int n2 = 0; n2 < 4; n2++) {
      bf16x8 bv;
#pragma unroll
      for (int j = 0; j < 8; j++)
        bv[j] = __ushort_as_bfloat16(Vs[(fk + j) * 72 + n2 * 16 + fr]);
      o[n2] = __builtin_amdgcn_mfma_f32_16x16x32_bf16(ap, bv, o[n2], 0, 0, 0);
    }
  }

  // epilogue: O/l, scatter to (b, n, h*64+d)
  int b = bh >> 2, h = bh & 3;
#pragma unroll
  for (int r = 0; r < 4; r++) {
    float inv = 1.f / l_run[r];
    long nrow = (long)(b * 4096 + qt * 64 + w * 16 + (lane >> 4) * 4 + r);
#pragma unroll
    for (int n2 = 0; n2 < 4; n2++) {
      O[nrow * 256 + h * 64 + n2 * 16 + fr] = o[n2][r] * inv;
    }
  }
}

// ------------- LayerNorm over 512 (one row per block) -----------------------
__global__ __launch_bounds__(256) void ln_kernel(float* __restrict__ y,
                                                 const float* __restrict__ lng,
                                                 const float* __restrict__ lnb) {
  long r = blockIdx.x;
  int tid = threadIdx.x;
  float v0 = y[r * 512 + tid];
  float v1 = y[r * 512 + 256 + tid];
  float s = v0 + v1;
  float q = v0 * v0 + v1 * v1;
#pragma unroll
  for (int off = 1; off < 64; off <<= 1) {
    s += __shfl_xor(s, off);
    q += __shfl_xor(q, off);
  }
  __shared__ float red[8];
  __shared__ float mv[2];
  int w = tid >> 6;
  if ((tid & 63) == 0) { red[w] = s; red[4 + w] = q; }
  __syncthreads();
  if (tid == 0) {
    float S = red[0] + red[1] + red[2] + red[3];
    float Q2 = red[4] + red[5] + red[6] + red[7];
    float mu = S * (1.f / 512.f);
    float var = Q2 * (1.f / 512.f) - mu * mu;
    mv[0] = mu;
    mv[1] = rsqrtf(var + 1e-5f);
  }
  __syncthreads();
  float mu = mv[0], rstd = mv[1];
  y[r * 512 + tid] = (v0 - mu) * rstd * lng[tid] + lnb[tid];
  y[r * 512 + 256 + tid] = (v1 - mu) * rstd * lng[256 + tid] + lnb[256 + tid];
}

// ------------- output 0: pos1 passthrough, f32 -> f32 ------------------------
__global__ void poscopy_kernel(const float* __restrict__ p, float* __restrict__ o) {
  int i = blockIdx.x * 256 + threadIdx.x;
  o[i] = p[i];
}

extern "C" void kernel_launch(void* const* d_in, const int* in_sizes, int n_in,
                              void* d_out, int out_size, void* d_ws, size_t ws_size,
                              hipStream_t stream) {
  (void)in_sizes; (void)n_in; (void)out_size; (void)ws_size;
  const float* pos1 = (const float*)d_in[0];
  const float* pos2 = (const float*)d_in[1];
  const float* f1 = (const float*)d_in[2];
  const float* f2 = (const float*)d_in[3];
  const float* w0 = (const float*)d_in[4];
  const float* g0 = (const float*)d_in[5];
  const float* b0 = (const float*)d_in[6];
  const float* w1 = (const float*)d_in[7];
  const float* g1 = (const float*)d_in[8];
  const float* b1 = (const float*)d_in[9];
  const float* w2 = (const float*)d_in[10];
  const float* g2 = (const float*)d_in[11];
  const float* b2 = (const float*)d_in[12];
  const float* qw = (const float*)d_in[13];
  const float* qb = (const float*)d_in[14];
  const float* kw = (const float*)d_in[15];
  const float* kb = (const float*)d_in[16];
  const float* vw = (const float*)d_in[17];
  const float* vb = (const float*)d_in[18];
  const float* ow = (const float*)d_in[19];
  const float* obv = (const float*)d_in[20];
  const float* lng = (const float*)d_in[21];
  const float* lnb = (const float*)d_in[22];
  const float* fw = (const float*)d_in[23];
  const float* fb = (const float*)d_in[24];

  char* ws = (char*)d_ws;
  __hip_bfloat16* z1b = (__hip_bfloat16*)(ws);
  float* Qb = (float*)(ws);
  float* Kbuf = (float*)(ws + (8ull << 20));
  float* Vbuf = (float*)(ws + (16ull << 20));
  float* attno = (float*)(ws + (24ull << 20));
  float* y0 = (float*)(ws);
  int* idx = (int*)(ws + (32ull << 20));
  float* A1 = (float*)(ws + (33ull << 20));
  float* A2 = (float*)(ws + (37ull << 20));
  float* feat = (float*)(ws + (32ull << 20));
  char* statp = ws + (48ull << 20);
  float* pd = (float*)(ws + (56ull << 20));
  int* pi = (int*)(ws + (64ull << 20));
  double* st0 = (double*)(statp);
  double* st1 = (double*)(statp + 2048);
  double* st2 = (double*)(statp + 4096);
  float* sc0 = (float*)(statp + 8192);
  float* sh0 = (float*)(statp + 8704);
  float* sc1 = (float*)(statp + 9216);
  float* sh1 = (float*)(statp + 9728);
  float* sc2 = (float*)(statp + 10240);
  float* sh2 = (float*)(statp + 11264);

  float* out0 = (float*)d_out;
  float* out1 = out0 + 24576;

  hipMemsetAsync(statp, 0, 8192, stream);

  knn_part_kernel<<<dim3(32, 16), 256, 0, stream>>>(pos1, pos2, pd, pi);
  knn_merge_kernel<<<32, 256, 0, stream>>>(pd, pi, idx);
  g131_kernel<<<512, 128, 0, stream>>>(pos2, f2, w0, A2, 1.f, 3);
  g131_kernel<<<512, 128, 0, stream>>>(pos1, f1, w0, A1, -1.f, 131);
  z0stats_kernel<<<256, 256, 0, stream>>>(idx, A1, A2, st0);
  bnfin_kernel<<<1, 256, 0, stream>>>(st0, g0, b0, sc0, sh0, 128, 1.0 / 131072.0);
  gemm_kernel<6, 3, true><<<dim3(2, 2048), 256, 0, stream>>>(
      A2, w1, nullptr, 128, 128, nullptr, sc0, sh0, nullptr, z1b, A1, idx, nullptr);
  statsb_kernel<<<512, 256, 0, stream>>>(z1b, 131072L, st1);
  bnfin_kernel<<<1, 256, 0, stream>>>(st1, g1, b1, sc1, sh1, 128, 1.0 / 131072.0);
  gemm_kernel<4, 2, true><<<dim3(4, 2048), 256, 0, stream>>>(
      z1b, w2, nullptr, 128, 256, nullptr, sc1, sh1, nullptr, nullptr, nullptr, nullptr, st2);
  bnfin_kernel<<<1, 256, 0, stream>>>(st2, g2, b2, sc2, sh2, 256, 1.0 / 131072.0);
  gemm_kernel<5, 2, true><<<dim3(4, 2048), 256, 0, stream>>>(
      z1b, w2, feat, 128, 256, sc2, sc1, sh1, sh2, nullptr, nullptr, nullptr, nullptr);
  gemm_kernel<1, 0, false><<<dim3(4, 128), 256, 0, stream>>>(
      feat, qw, Qb, 512, 256, qb, nullptr, nullptr, nullptr, nullptr, nullptr, nullptr, nullptr);
  gemm_kernel<1, 1, false><<<dim3(4, 128), 256, 0, stream>>>(
      f2, kw, Kbuf, 128, 256, kb, nullptr, nullptr, nullptr, nullptr, nullptr, nullptr, nullptr);
  gemm_kernel<1, 1, false><<<dim3(4, 128), 256, 0, stream>>>(
      f2, vw, Vbuf, 128, 256, vb, nullptr, nullptr, nullptr, nullptr, nullptr, nullptr, nullptr);
  flash_mfma_kernel<<<512, 256, 0, stream>>>(Qb, Kbuf, Vbuf, attno);
  gemm_kernel<2, 0, false><<<dim3(8, 128), 256, 0, stream>>>(
      attno, ow, y0, 256, 512, obv, nullptr, nullptr, feat, nullptr, nullptr, nullptr, nullptr);
  ln_kernel<<<8192, 256, 0, stream>>>(y0, lng, lnb);
  gemm_kernel<3, 0, false><<<dim3(4, 128), 256, 0, stream>>>(
      y0, fw, out1, 512, 256, fb, nullptr, nullptr, nullptr, nullptr, nullptr, nullptr, nullptr);
  poscopy_kernel<<<96, 256, 0, stream>>>(pos1, out0);
}

// Round 19
// 1147.640 us; speedup vs baseline: 2.5185x; 1.0598x over previous
//
#include <hip/hip_runtime.h>
#include <hip/hip_bf16.h>

constexpr int B_ = 2, N_ = 4096, M_ = 4096, C_ = 128;

typedef __attribute__((ext_vector_type(8))) __bf16 bf16x8;
typedef __attribute__((ext_vector_type(4))) float f32x4;

// ---- KNN phase 1: per-(query, 256-candidate segment) register top-16 -------
// (R17 exact version — known-good selection)
__global__ __launch_bounds__(256) void knn_part_kernel(const float* __restrict__ pos1,
                                                       const float* __restrict__ pos2,
                                                       float* __restrict__ pd,
                                                       int* __restrict__ pi) {
  __shared__ float tX[256], tY[256], tZ[256], tS[256];
  int tid = threadIdx.x;
  int bn = blockIdx.x * 256 + tid;
  int b = bn >> 12, n = bn & 4095;
  int seg = blockIdx.y;
  const float* p1 = pos1 + (long)b * 3 * N_;
  float qx = p1[n], qy = p1[N_ + n], qz = p1[2 * N_ + n];
  float s1 = __fadd_rn(__fadd_rn(__fmul_rn(qx, qx), __fmul_rn(qy, qy)), __fmul_rn(qz, qz));
  const float* p2 = pos2 + (long)b * 3 * M_ + seg * 256;
  {
    float x = p2[tid], y = p2[M_ + tid], z = p2[2 * M_ + tid];
    tX[tid] = x; tY[tid] = y; tZ[tid] = z;
    tS[tid] = __fadd_rn(__fadd_rn(__fmul_rn(x, x), __fmul_rn(y, y)), __fmul_rn(z, z));
  }
  __syncthreads();
  float rd[16]; int ri[16];
#pragma unroll
  for (int k = 0; k < 16; k++) { rd[k] = 3.0e38f; ri[k] = 0; }
  for (int mm = 0; mm < 256; mm++) {
    float e = __fmaf_rn(qz, tZ[mm], __fmaf_rn(qy, tY[mm], __fmul_rn(qx, tX[mm])));
    float d = __fadd_rn(__fsub_rn(s1, __fadd_rn(e, e)), tS[mm]);
    if (d < rd[15]) {
      float cd = d; int ci = seg * 256 + mm;
#pragma unroll
      for (int k = 0; k < 16; k++) {
        bool lt = cd < rd[k];
        float td = lt ? rd[k] : cd;
        int ti = lt ? ri[k] : ci;
        rd[k] = lt ? cd : rd[k];
        ri[k] = lt ? ci : ri[k];
        cd = td; ci = ti;
      }
    }
  }
  long base = (long)seg * 16 * 8192 + bn;
#pragma unroll
  for (int k = 0; k < 16; k++) {
    pd[base + (long)k * 8192] = rd[k];
    pi[base + (long)k * 8192] = ri[k];
  }
}

// ---- KNN phase 2: merge 16 sorted lists of 16 per query (R17 exact) --------
__global__ __launch_bounds__(256) void knn_merge_kernel(const float* __restrict__ pd,
                                                        const int* __restrict__ pi,
                                                        int* __restrict__ idx) {
  int bn = blockIdx.x * 256 + threadIdx.x;
  float rd[16]; int ri[16];
#pragma unroll
  for (int k = 0; k < 16; k++) { rd[k] = 3.0e38f; ri[k] = 0; }
  for (int seg = 0; seg < 16; seg++) {
    for (int k = 0; k < 16; k++) {
      float d = pd[((long)seg * 16 + k) * 8192 + bn];
      if (d >= rd[15]) break;
      int ci = pi[((long)seg * 16 + k) * 8192 + bn];
      float cd = d;
#pragma unroll
      for (int j = 0; j < 16; j++) {
        bool lt = cd < rd[j];
        float td = lt ? rd[j] : cd;
        int ti = lt ? ri[j] : ci;
        rd[j] = lt ? cd : rd[j];
        ri[j] = lt ? ci : ri[j];
        cd = td; ci = ti;
      }
    }
  }
#pragma unroll
  for (int k = 0; k < 16; k++) idx[(long)bn * 16 + k] = ri[k];
}

// ------------- layer0 decomposition: 131-wide GEMM over points --------------
__global__ __launch_bounds__(128) void g131_kernel(const float* __restrict__ pos,
                                                   const float* __restrict__ feat,
                                                   const float* __restrict__ w0,
                                                   float* __restrict__ out,
                                                   float sign, int woff) {
  __shared__ float Xs[131 * 16];
  int tid = threadIdx.x;
  long b = blockIdx.x >> 8;
  int i0 = (blockIdx.x & 255) * 16;
  for (int e = tid; e < 131 * 16; e += 128) {
    int r = e & 15, c = e >> 4;
    float v = (c < 3) ? sign * pos[b * 3 * N_ + (long)c * N_ + i0 + r]
                      : feat[b * C_ * N_ + (long)(c - 3) * N_ + i0 + r];
    Xs[c * 16 + r] = v;
  }
  __syncthreads();
  int o = tid;
  float acc[16];
#pragma unroll
  for (int r = 0; r < 16; r++) acc[r] = 0.f;
  for (int c = 0; c < 131; c++) {
    float wv = w0[(long)o * 259 + (c < 3 ? c : (woff + c - 3))];
    const float* xr = &Xs[c * 16];
#pragma unroll
    for (int r = 0; r < 16; r++) acc[r] = fmaf(xr[r], wv, acc[r]);
  }
#pragma unroll
  for (int r = 0; r < 16; r++) out[((b << 12) + i0 + r) * 128 + o] = acc[r];
}

// ------------- BN0 stats from (idx, A1, A2), no z0 store --------------------
__global__ __launch_bounds__(256) void z0stats_kernel(const int* __restrict__ idx,
                                                      const float* __restrict__ A1,
                                                      const float* __restrict__ A2,
                                                      double* __restrict__ st) {
  int tid = threadIdx.x;
  int o = tid & 127, half = tid >> 7;
  float sum = 0.f, sq = 0.f;
  int g0 = blockIdx.x * 32;
  for (int gi = 0; gi < 32; gi++) {
    int bn = g0 + gi;
    long b = bn >> 12;
    float a1 = A1[(long)bn * 128 + o];
    for (int k = half; k < 16; k += 2) {
      int m = idx[bn * 16 + k];
      float v = A2[(b * 4096 + m) * 128 + o] + a1;
      sum += v;
      sq += v * v;
    }
  }
  __shared__ float ls[256], lq[256];
  ls[tid] = sum; lq[tid] = sq;
  __syncthreads();
  if (tid < 128) {
    atomicAdd(&st[o], (double)(ls[tid] + ls[tid + 128]));
    atomicAdd(&st[128 + o], (double)(lq[tid] + lq[tid + 128]));
  }
}

// ------------- per-channel stats over bf16 (nrows x 128) --------------------
__global__ __launch_bounds__(256) void statsb_kernel(const __hip_bfloat16* __restrict__ Z,
                                                     long nrows, double* __restrict__ st) {
  int tid = threadIdx.x;
  int c = tid & 127, sub = tid >> 7;
  long slot = (long)blockIdx.x * 2 + sub;
  long stride = (long)gridDim.x * 2;
  float sum = 0.f, sq = 0.f;
  for (long r = slot; r < nrows; r += stride) {
    float v = __bfloat162float(Z[r * 128 + c]);
    sum += v;
    sq += v * v;
  }
  __shared__ float ls[256], lq[256];
  ls[tid] = sum; lq[tid] = sq;
  __syncthreads();
  if (tid < 128) {
    atomicAdd(&st[c], (double)(ls[tid] + ls[tid + 128]));
    atomicAdd(&st[128 + c], (double)(lq[tid] + lq[tid + 128]));
  }
}

// ------------- BN finalize: fold mean/var/g/b into scale+shift --------------
__global__ void bnfin_kernel(const double* __restrict__ st, const float* __restrict__ g,
                             const float* __restrict__ bb, float* __restrict__ sc,
                             float* __restrict__ sh, int CO, double inv) {
  int c = threadIdx.x;
  if (c < CO) {
    double mu = st[c] * inv;
    double var = st[CO + c] * inv - mu * mu;
    double rstd = 1.0 / sqrt(var + 1e-5);
    double scv = (double)g[c] * rstd;
    sc[c] = (float)scv;
    sh[c] = (float)((double)bb[c] - mu * scv);
  }
}

// ------------- tiled GEMM: out = act(X) * W^T (+epilogues), f32 accum -------
template <int EPI, int XM, bool BN>
__global__ __launch_bounds__(256) void gemm_kernel(
    const void* __restrict__ Xv, const float* __restrict__ W, float* __restrict__ out,
    int K, int CO, const float* __restrict__ bias, const float* __restrict__ sc,
    const float* __restrict__ sh, const float* __restrict__ res,
    __hip_bfloat16* __restrict__ obf, const float* __restrict__ A1,
    const int* __restrict__ idxp, double* __restrict__ st) {
  __shared__ float S[2][32 * 68];
  int tid = threadIdx.x;
  int tx = tid & 15, ty = tid >> 4;
  int cb = blockIdx.x;
  long r0 = (long)blockIdx.y * 64;
  int c0 = cb * 64;
  float acc[4][4];
#pragma unroll
  for (int i = 0; i < 4; i++)
#pragma unroll
    for (int j = 0; j < 4; j++) acc[i][j] = 0.f;

  for (int k0 = 0; k0 < K; k0 += 32) {
    if (XM != 1) {
      int c = tid & 31, rr = tid >> 5;
      float scv = 0.f, shv = 0.f;
      if (BN) { scv = sc[k0 + c]; shv = sh[k0 + c]; }
#pragma unroll
      for (int i = 0; i < 8; i++) {
        int r = rr + i * 8;
        long g = r0 + r;
        float v;
        if (XM == 0) {
          v = ((const float*)Xv)[g * K + k0 + c];
        } else if (XM == 2) {
          v = __bfloat162float(((const __hip_bfloat16*)Xv)[g * K + k0 + c]);
        } else {
          const float* A2 = (const float*)Xv;
          int m = idxp[g];
          v = A2[(((g >> 16) << 12) + m) * 128 + k0 + c] + A1[(g >> 4) * 128 + k0 + c];
        }
        if (BN) v = fmaxf(0.f, fmaf(v, scv, shv));
        S[0][c * 68 + r] = v;
      }
    } else {
      int m = tid & 63, cc = tid >> 6;
      long b = r0 >> 12;
      long mg = (r0 & 4095) + m;
#pragma unroll
      for (int i = 0; i < 8; i++) {
        int c = cc + i * 4;
        S[0][c * 68 + m] = ((const float*)Xv)[(b * K + k0 + c) * 4096 + mg];
      }
    }
    {
      int c = tid & 31, oo = tid >> 5;
#pragma unroll
      for (int i = 0; i < 8; i++) {
        int o = oo + i * 8;
        S[1][c * 68 + o] = W[(long)(c0 + o) * K + k0 + c];
      }
    }
    __syncthreads();
#pragma unroll
    for (int kk = 0; kk < 32; kk++) {
      float4 a = *reinterpret_cast<const float4*>(&S[0][kk * 68 + ty * 4]);
      float4 bv = *reinterpret_cast<const float4*>(&S[1][kk * 68 + tx * 4]);
      float av[4] = {a.x, a.y, a.z, a.w};
      float bw[4] = {bv.x, bv.y, bv.z, bv.w};
#pragma unroll
      for (int i = 0; i < 4; i++)
#pragma unroll
        for (int j = 0; j < 4; j++) acc[i][j] = fmaf(av[i], bw[j], acc[i][j]);
    }
    __syncthreads();
  }

  if (EPI == 1) {
    long b = r0 >> 12;
    long nn = (r0 & 4095) + ty * 4;
    const float4 b4 = *reinterpret_cast<const float4*>(&bias[c0 + tx * 4]);
    float* Ob = out + ((b * (CO >> 6) + cb) * 4096L) * 64;
#pragma unroll
    for (int i = 0; i < 4; i++) {
      float4 o4 = make_float4(acc[i][0] + b4.x, acc[i][1] + b4.y, acc[i][2] + b4.z,
                              acc[i][3] + b4.w);
      *reinterpret_cast<float4*>(&Ob[(nn + i) * 64 + tx * 4]) = o4;
    }
  } else if (EPI == 2) {
    const float4 b4 = *reinterpret_cast<const float4*>(&bias[c0 + tx * 4]);
#pragma unroll
    for (int i = 0; i < 4; i++) {
      long r = r0 + ty * 4 + i;
      float4 f4 = *reinterpret_cast<const float4*>(&res[r * CO + c0 + tx * 4]);
      float4 o4 = make_float4(acc[i][0] + b4.x + f4.x, acc[i][1] + b4.y + f4.y,
                              acc[i][2] + b4.z + f4.z, acc[i][3] + b4.w + f4.w);
      *reinterpret_cast<float4*>(&out[r * CO + c0 + tx * 4]) = o4;
    }
  } else if (EPI == 3) {
    float* Sf = &S[0][0];
#pragma unroll
    for (int j = 0; j < 4; j++) {
      float bj = bias[c0 + tx * 4 + j];
      float4 colv = make_float4(acc[0][j] + bj, acc[1][j] + bj, acc[2][j] + bj,
                                acc[3][j] + bj);
      *reinterpret_cast<float4*>(&Sf[(tx * 4 + j) * 68 + ty * 4]) = colv;
    }
    __syncthreads();
    long b = r0 >> 12;
    long n0 = (r0 & 4095);
    int n = tid & 63, oo = tid >> 6;
#pragma unroll
    for (int i = 0; i < 16; i++) {
      int o = oo + i * 4;
      out[(b * CO + c0 + o) * 4096L + n0 + n] = Sf[o * 68 + n];
    }
  } else if (EPI == 4) {
    float* rs = &S[0][0];
    float* rq = &S[0][1024];
#pragma unroll
    for (int j = 0; j < 4; j++) {
      float s = 0.f, q = 0.f;
#pragma unroll
      for (int i = 0; i < 4; i++) {
        s += acc[i][j];
        q += acc[i][j] * acc[i][j];
      }
      rs[ty * 64 + tx * 4 + j] = s;
      rq[ty * 64 + tx * 4 + j] = q;
    }
    __syncthreads();
    if (tid < 128) {
      int col = tid & 63;
      bool isq = tid >= 64;
      const float* src = isq ? rq : rs;
      float a = 0.f;
#pragma unroll
      for (int t = 0; t < 16; t++) a += src[t * 64 + col];
      atomicAdd(&st[(isq ? CO : 0) + c0 + col], (double)a);
    }
  } else if (EPI == 5) {
    float* pm = &S[0][0];
    float* ps = &S[0][1024];
#pragma unroll
    for (int j = 0; j < 4; j++) {
      int c = c0 + tx * 4 + j;
      float scv = bias[c];          // sc2
      float shv = res[c];           // sh2
      float mx = -1e30f, sm = 0.f;
#pragma unroll
      for (int i = 0; i < 4; i++) {
        float v = fmaxf(0.f, fmaf(acc[i][j], scv, shv));
        mx = fmaxf(mx, v);
        sm += v;
      }
      pm[ty * 64 + tx * 4 + j] = mx;
      ps[ty * 64 + tx * 4 + j] = sm;
    }
    __syncthreads();
    int g = tid >> 6, col = tid & 63;
    float mx = pm[(g * 4 + 0) * 64 + col];
    float sm = ps[(g * 4 + 0) * 64 + col];
#pragma unroll
    for (int t = 1; t < 4; t++) {
      mx = fmaxf(mx, pm[(g * 4 + t) * 64 + col]);
      sm += ps[(g * 4 + t) * 64 + col];
    }
    long bn = (r0 >> 4) + g;
    out[bn * 512 + c0 + col] = mx;
    out[bn * 512 + 256 + c0 + col] = sm * (1.f / 16.f);
  } else if (EPI == 6) {
#pragma unroll
    for (int i = 0; i < 4; i++) {
      long r = r0 + ty * 4 + i;
      __hip_bfloat162 p0, p1;
      p0.x = __float2bfloat16(acc[i][0]);
      p0.y = __float2bfloat16(acc[i][1]);
      p1.x = __float2bfloat16(acc[i][2]);
      p1.y = __float2bfloat16(acc[i][3]);
      __hip_bfloat162* dst = reinterpret_cast<__hip_bfloat162*>(&obf[r * CO + c0 + tx * 4]);
      dst[0] = p0;
      dst[1] = p1;
    }
  }
}

// ------- MFMA flash attention: 64-key tiles, V transposed+swizzled ----------
__global__ __launch_bounds__(256) void flash_mfma_kernel(const float* __restrict__ Q,
                                                         const float* __restrict__ Kb,
                                                         const float* __restrict__ Vb,
                                                         float* __restrict__ O) {
  __shared__ unsigned short Ks[64 * 72];
  __shared__ unsigned short Vt[64 * 72];
  __shared__ unsigned short Ps[4][16 * 72];
  int tid = threadIdx.x;
  int lane = tid & 63, w = tid >> 6;
  int bh = blockIdx.x >> 6;
  int qt = blockIdx.x & 63;
  long base = (long)bh * 4096 * 64;
  int row0 = qt * 64 + w * 16;
  int fr = lane & 15;
  int fk = (lane >> 4) * 8;

  bf16x8 aq[2];
#pragma unroll
  for (int kk = 0; kk < 2; kk++) {
    const float* qp = &Q[base + (long)(row0 + fr) * 64 + kk * 32 + fk];
#pragma unroll
    for (int j = 0; j < 8; j++) aq[kk][j] = (__bf16)qp[j];
  }

  f32x4 o[4];
#pragma unroll
  for (int i = 0; i < 4; i++) o[i] = (f32x4){0.f, 0.f, 0.f, 0.f};
  float m_run[4], l_run[4];
#pragma unroll
  for (int r = 0; r < 4; r++) { m_run[r] = -3.0e38f; l_run[r] = 0.f; }

  int skey = tid >> 2, sdc = (tid & 3) * 16;
  int vd = tid & 63, vkg = tid >> 6;
  int vsw = (vd ^ (vd >> 3)) & 7;

  for (int m0 = 0; m0 < 4096; m0 += 64) {
    __syncthreads();
    {
      const float* kp = &Kb[base + (long)(m0 + skey) * 64 + sdc];
      union { unsigned short u[8]; uint4 v; } pk;
#pragma unroll
      for (int h = 0; h < 2; h++) {
#pragma unroll
        for (int j = 0; j < 8; j++)
          pk.u[j] = __bfloat16_as_ushort(__float2bfloat16(kp[h * 8 + j]));
        *reinterpret_cast<uint4*>(&Ks[skey * 72 + sdc + h * 8]) = pk.v;
      }
#pragma unroll
      for (int j = 0; j < 16; j++) {
        int k = vkg * 16 + j;
        float v = Vb[base + (long)(m0 + k) * 64 + vd];
        int kb = k >> 3, ko = k & 7;
        Vt[vd * 72 + ((kb ^ vsw) << 3) + ko] = __bfloat16_as_ushort(__float2bfloat16(v));
      }
    }
    __syncthreads();

    f32x4 s[4];
#pragma unroll
    for (int n = 0; n < 4; n++) {
      s[n] = (f32x4){0.f, 0.f, 0.f, 0.f};
#pragma unroll
      for (int kk = 0; kk < 2; kk++) {
        bf16x8 bk = *reinterpret_cast<const bf16x8*>(&Ks[(n * 16 + fr) * 72 + kk * 32 + fk]);
        s[n] = __builtin_amdgcn_mfma_f32_16x16x32_bf16(aq[kk], bk, s[n], 0, 0, 0);
      }
    }

    float p[4][4];
#pragma unroll
    for (int r = 0; r < 4; r++) {
      float sv0 = s[0][r] * 0.125f, sv1 = s[1][r] * 0.125f;
      float sv2 = s[2][r] * 0.125f, sv3 = s[3][r] * 0.125f;
      float mx = fmaxf(fmaxf(sv0, sv1), fmaxf(sv2, sv3));
      mx = fmaxf(mx, __shfl_xor(mx, 1));
      mx = fmaxf(mx, __shfl_xor(mx, 2));
      mx = fmaxf(mx, __shfl_xor(mx, 4));
      mx = fmaxf(mx, __shfl_xor(mx, 8));
      float mn = fmaxf(m_run[r], mx);
      float fac = __expf(m_run[r] - mn);
      p[0][r] = __expf(sv0 - mn);
      p[1][r] = __expf(sv1 - mn);
      p[2][r] = __expf(sv2 - mn);
      p[3][r] = __expf(sv3 - mn);
      float rs = (p[0][r] + p[1][r]) + (p[2][r] + p[3][r]);
      rs += __shfl_xor(rs, 1);
      rs += __shfl_xor(rs, 2);
      rs += __shfl_xor(rs, 4);
      rs += __shfl_xor(rs, 8);
      l_run[r] = l_run[r] * fac + rs;
      m_run[r] = mn;
#pragma unroll
      for (int n2 = 0; n2 < 4; n2++) o[n2][r] *= fac;
    }

    unsigned short* pw = &Ps[w][0];
#pragma unroll
    for (int r = 0; r < 4; r++) {
      int prow = (lane >> 4) * 4 + r;
#pragma unroll
      for (int n = 0; n < 4; n++)
        pw[prow * 72 + n * 16 + fr] = __bfloat16_as_ushort(__float2bfloat16(p[n][r]));
    }
    bf16x8 ap[2];
#pragma unroll
    for (int kk = 0; kk < 2; kk++)
      ap[kk] = *reinterpret_cast<const bf16x8*>(&pw[fr * 72 + kk * 32 + fk]);

#pragma unroll
    for (int n2 = 0; n2 < 4; n2++) {
      int d = n2 * 16 + fr;
      int dsw = (d ^ (d >> 3)) & 7;
#pragma unroll
      for (int kk = 0; kk < 2; kk++) {
        int kb = kk * 4 + (lane >> 4);
        bf16x8 bv = *reinterpret_cast<const bf16x8*>(&Vt[d * 72 + ((kb ^ dsw) << 3)]);
        o[n2] = __builtin_amdgcn_mfma_f32_16x16x32_bf16(ap[kk], bv, o[n2], 0, 0, 0);
      }
    }
  }

  int b = bh >> 2, h = bh & 3;
#pragma unroll
  for (int r = 0; r < 4; r++) {
    float inv = 1.f / l_run[r];
    long nrow = (long)(b * 4096 + qt * 64 + w * 16 + (lane >> 4) * 4 + r);
#pragma unroll
    for (int n2 = 0; n2 < 4; n2++) {
      O[nrow * 256 + h * 64 + n2 * 16 + fr] = o[n2][r] * inv;
    }
  }
}

// ------------- LayerNorm over 512 (one row per block) -----------------------
__global__ __launch_bounds__(256) void ln_kernel(float* __restrict__ y,
                                                 const float* __restrict__ lng,
                                                 const float* __restrict__ lnb) {
  long r = blockIdx.x;
  int tid = threadIdx.x;
  float v0 = y[r * 512 + tid];
  float v1 = y[r * 512 + 256 + tid];
  float s = v0 + v1;
  float q = v0 * v0 + v1 * v1;
#pragma unroll
  for (int off = 1; off < 64; off <<= 1) {
    s += __shfl_xor(s, off);
    q += __shfl_xor(q, off);
  }
  __shared__ float red[8];
  __shared__ float mv[2];
  int w = tid >> 6;
  if ((tid & 63) == 0) { red[w] = s; red[4 + w] = q; }
  __syncthreads();
  if (tid == 0) {
    float S = red[0] + red[1] + red[2] + red[3];
    float Q2 = red[4] + red[5] + red[6] + red[7];
    float mu = S * (1.f / 512.f);
    float var = Q2 * (1.f / 512.f) - mu * mu;
    mv[0] = mu;
    mv[1] = rsqrtf(var + 1e-5f);
  }
  __syncthreads();
  float mu = mv[0], rstd = mv[1];
  y[r * 512 + tid] = (v0 - mu) * rstd * lng[tid] + lnb[tid];
  y[r * 512 + 256 + tid] = (v1 - mu) * rstd * lng[256 + tid] + lnb[256 + tid];
}

// ------------- output 0: pos1 passthrough, f32 -> f32 ------------------------
__global__ void poscopy_kernel(const float* __restrict__ p, float* __restrict__ o) {
  int i = blockIdx.x * 256 + threadIdx.x;
  o[i] = p[i];
}

extern "C" void kernel_launch(void* const* d_in, const int* in_sizes, int n_in,
                              void* d_out, int out_size, void* d_ws, size_t ws_size,
                              hipStream_t stream) {
  (void)in_sizes; (void)n_in; (void)out_size; (void)ws_size;
  const float* pos1 = (const float*)d_in[0];
  const float* pos2 = (const float*)d_in[1];
  const float* f1 = (const float*)d_in[2];
  const float* f2 = (const float*)d_in[3];
  const float* w0 = (const float*)d_in[4];
  const float* g0 = (const float*)d_in[5];
  const float* b0 = (const float*)d_in[6];
  const float* w1 = (const float*)d_in[7];
  const float* g1 = (const float*)d_in[8];
  const float* b1 = (const float*)d_in[9];
  const float* w2 = (const float*)d_in[10];
  const float* g2 = (const float*)d_in[11];
  const float* b2 = (const float*)d_in[12];
  const float* qw = (const float*)d_in[13];
  const float* qb = (const float*)d_in[14];
  const float* kw = (const float*)d_in[15];
  const float* kb = (const float*)d_in[16];
  const float* vw = (const float*)d_in[17];
  const float* vb = (const float*)d_in[18];
  const float* ow = (const float*)d_in[19];
  const float* obv = (const float*)d_in[20];
  const float* lng = (const float*)d_in[21];
  const float* lnb = (const float*)d_in[22];
  const float* fw = (const float*)d_in[23];
  const float* fb = (const float*)d_in[24];

  // ws layout (within proven ≤72MB envelope):
  // [0,32) z1b/QKV/attno/y0 ; [32,48) idx+A1+A2 -> feat ; 48MB stats
  // [56,64) knn pd ; [64,72) knn pi
  char* ws = (char*)d_ws;
  __hip_bfloat16* z1b = (__hip_bfloat16*)(ws);
  float* Qb = (float*)(ws);
  float* Kbuf = (float*)(ws + (8ull << 20));
  float* Vbuf = (float*)(ws + (16ull << 20));
  float* attno = (float*)(ws + (24ull << 20));
  float* y0 = (float*)(ws);
  int* idx = (int*)(ws + (32ull << 20));
  float* A1 = (float*)(ws + (33ull << 20));
  float* A2 = (float*)(ws + (37ull << 20));
  float* feat = (float*)(ws + (32ull << 20));
  char* statp = ws + (48ull << 20);
  float* pd = (float*)(ws + (56ull << 20));
  int* pi = (int*)(ws + (64ull << 20));
  double* st0 = (double*)(statp);
  double* st1 = (double*)(statp + 2048);
  double* st2 = (double*)(statp + 4096);
  float* sc0 = (float*)(statp + 8192);
  float* sh0 = (float*)(statp + 8704);
  float* sc1 = (float*)(statp + 9216);
  float* sh1 = (float*)(statp + 9728);
  float* sc2 = (float*)(statp + 10240);
  float* sh2 = (float*)(statp + 11264);

  float* out0 = (float*)d_out;
  float* out1 = out0 + 24576;

  hipMemsetAsync(statp, 0, 8192, stream);

  knn_part_kernel<<<dim3(32, 16), 256, 0, stream>>>(pos1, pos2, pd, pi);
  knn_merge_kernel<<<32, 256, 0, stream>>>(pd, pi, idx);
  g131_kernel<<<512, 128, 0, stream>>>(pos2, f2, w0, A2, 1.f, 3);
  g131_kernel<<<512, 128, 0, stream>>>(pos1, f1, w0, A1, -1.f, 131);
  z0stats_kernel<<<256, 256, 0, stream>>>(idx, A1, A2, st0);
  bnfin_kernel<<<1, 256, 0, stream>>>(st0, g0, b0, sc0, sh0, 128, 1.0 / 131072.0);
  gemm_kernel<6, 3, true><<<dim3(2, 2048), 256, 0, stream>>>(
      A2, w1, nullptr, 128, 128, nullptr, sc0, sh0, nullptr, z1b, A1, idx, nullptr);
  statsb_kernel<<<512, 256, 0, stream>>>(z1b, 131072L, st1);
  bnfin_kernel<<<1, 256, 0, stream>>>(st1, g1, b1, sc1, sh1, 128, 1.0 / 131072.0);
  gemm_kernel<4, 2, true><<<dim3(4, 2048), 256, 0, stream>>>(
      z1b, w2, nullptr, 128, 256, nullptr, sc1, sh1, nullptr, nullptr, nullptr, nullptr, st2);
  bnfin_kernel<<<1, 256, 0, stream>>>(st2, g2, b2, sc2, sh2, 256, 1.0 / 131072.0);
  gemm_kernel<5, 2, true><<<dim3(4, 2048), 256, 0, stream>>>(
      z1b, w2, feat, 128, 256, sc2, sc1, sh1, sh2, nullptr, nullptr, nullptr, nullptr);
  gemm_kernel<1, 0, false><<<dim3(4, 128), 256, 0, stream>>>(
      feat, qw, Qb, 512, 256, qb, nullptr, nullptr, nullptr, nullptr, nullptr, nullptr, nullptr);
  gemm_kernel<1, 1, false><<<dim3(4, 128), 256, 0, stream>>>(
      f2, kw, Kbuf, 128, 256, kb, nullptr, nullptr, nullptr, nullptr, nullptr, nullptr, nullptr);
  gemm_kernel<1, 1, false><<<dim3(4, 128), 256, 0, stream>>>(
      f2, vw, Vbuf, 128, 256, vb, nullptr, nullptr, nullptr, nullptr, nullptr, nullptr, nullptr);
  flash_mfma_kernel<<<512, 256, 0, stream>>>(Qb, Kbuf, Vbuf, attno);
  gemm_kernel<2, 0, false><<<dim3(8, 128), 256, 0, stream>>>(
      attno, ow, y0, 256, 512, obv, nullptr, nullptr, feat, nullptr, nullptr, nullptr, nullptr);
  ln_kernel<<<8192, 256, 0, stream>>>(y0, lng, lnb);
  gemm_kernel<3, 0, false><<<dim3(4, 128), 256, 0, stream>>>(
      y0, fw, out1, 512, 256, fb, nullptr, nullptr, nullptr, nullptr, nullptr, nullptr, nullptr);
  poscopy_kernel<<<96, 256, 0, stream>>>(pos1, out0);
}

// Round 21
// 1013.221 us; speedup vs baseline: 2.8527x; 1.1327x over previous
//
#include <hip/hip_runtime.h>
#include <hip/hip_bf16.h>

constexpr int B_ = 2, N_ = 4096, M_ = 4096, C_ = 128;

typedef __attribute__((ext_vector_type(8))) __bf16 bf16x8;
typedef __attribute__((ext_vector_type(4))) float f32x4;

// ---- KNN phase 1: per-(query, 256-candidate segment) register top-16 -------
// FROZEN known-good version (R17/R19). Do not restructure.
__global__ __launch_bounds__(256) void knn_part_kernel(const float* __restrict__ pos1,
                                                       const float* __restrict__ pos2,
                                                       float* __restrict__ pd,
                                                       int* __restrict__ pi) {
  __shared__ float tX[256], tY[256], tZ[256], tS[256];
  int tid = threadIdx.x;
  int bn = blockIdx.x * 256 + tid;
  int b = bn >> 12, n = bn & 4095;
  int seg = blockIdx.y;
  const float* p1 = pos1 + (long)b * 3 * N_;
  float qx = p1[n], qy = p1[N_ + n], qz = p1[2 * N_ + n];
  float s1 = __fadd_rn(__fadd_rn(__fmul_rn(qx, qx), __fmul_rn(qy, qy)), __fmul_rn(qz, qz));
  const float* p2 = pos2 + (long)b * 3 * M_ + seg * 256;
  {
    float x = p2[tid], y = p2[M_ + tid], z = p2[2 * M_ + tid];
    tX[tid] = x; tY[tid] = y; tZ[tid] = z;
    tS[tid] = __fadd_rn(__fadd_rn(__fmul_rn(x, x), __fmul_rn(y, y)), __fmul_rn(z, z));
  }
  __syncthreads();
  float rd[16]; int ri[16];
#pragma unroll
  for (int k = 0; k < 16; k++) { rd[k] = 3.0e38f; ri[k] = 0; }
  for (int mm = 0; mm < 256; mm++) {
    float e = __fmaf_rn(qz, tZ[mm], __fmaf_rn(qy, tY[mm], __fmul_rn(qx, tX[mm])));
    float d = __fadd_rn(__fsub_rn(s1, __fadd_rn(e, e)), tS[mm]);
    if (d < rd[15]) {
      float cd = d; int ci = seg * 256 + mm;
#pragma unroll
      for (int k = 0; k < 16; k++) {
        bool lt = cd < rd[k];
        float td = lt ? rd[k] : cd;
        int ti = lt ? ri[k] : ci;
        rd[k] = lt ? cd : rd[k];
        ri[k] = lt ? ci : ri[k];
        cd = td; ci = ti;
      }
    }
  }
  long base = (long)seg * 16 * 8192 + bn;
#pragma unroll
  for (int k = 0; k < 16; k++) {
    pd[base + (long)k * 8192] = rd[k];
    pi[base + (long)k * 8192] = ri[k];
  }
}

// ---- KNN phase 2: merge 16 sorted lists of 16 per query (frozen) -----------
__global__ __launch_bounds__(256) void knn_merge_kernel(const float* __restrict__ pd,
                                                        const int* __restrict__ pi,
                                                        int* __restrict__ idx) {
  int bn = blockIdx.x * 256 + threadIdx.x;
  float rd[16]; int ri[16];
#pragma unroll
  for (int k = 0; k < 16; k++) { rd[k] = 3.0e38f; ri[k] = 0; }
  for (int seg = 0; seg < 16; seg++) {
    for (int k = 0; k < 16; k++) {
      float d = pd[((long)seg * 16 + k) * 8192 + bn];
      if (d >= rd[15]) break;
      int ci = pi[((long)seg * 16 + k) * 8192 + bn];
      float cd = d;
#pragma unroll
      for (int j = 0; j < 16; j++) {
        bool lt = cd < rd[j];
        float td = lt ? rd[j] : cd;
        int ti = lt ? ri[j] : ci;
        rd[j] = lt ? cd : rd[j];
        ri[j] = lt ? ci : ri[j];
        cd = td; ci = ti;
      }
    }
  }
#pragma unroll
  for (int k = 0; k < 16; k++) idx[(long)bn * 16 + k] = ri[k];
}

// ------------- layer0 decomposition: 131-wide GEMM over points --------------
__global__ __launch_bounds__(128) void g131_kernel(const float* __restrict__ pos,
                                                   const float* __restrict__ feat,
                                                   const float* __restrict__ w0,
                                                   float* __restrict__ out,
                                                   float sign, int woff) {
  __shared__ float Xs[131 * 16];
  int tid = threadIdx.x;
  long b = blockIdx.x >> 8;
  int i0 = (blockIdx.x & 255) * 16;
  for (int e = tid; e < 131 * 16; e += 128) {
    int r = e & 15, c = e >> 4;
    float v = (c < 3) ? sign * pos[b * 3 * N_ + (long)c * N_ + i0 + r]
                      : feat[b * C_ * N_ + (long)(c - 3) * N_ + i0 + r];
    Xs[c * 16 + r] = v;
  }
  __syncthreads();
  int o = tid;
  float acc[16];
#pragma unroll
  for (int r = 0; r < 16; r++) acc[r] = 0.f;
  for (int c = 0; c < 131; c++) {
    float wv = w0[(long)o * 259 + (c < 3 ? c : (woff + c - 3))];
    const float* xr = &Xs[c * 16];
#pragma unroll
    for (int r = 0; r < 16; r++) acc[r] = fmaf(xr[r], wv, acc[r]);
  }
#pragma unroll
  for (int r = 0; r < 16; r++) out[((b << 12) + i0 + r) * 128 + o] = acc[r];
}

// ------------- BN0 stats from (idx, A1, A2), no z0 store --------------------
__global__ __launch_bounds__(256) void z0stats_kernel(const int* __restrict__ idx,
                                                      const float* __restrict__ A1,
                                                      const float* __restrict__ A2,
                                                      double* __restrict__ st) {
  int tid = threadIdx.x;
  int o = tid & 127, half = tid >> 7;
  float sum = 0.f, sq = 0.f;
  int g0 = blockIdx.x * 32;
  for (int gi = 0; gi < 32; gi++) {
    int bn = g0 + gi;
    long b = bn >> 12;
    float a1 = A1[(long)bn * 128 + o];
    for (int k = half; k < 16; k += 2) {
      int m = idx[bn * 16 + k];
      float v = A2[(b * 4096 + m) * 128 + o] + a1;
      sum += v;
      sq += v * v;
    }
  }
  __shared__ float ls[256], lq[256];
  ls[tid] = sum; lq[tid] = sq;
  __syncthreads();
  if (tid < 128) {
    atomicAdd(&st[o], (double)(ls[tid] + ls[tid + 128]));
    atomicAdd(&st[128 + o], (double)(lq[tid] + lq[tid + 128]));
  }
}

// ------------- per-channel stats over bf16 (nrows x 128) --------------------
__global__ __launch_bounds__(256) void statsb_kernel(const __hip_bfloat16* __restrict__ Z,
                                                     long nrows, double* __restrict__ st) {
  int tid = threadIdx.x;
  int c = tid & 127, sub = tid >> 7;
  long slot = (long)blockIdx.x * 2 + sub;
  long stride = (long)gridDim.x * 2;
  float sum = 0.f, sq = 0.f;
  for (long r = slot; r < nrows; r += stride) {
    float v = __bfloat162float(Z[r * 128 + c]);
    sum += v;
    sq += v * v;
  }
  __shared__ float ls[256], lq[256];
  ls[tid] = sum; lq[tid] = sq;
  __syncthreads();
  if (tid < 128) {
    atomicAdd(&st[c], (double)(ls[tid] + ls[tid + 128]));
    atomicAdd(&st[128 + c], (double)(lq[tid] + lq[tid + 128]));
  }
}

// ------------- BN finalize: fold mean/var/g/b into scale+shift --------------
__global__ void bnfin_kernel(const double* __restrict__ st, const float* __restrict__ g,
                             const float* __restrict__ bb, float* __restrict__ sc,
                             float* __restrict__ sh, int CO, double inv) {
  int c = threadIdx.x;
  if (c < CO) {
    double mu = st[c] * inv;
    double var = st[CO + c] * inv - mu * mu;
    double rstd = 1.0 / sqrt(var + 1e-5);
    double scv = (double)g[c] * rstd;
    sc[c] = (float)scv;
    sh[c] = (float)((double)bb[c] - mu * scv);
  }
}

// ---- MFMA z2 pass: C = BN1ReLU(z1b) @ w2^T, 64x64 tile, 4 waves ------------
// EPI 4: raw-acc channel stats -> f64 atomics.  EPI 5: BN2ReLU + max/mean pool.
template <int EPI>
__global__ __launch_bounds__(256) void gemm2_mfma_kernel(
    const __hip_bfloat16* __restrict__ z1b, const float* __restrict__ w2,
    const float* __restrict__ sc1, const float* __restrict__ sh1,
    const float* __restrict__ sc2, const float* __restrict__ sh2,
    float* __restrict__ feat, double* __restrict__ st) {
  __shared__ unsigned short As[64 * 136];
  __shared__ unsigned short Bs[64 * 136];
  __shared__ float scs[128], shs[128];
  __shared__ float Sred[4 * 64], Qred[4 * 64];
  int tid = threadIdx.x;
  int lane = tid & 63, w = tid >> 6;
  int cb = blockIdx.x;
  long r0 = (long)blockIdx.y * 64;
  int c0 = cb * 64;
  if (tid < 128) { scs[tid] = sc1[tid]; shs[tid] = sh1[tid]; }
  __syncthreads();
  {  // stage A (BN1+relu, bf16) and B (w2 bf16)
    int row = tid >> 2, kb = (tid & 3) * 32;
    const __hip_bfloat16* zp = &z1b[(r0 + row) * 128 + kb];
    unsigned short* ap = &As[row * 136 + kb];
    const float* wp = &w2[(long)(c0 + row) * 128 + kb];
    unsigned short* bp = &Bs[row * 136 + kb];
#pragma unroll
    for (int h = 0; h < 4; h++) {
      union { unsigned short u[8]; uint4 v; } in, oa, ob;
      in.v = *reinterpret_cast<const uint4*>(zp + h * 8);
#pragma unroll
      for (int j = 0; j < 8; j++) {
        int k = kb + h * 8 + j;
        float f = __bfloat162float(__ushort_as_bfloat16(in.u[j]));
        float v = fmaxf(0.f, fmaf(f, scs[k], shs[k]));
        oa.u[j] = __bfloat16_as_ushort(__float2bfloat16(v));
        ob.u[j] = __bfloat16_as_ushort(__float2bfloat16(wp[h * 8 + j]));
      }
      *reinterpret_cast<uint4*>(ap + h * 8) = oa.v;
      *reinterpret_cast<uint4*>(bp + h * 8) = ob.v;
    }
  }
  __syncthreads();

  int fr = lane & 15, fk = (lane >> 4) * 8;
  bf16x8 a[4];
#pragma unroll
  for (int kk = 0; kk < 4; kk++)
    a[kk] = *reinterpret_cast<const bf16x8*>(&As[(w * 16 + fr) * 136 + kk * 32 + fk]);
  f32x4 acc[4];
#pragma unroll
  for (int n2 = 0; n2 < 4; n2++) {
    acc[n2] = (f32x4){0.f, 0.f, 0.f, 0.f};
#pragma unroll
    for (int kk = 0; kk < 4; kk++) {
      bf16x8 bfrag = *reinterpret_cast<const bf16x8*>(&Bs[(n2 * 16 + fr) * 136 + kk * 32 + fk]);
      acc[n2] = __builtin_amdgcn_mfma_f32_16x16x32_bf16(a[kk], bfrag, acc[n2], 0, 0, 0);
    }
  }

  if (EPI == 4) {
#pragma unroll
    for (int n2 = 0; n2 < 4; n2++) {
      float s = 0.f, q = 0.f;
#pragma unroll
      for (int r = 0; r < 4; r++) { s += acc[n2][r]; q += acc[n2][r] * acc[n2][r]; }
      s += __shfl_xor(s, 16); s += __shfl_xor(s, 32);
      q += __shfl_xor(q, 16); q += __shfl_xor(q, 32);
      if (lane < 16) { Sred[w * 64 + n2 * 16 + fr] = s; Qred[w * 64 + n2 * 16 + fr] = q; }
    }
    __syncthreads();
    if (tid < 64) {
      float S = Sred[tid] + Sred[64 + tid] + Sred[128 + tid] + Sred[192 + tid];
      float Q = Qred[tid] + Qred[64 + tid] + Qred[128 + tid] + Qred[192 + tid];
      atomicAdd(&st[c0 + tid], (double)S);
      atomicAdd(&st[256 + c0 + tid], (double)Q);
    }
  } else {
    int bn = (int)(r0 >> 4) + w;
#pragma unroll
    for (int n2 = 0; n2 < 4; n2++) {
      int c = c0 + n2 * 16 + fr;
      float scv = sc2[c], shv = sh2[c];
      float mx = -1e30f, sm = 0.f;
#pragma unroll
      for (int r = 0; r < 4; r++) {
        float v = fmaxf(0.f, fmaf(acc[n2][r], scv, shv));
        mx = fmaxf(mx, v);
        sm += v;
      }
      mx = fmaxf(mx, __shfl_xor(mx, 16)); mx = fmaxf(mx, __shfl_xor(mx, 32));
      sm += __shfl_xor(sm, 16); sm += __shfl_xor(sm, 32);
      if (lane < 16) {
        feat[(long)bn * 512 + c] = mx;
        feat[(long)bn * 512 + 256 + c] = sm * (1.f / 16.f);
      }
    }
  }
}

// ------------- tiled GEMM: out = act(X) * W^T (+epilogues), f32 accum -------
template <int EPI, int XM, bool BN>
__global__ __launch_bounds__(256) void gemm_kernel(
    const void* __restrict__ Xv, const float* __restrict__ W, float* __restrict__ out,
    int K, int CO, const float* __restrict__ bias, const float* __restrict__ sc,
    const float* __restrict__ sh, const float* __restrict__ res,
    __hip_bfloat16* __restrict__ obf, const float* __restrict__ A1,
    const int* __restrict__ idxp, double* __restrict__ st) {
  __shared__ float S[2][32 * 68];
  int tid = threadIdx.x;
  int tx = tid & 15, ty = tid >> 4;
  int cb = blockIdx.x;
  long r0 = (long)blockIdx.y * 64;
  int c0 = cb * 64;
  float acc[4][4];
#pragma unroll
  for (int i = 0; i < 4; i++)
#pragma unroll
    for (int j = 0; j < 4; j++) acc[i][j] = 0.f;

  for (int k0 = 0; k0 < K; k0 += 32) {
    if (XM != 1) {
      int c = tid & 31, rr = tid >> 5;
      float scv = 0.f, shv = 0.f;
      if (BN) { scv = sc[k0 + c]; shv = sh[k0 + c]; }
#pragma unroll
      for (int i = 0; i < 8; i++) {
        int r = rr + i * 8;
        long g = r0 + r;
        float v;
        if (XM == 0) {
          v = ((const float*)Xv)[g * K + k0 + c];
        } else if (XM == 2) {
          v = __bfloat162float(((const __hip_bfloat16*)Xv)[g * K + k0 + c]);
        } else {
          const float* A2 = (const float*)Xv;
          int m = idxp[g];
          v = A2[(((g >> 16) << 12) + m) * 128 + k0 + c] + A1[(g >> 4) * 128 + k0 + c];
        }
        if (BN) v = fmaxf(0.f, fmaf(v, scv, shv));
        S[0][c * 68 + r] = v;
      }
    } else {
      int m = tid & 63, cc = tid >> 6;
      long b = r0 >> 12;
      long mg = (r0 & 4095) + m;
#pragma unroll
      for (int i = 0; i < 8; i++) {
        int c = cc + i * 4;
        S[0][c * 68 + m] = ((const float*)Xv)[(b * K + k0 + c) * 4096 + mg];
      }
    }
    {
      int c = tid & 31, oo = tid >> 5;
#pragma unroll
      for (int i = 0; i < 8; i++) {
        int o = oo + i * 8;
        S[1][c * 68 + o] = W[(long)(c0 + o) * K + k0 + c];
      }
    }
    __syncthreads();
#pragma unroll
    for (int kk = 0; kk < 32; kk++) {
      float4 a = *reinterpret_cast<const float4*>(&S[0][kk * 68 + ty * 4]);
      float4 bv = *reinterpret_cast<const float4*>(&S[1][kk * 68 + tx * 4]);
      float av[4] = {a.x, a.y, a.z, a.w};
      float bw[4] = {bv.x, bv.y, bv.z, bv.w};
#pragma unroll
      for (int i = 0; i < 4; i++)
#pragma unroll
        for (int j = 0; j < 4; j++) acc[i][j] = fmaf(av[i], bw[j], acc[i][j]);
    }
    __syncthreads();
  }

  if (EPI == 1) {
    long b = r0 >> 12;
    long nn = (r0 & 4095) + ty * 4;
    const float4 b4 = *reinterpret_cast<const float4*>(&bias[c0 + tx * 4]);
    float* Ob = out + ((b * (CO >> 6) + cb) * 4096L) * 64;
#pragma unroll
    for (int i = 0; i < 4; i++) {
      float4 o4 = make_float4(acc[i][0] + b4.x, acc[i][1] + b4.y, acc[i][2] + b4.z,
                              acc[i][3] + b4.w);
      *reinterpret_cast<float4*>(&Ob[(nn + i) * 64 + tx * 4]) = o4;
    }
  } else if (EPI == 2) {
    const float4 b4 = *reinterpret_cast<const float4*>(&bias[c0 + tx * 4]);
#pragma unroll
    for (int i = 0; i < 4; i++) {
      long r = r0 + ty * 4 + i;
      float4 f4 = *reinterpret_cast<const float4*>(&res[r * CO + c0 + tx * 4]);
      float4 o4 = make_float4(acc[i][0] + b4.x + f4.x, acc[i][1] + b4.y + f4.y,
                              acc[i][2] + b4.z + f4.z, acc[i][3] + b4.w + f4.w);
      *reinterpret_cast<float4*>(&out[r * CO + c0 + tx * 4]) = o4;
    }
  } else if (EPI == 3) {
    float* Sf = &S[0][0];
#pragma unroll
    for (int j = 0; j < 4; j++) {
      float bj = bias[c0 + tx * 4 + j];
      float4 colv = make_float4(acc[0][j] + bj, acc[1][j] + bj, acc[2][j] + bj,
                                acc[3][j] + bj);
      *reinterpret_cast<float4*>(&Sf[(tx * 4 + j) * 68 + ty * 4]) = colv;
    }
    __syncthreads();
    long b = r0 >> 12;
    long n0 = (r0 & 4095);
    int n = tid & 63, oo = tid >> 6;
#pragma unroll
    for (int i = 0; i < 16; i++) {
      int o = oo + i * 4;
      out[(b * CO + c0 + o) * 4096L + n0 + n] = Sf[o * 68 + n];
    }
  } else if (EPI == 6) {
#pragma unroll
    for (int i = 0; i < 4; i++) {
      long r = r0 + ty * 4 + i;
      __hip_bfloat162 p0, p1;
      p0.x = __float2bfloat16(acc[i][0]);
      p0.y = __float2bfloat16(acc[i][1]);
      p1.x = __float2bfloat16(acc[i][2]);
      p1.y = __float2bfloat16(acc[i][3]);
      __hip_bfloat162* dst = reinterpret_cast<__hip_bfloat162*>(&obf[r * CO + c0 + tx * 4]);
      dst[0] = p0;
      dst[1] = p1;
    }
  }
}

// ------- MFMA flash attention: 64-key tiles, V transposed+swizzled ----------
__global__ __launch_bounds__(256) void flash_mfma_kernel(const float* __restrict__ Q,
                                                         const float* __restrict__ Kb,
                                                         const float* __restrict__ Vb,
                                                         float* __restrict__ O) {
  __shared__ unsigned short Ks[64 * 72];
  __shared__ unsigned short Vt[64 * 72];
  __shared__ unsigned short Ps[4][16 * 72];
  int tid = threadIdx.x;
  int lane = tid & 63, w = tid >> 6;
  int bh = blockIdx.x >> 6;
  int qt = blockIdx.x & 63;
  long base = (long)bh * 4096 * 64;
  int row0 = qt * 64 + w * 16;
  int fr = lane & 15;
  int fk = (lane >> 4) * 8;

  bf16x8 aq[2];
#pragma unroll
  for (int kk = 0; kk < 2; kk++) {
    const float* qp = &Q[base + (long)(row0 + fr) * 64 + kk * 32 + fk];
#pragma unroll
    for (int j = 0; j < 8; j++) aq[kk][j] = (__bf16)qp[j];
  }

  f32x4 o[4];
#pragma unroll
  for (int i = 0; i < 4; i++) o[i] = (f32x4){0.f, 0.f, 0.f, 0.f};
  float m_run[4], l_run[4];
#pragma unroll
  for (int r = 0; r < 4; r++) { m_run[r] = -3.0e38f; l_run[r] = 0.f; }

  int skey = tid >> 2, sdc = (tid & 3) * 16;
  int vd = tid & 63, vkg = tid >> 6;
  int vsw = (vd ^ (vd >> 3)) & 7;

  for (int m0 = 0; m0 < 4096; m0 += 64) {
    __syncthreads();
    {
      const float* kp = &Kb[base + (long)(m0 + skey) * 64 + sdc];
      union { unsigned short u[8]; uint4 v; } pk;
#pragma unroll
      for (int h = 0; h < 2; h++) {
#pragma unroll
        for (int j = 0; j < 8; j++)
          pk.u[j] = __bfloat16_as_ushort(__float2bfloat16(kp[h * 8 + j]));
        *reinterpret_cast<uint4*>(&Ks[skey * 72 + sdc + h * 8]) = pk.v;
      }
#pragma unroll
      for (int j = 0; j < 16; j++) {
        int k = vkg * 16 + j;
        float v = Vb[base + (long)(m0 + k) * 64 + vd];
        int kb = k >> 3, ko = k & 7;
        Vt[vd * 72 + ((kb ^ vsw) << 3) + ko] = __bfloat16_as_ushort(__float2bfloat16(v));
      }
    }
    __syncthreads();

    f32x4 s[4];
#pragma unroll
    for (int n = 0; n < 4; n++) {
      s[n] = (f32x4){0.f, 0.f, 0.f, 0.f};
#pragma unroll
      for (int kk = 0; kk < 2; kk++) {
        bf16x8 bk = *reinterpret_cast<const bf16x8*>(&Ks[(n * 16 + fr) * 72 + kk * 32 + fk]);
        s[n] = __builtin_amdgcn_mfma_f32_16x16x32_bf16(aq[kk], bk, s[n], 0, 0, 0);
      }
    }

    float p[4][4];
#pragma unroll
    for (int r = 0; r < 4; r++) {
      float sv0 = s[0][r] * 0.125f, sv1 = s[1][r] * 0.125f;
      float sv2 = s[2][r] * 0.125f, sv3 = s[3][r] * 0.125f;
      float mx = fmaxf(fmaxf(sv0, sv1), fmaxf(sv2, sv3));
      mx = fmaxf(mx, __shfl_xor(mx, 1));
      mx = fmaxf(mx, __shfl_xor(mx, 2));
      mx = fmaxf(mx, __shfl_xor(mx, 4));
      mx = fmaxf(mx, __shfl_xor(mx, 8));
      float mn = fmaxf(m_run[r], mx);
      float fac = __expf(m_run[r] - mn);
      p[0][r] = __expf(sv0 - mn);
      p[1][r] = __expf(sv1 - mn);
      p[2][r] = __expf(sv2 - mn);
      p[3][r] = __expf(sv3 - mn);
      float rs = (p[0][r] + p[1][r]) + (p[2][r] + p[3][r]);
      rs += __shfl_xor(rs, 1);
      rs += __shfl_xor(rs, 2);
      rs += __shfl_xor(rs, 4);
      rs += __shfl_xor(rs, 8);
      l_run[r] = l_run[r] * fac + rs;
      m_run[r] = mn;
#pragma unroll
      for (int n2 = 0; n2 < 4; n2++) o[n2][r] *= fac;
    }

    unsigned short* pw = &Ps[w][0];
#pragma unroll
    for (int r = 0; r < 4; r++) {
      int prow = (lane >> 4) * 4 + r;
#pragma unroll
      for (int n = 0; n < 4; n++)
        pw[prow * 72 + n * 16 + fr] = __bfloat16_as_ushort(__float2bfloat16(p[n][r]));
    }
    bf16x8 ap[2];
#pragma unroll
    for (int kk = 0; kk < 2; kk++)
      ap[kk] = *reinterpret_cast<const bf16x8*>(&pw[fr * 72 + kk * 32 + fk]);

#pragma unroll
    for (int n2 = 0; n2 < 4; n2++) {
      int d = n2 * 16 + fr;
      int dsw = (d ^ (d >> 3)) & 7;
#pragma unroll
      for (int kk = 0; kk < 2; kk++) {
        int kb = kk * 4 + (lane >> 4);
        bf16x8 bv = *reinterpret_cast<const bf16x8*>(&Vt[d * 72 + ((kb ^ dsw) << 3)]);
        o[n2] = __builtin_amdgcn_mfma_f32_16x16x32_bf16(ap[kk], bv, o[n2], 0, 0, 0);
      }
    }
  }

  int b = bh >> 2, h = bh & 3;
#pragma unroll
  for (int r = 0; r < 4; r++) {
    float inv = 1.f / l_run[r];
    long nrow = (long)(b * 4096 + qt * 64 + w * 16 + (lane >> 4) * 4 + r);
#pragma unroll
    for (int n2 = 0; n2 < 4; n2++) {
      O[nrow * 256 + h * 64 + n2 * 16 + fr] = o[n2][r] * inv;
    }
  }
}

// ------------- LayerNorm over 512 (one row per block) -----------------------
__global__ __launch_bounds__(256) void ln_kernel(float* __restrict__ y,
                                                 const float* __restrict__ lng,
                                                 const float* __restrict__ lnb) {
  long r = blockIdx.x;
  int tid = threadIdx.x;
  float v0 = y[r * 512 + tid];
  float v1 = y[r * 512 + 256 + tid];
  float s = v0 + v1;
  float q = v0 * v0 + v1 * v1;
#pragma unroll
  for (int off = 1; off < 64; off <<= 1) {
    s += __shfl_xor(s, off);
    q += __shfl_xor(q, off);
  }
  __shared__ float red[8];
  __shared__ float mv[2];
  int w = tid >> 6;
  if ((tid & 63) == 0) { red[w] = s; red[4 + w] = q; }
  __syncthreads();
  if (tid == 0) {
    float S = red[0] + red[1] + red[2] + red[3];
    float Q2 = red[4] + red[5] + red[6] + red[7];
    float mu = S * (1.f / 512.f);
    float var = Q2 * (1.f / 512.f) - mu * mu;
    mv[0] = mu;
    mv[1] = rsqrtf(var + 1e-5f);
  }
  __syncthreads();
  float mu = mv[0], rstd = mv[1];
  y[r * 512 + tid] = (v0 - mu) * rstd * lng[tid] + lnb[tid];
  y[r * 512 + 256 + tid] = (v1 - mu) * rstd * lng[256 + tid] + lnb[256 + tid];
}

// ------------- output 0: pos1 passthrough, f32 -> f32 ------------------------
__global__ void poscopy_kernel(const float* __restrict__ p, float* __restrict__ o) {
  int i = blockIdx.x * 256 + threadIdx.x;
  o[i] = p[i];
}

extern "C" void kernel_launch(void* const* d_in, const int* in_sizes, int n_in,
                              void* d_out, int out_size, void* d_ws, size_t ws_size,
                              hipStream_t stream) {
  (void)in_sizes; (void)n_in; (void)out_size; (void)ws_size;
  const float* pos1 = (const float*)d_in[0];
  const float* pos2 = (const float*)d_in[1];
  const float* f1 = (const float*)d_in[2];
  const float* f2 = (const float*)d_in[3];
  const float* w0 = (const float*)d_in[4];
  const float* g0 = (const float*)d_in[5];
  const float* b0 = (const float*)d_in[6];
  const float* w1 = (const float*)d_in[7];
  const float* g1 = (const float*)d_in[8];
  const float* b1 = (const float*)d_in[9];
  const float* w2 = (const float*)d_in[10];
  const float* g2 = (const float*)d_in[11];
  const float* b2 = (const float*)d_in[12];
  const float* qw = (const float*)d_in[13];
  const float* qb = (const float*)d_in[14];
  const float* kw = (const float*)d_in[15];
  const float* kb = (const float*)d_in[16];
  const float* vw = (const float*)d_in[17];
  const float* vb = (const float*)d_in[18];
  const float* ow = (const float*)d_in[19];
  const float* obv = (const float*)d_in[20];
  const float* lng = (const float*)d_in[21];
  const float* lnb = (const float*)d_in[22];
  const float* fw = (const float*)d_in[23];
  const float* fb = (const float*)d_in[24];

  // ws layout identical to passing R19:
  // [0,32) z1b/Qb/K/V/attno/y0 ; [32,48) idx+A1+A2 -> feat ; 48MB stats ;
  // [56,64) knn pd ; [64,72) knn pi  (proven locations)
  char* ws = (char*)d_ws;
  __hip_bfloat16* z1b = (__hip_bfloat16*)(ws);
  float* Qb = (float*)(ws);
  float* Kbuf = (float*)(ws + (8ull << 20));
  float* Vbuf = (float*)(ws + (16ull << 20));
  float* attno = (float*)(ws + (24ull << 20));
  float* y0 = (float*)(ws);
  int* idx = (int*)(ws + (32ull << 20));
  float* A1 = (float*)(ws + (33ull << 20));
  float* A2 = (float*)(ws + (37ull << 20));
  float* feat = (float*)(ws + (32ull << 20));
  char* statp = ws + (48ull << 20);
  float* pd = (float*)(ws + (56ull << 20));
  int* pi = (int*)(ws + (64ull << 20));
  double* st0 = (double*)(statp);
  double* st1 = (double*)(statp + 2048);
  double* st2 = (double*)(statp + 4096);
  float* sc0 = (float*)(statp + 8192);
  float* sh0 = (float*)(statp + 8704);
  float* sc1 = (float*)(statp + 9216);
  float* sh1 = (float*)(statp + 9728);
  float* sc2 = (float*)(statp + 10240);
  float* sh2 = (float*)(statp + 11264);

  float* out0 = (float*)d_out;
  float* out1 = out0 + 24576;

  hipMemsetAsync(statp, 0, 8192, stream);

  knn_part_kernel<<<dim3(32, 16), 256, 0, stream>>>(pos1, pos2, pd, pi);
  knn_merge_kernel<<<32, 256, 0, stream>>>(pd, pi, idx);
  g131_kernel<<<512, 128, 0, stream>>>(pos2, f2, w0, A2, 1.f, 3);
  g131_kernel<<<512, 128, 0, stream>>>(pos1, f1, w0, A1, -1.f, 131);
  z0stats_kernel<<<256, 256, 0, stream>>>(idx, A1, A2, st0);
  bnfin_kernel<<<1, 256, 0, stream>>>(st0, g0, b0, sc0, sh0, 128, 1.0 / 131072.0);
  gemm_kernel<6, 3, true><<<dim3(2, 2048), 256, 0, stream>>>(
      A2, w1, nullptr, 128, 128, nullptr, sc0, sh0, nullptr, z1b, A1, idx, nullptr);
  statsb_kernel<<<512, 256, 0, stream>>>(z1b, 131072L, st1);
  bnfin_kernel<<<1, 256, 0, stream>>>(st1, g1, b1, sc1, sh1, 128, 1.0 / 131072.0);
  gemm2_mfma_kernel<4><<<dim3(4, 2048), 256, 0, stream>>>(
      z1b, w2, sc1, sh1, nullptr, nullptr, nullptr, st2);
  bnfin_kernel<<<1, 256, 0, stream>>>(st2, g2, b2, sc2, sh2, 256, 1.0 / 131072.0);
  gemm2_mfma_kernel<5><<<dim3(4, 2048), 256, 0, stream>>>(
      z1b, w2, sc1, sh1, sc2, sh2, feat, nullptr);
  gemm_kernel<1, 0, false><<<dim3(4, 128), 256, 0, stream>>>(
      feat, qw, Qb, 512, 256, qb, nullptr, nullptr, nullptr, nullptr, nullptr, nullptr, nullptr);
  gemm_kernel<1, 1, false><<<dim3(4, 128), 256, 0, stream>>>(
      f2, kw, Kbuf, 128, 256, kb, nullptr, nullptr, nullptr, nullptr, nullptr, nullptr, nullptr);
  gemm_kernel<1, 1, false><<<dim3(4, 128), 256, 0, stream>>>(
      f2, vw, Vbuf, 128, 256, vb, nullptr, nullptr, nullptr, nullptr, nullptr, nullptr, nullptr);
  flash_mfma_kernel<<<512, 256, 0, stream>>>(Qb, Kbuf, Vbuf, attno);
  gemm_kernel<2, 0, false><<<dim3(8, 128), 256, 0, stream>>>(
      attno, ow, y0, 256, 512, obv, nullptr, nullptr, feat, nullptr, nullptr, nullptr, nullptr);
  ln_kernel<<<8192, 256, 0, stream>>>(y0, lng, lnb);
  gemm_kernel<3, 0, false><<<dim3(4, 128), 256, 0, stream>>>(
      y0, fw, out1, 512, 256, fb, nullptr, nullptr, nullptr, nullptr, nullptr, nullptr, nullptr);
  poscopy_kernel<<<96, 256, 0, stream>>>(pos1, out0);
}

// Round 22
// 837.461 us; speedup vs baseline: 3.4513x; 1.2099x over previous
//
#include <hip/hip_runtime.h>
#include <hip/hip_bf16.h>

constexpr int B_ = 2, N_ = 4096, M_ = 4096, C_ = 128;

typedef __attribute__((ext_vector_type(8))) __bf16 bf16x8;
typedef __attribute__((ext_vector_type(4))) float f32x4;

// ---- KNN phase 1: per-(query, 256-candidate segment) register top-16 -------
// FROZEN selection semantics (R17/R19). Inner loop unrolled x8 for ILP only:
// identical arithmetic ops, identical mm-ascending insertion sequence.
__global__ __launch_bounds__(256) void knn_part_kernel(const float* __restrict__ pos1,
                                                       const float* __restrict__ pos2,
                                                       float* __restrict__ pd,
                                                       int* __restrict__ pi) {
  __shared__ float tX[256], tY[256], tZ[256], tS[256];
  int tid = threadIdx.x;
  int bn = blockIdx.x * 256 + tid;
  int b = bn >> 12, n = bn & 4095;
  int seg = blockIdx.y;
  const float* p1 = pos1 + (long)b * 3 * N_;
  float qx = p1[n], qy = p1[N_ + n], qz = p1[2 * N_ + n];
  float s1 = __fadd_rn(__fadd_rn(__fmul_rn(qx, qx), __fmul_rn(qy, qy)), __fmul_rn(qz, qz));
  const float* p2 = pos2 + (long)b * 3 * M_ + seg * 256;
  {
    float x = p2[tid], y = p2[M_ + tid], z = p2[2 * M_ + tid];
    tX[tid] = x; tY[tid] = y; tZ[tid] = z;
    tS[tid] = __fadd_rn(__fadd_rn(__fmul_rn(x, x), __fmul_rn(y, y)), __fmul_rn(z, z));
  }
  __syncthreads();
  float rd[16]; int ri[16];
#pragma unroll
  for (int k = 0; k < 16; k++) { rd[k] = 3.0e38f; ri[k] = 0; }
  for (int mm = 0; mm < 256; mm += 8) {
    float dv[8];
#pragma unroll
    for (int u = 0; u < 8; u++) {
      float e = __fmaf_rn(qz, tZ[mm + u],
                          __fmaf_rn(qy, tY[mm + u], __fmul_rn(qx, tX[mm + u])));
      dv[u] = __fadd_rn(__fsub_rn(s1, __fadd_rn(e, e)), tS[mm + u]);
    }
    float thr = rd[15];
    bool any = false;
#pragma unroll
    for (int u = 0; u < 8; u++) any = any || (dv[u] < thr);
    if (any) {
#pragma unroll
      for (int u = 0; u < 8; u++) {
        float d = dv[u];
        if (d < rd[15]) {
          float cd = d; int ci = seg * 256 + mm + u;
#pragma unroll
          for (int k = 0; k < 16; k++) {
            bool lt = cd < rd[k];
            float td = lt ? rd[k] : cd;
            int ti = lt ? ri[k] : ci;
            rd[k] = lt ? cd : rd[k];
            ri[k] = lt ? ci : ri[k];
            cd = td; ci = ti;
          }
        }
      }
    }
  }
  long base = (long)seg * 16 * 8192 + bn;
#pragma unroll
  for (int k = 0; k < 16; k++) {
    pd[base + (long)k * 8192] = rd[k];
    pi[base + (long)k * 8192] = ri[k];
  }
}

// ---- KNN phase 2: merge 16 sorted lists of 16 per query (frozen) -----------
__global__ __launch_bounds__(256) void knn_merge_kernel(const float* __restrict__ pd,
                                                        const int* __restrict__ pi,
                                                        int* __restrict__ idx) {
  int bn = blockIdx.x * 256 + threadIdx.x;
  float rd[16]; int ri[16];
#pragma unroll
  for (int k = 0; k < 16; k++) { rd[k] = 3.0e38f; ri[k] = 0; }
  for (int seg = 0; seg < 16; seg++) {
    for (int k = 0; k < 16; k++) {
      float d = pd[((long)seg * 16 + k) * 8192 + bn];
      if (d >= rd[15]) break;
      int ci = pi[((long)seg * 16 + k) * 8192 + bn];
      float cd = d;
#pragma unroll
      for (int j = 0; j < 16; j++) {
        bool lt = cd < rd[j];
        float td = lt ? rd[j] : cd;
        int ti = lt ? ri[j] : ci;
        rd[j] = lt ? cd : rd[j];
        ri[j] = lt ? ci : ri[j];
        cd = td; ci = ti;
      }
    }
  }
#pragma unroll
  for (int k = 0; k < 16; k++) idx[(long)bn * 16 + k] = ri[k];
}

// ------------- layer0 decomposition: 131-wide GEMM over points --------------
__global__ __launch_bounds__(128) void g131_kernel(const float* __restrict__ pos,
                                                   const float* __restrict__ feat,
                                                   const float* __restrict__ w0,
                                                   float* __restrict__ out,
                                                   float sign, int woff) {
  __shared__ float Xs[131 * 16];
  int tid = threadIdx.x;
  long b = blockIdx.x >> 8;
  int i0 = (blockIdx.x & 255) * 16;
  for (int e = tid; e < 131 * 16; e += 128) {
    int r = e & 15, c = e >> 4;
    float v = (c < 3) ? sign * pos[b * 3 * N_ + (long)c * N_ + i0 + r]
                      : feat[b * C_ * N_ + (long)(c - 3) * N_ + i0 + r];
    Xs[c * 16 + r] = v;
  }
  __syncthreads();
  int o = tid;
  float acc[16];
#pragma unroll
  for (int r = 0; r < 16; r++) acc[r] = 0.f;
  for (int c = 0; c < 131; c++) {
    float wv = w0[(long)o * 259 + (c < 3 ? c : (woff + c - 3))];
    const float* xr = &Xs[c * 16];
#pragma unroll
    for (int r = 0; r < 16; r++) acc[r] = fmaf(xr[r], wv, acc[r]);
  }
#pragma unroll
  for (int r = 0; r < 16; r++) out[((b << 12) + i0 + r) * 128 + o] = acc[r];
}

// ------------- BN0 stats from (idx, A1, A2), no z0 store --------------------
__global__ __launch_bounds__(256) void z0stats_kernel(const int* __restrict__ idx,
                                                      const float* __restrict__ A1,
                                                      const float* __restrict__ A2,
                                                      double* __restrict__ st) {
  int tid = threadIdx.x;
  int o = tid & 127, half = tid >> 7;
  float sum = 0.f, sq = 0.f;
  int g0 = blockIdx.x * 32;
  for (int gi = 0; gi < 32; gi++) {
    int bn = g0 + gi;
    long b = bn >> 12;
    float a1 = A1[(long)bn * 128 + o];
    for (int k = half; k < 16; k += 2) {
      int m = idx[bn * 16 + k];
      float v = A2[(b * 4096 + m) * 128 + o] + a1;
      sum += v;
      sq += v * v;
    }
  }
  __shared__ float ls[256], lq[256];
  ls[tid] = sum; lq[tid] = sq;
  __syncthreads();
  if (tid < 128) {
    atomicAdd(&st[o], (double)(ls[tid] + ls[tid + 128]));
    atomicAdd(&st[128 + o], (double)(lq[tid] + lq[tid + 128]));
  }
}

// ------------- per-channel stats over bf16 (nrows x 128) --------------------
__global__ __launch_bounds__(256) void statsb_kernel(const __hip_bfloat16* __restrict__ Z,
                                                     long nrows, double* __restrict__ st) {
  int tid = threadIdx.x;
  int c = tid & 127, sub = tid >> 7;
  long slot = (long)blockIdx.x * 2 + sub;
  long stride = (long)gridDim.x * 2;
  float sum = 0.f, sq = 0.f;
  for (long r = slot; r < nrows; r += stride) {
    float v = __bfloat162float(Z[r * 128 + c]);
    sum += v;
    sq += v * v;
  }
  __shared__ float ls[256], lq[256];
  ls[tid] = sum; lq[tid] = sq;
  __syncthreads();
  if (tid < 128) {
    atomicAdd(&st[c], (double)(ls[tid] + ls[tid + 128]));
    atomicAdd(&st[128 + c], (double)(lq[tid] + lq[tid + 128]));
  }
}

// ------------- BN finalize: fold mean/var/g/b into scale+shift --------------
__global__ void bnfin_kernel(const double* __restrict__ st, const float* __restrict__ g,
                             const float* __restrict__ bb, float* __restrict__ sc,
                             float* __restrict__ sh, int CO, double inv) {
  int c = threadIdx.x;
  if (c < CO) {
    double mu = st[c] * inv;
    double var = st[CO + c] * inv - mu * mu;
    double rstd = 1.0 / sqrt(var + 1e-5);
    double scv = (double)g[c] * rstd;
    sc[c] = (float)scv;
    sh[c] = (float)((double)bb[c] - mu * scv);
  }
}

// ---- MFMA z1 pass: z1 = BN0ReLU(gather(A2)+A1) @ w1^T -> bf16 --------------
__global__ __launch_bounds__(256) void gemm1_mfma_kernel(
    const float* __restrict__ A2, const float* __restrict__ A1,
    const int* __restrict__ idxp, const float* __restrict__ w1,
    const float* __restrict__ sc0, const float* __restrict__ sh0,
    __hip_bfloat16* __restrict__ z1b) {
  __shared__ unsigned short As[64 * 136];
  __shared__ unsigned short Bs[64 * 136];
  __shared__ float scs[128], shs[128];
  int tid = threadIdx.x;
  int lane = tid & 63, w = tid >> 6;
  int cb = blockIdx.x;
  long r0 = (long)blockIdx.y * 64;
  int c0 = cb * 64;
  if (tid < 128) { scs[tid] = sc0[tid]; shs[tid] = sh0[tid]; }
  __syncthreads();
  {
    int row = tid >> 2, kb = (tid & 3) * 32;
    long g = r0 + row;
    int m = idxp[g];
    const float* a2p = &A2[(((g >> 16) << 12) + m) * 128 + kb];
    const float* a1p = &A1[(g >> 4) * 128 + kb];
    unsigned short* ap = &As[row * 136 + kb];
    const float* wp = &w1[(long)(c0 + row) * 128 + kb];
    unsigned short* bp = &Bs[row * 136 + kb];
#pragma unroll
    for (int h = 0; h < 4; h++) {
      union { unsigned short u[8]; uint4 v; } oa, ob;
#pragma unroll
      for (int j = 0; j < 8; j++) {
        int k = kb + h * 8 + j;
        float raw = a2p[h * 8 + j] + a1p[h * 8 + j];
        float v = fmaxf(0.f, fmaf(raw, scs[k], shs[k]));
        oa.u[j] = __bfloat16_as_ushort(__float2bfloat16(v));
        ob.u[j] = __bfloat16_as_ushort(__float2bfloat16(wp[h * 8 + j]));
      }
      *reinterpret_cast<uint4*>(ap + h * 8) = oa.v;
      *reinterpret_cast<uint4*>(bp + h * 8) = ob.v;
    }
  }
  __syncthreads();

  int fr = lane & 15, fk = (lane >> 4) * 8;
  bf16x8 a[4];
#pragma unroll
  for (int kk = 0; kk < 4; kk++)
    a[kk] = *reinterpret_cast<const bf16x8*>(&As[(w * 16 + fr) * 136 + kk * 32 + fk]);
  f32x4 acc[4];
#pragma unroll
  for (int n2 = 0; n2 < 4; n2++) {
    acc[n2] = (f32x4){0.f, 0.f, 0.f, 0.f};
#pragma unroll
    for (int kk = 0; kk < 4; kk++) {
      bf16x8 bfrag = *reinterpret_cast<const bf16x8*>(&Bs[(n2 * 16 + fr) * 136 + kk * 32 + fk]);
      acc[n2] = __builtin_amdgcn_mfma_f32_16x16x32_bf16(a[kk], bfrag, acc[n2], 0, 0, 0);
    }
  }
#pragma unroll
  for (int n2 = 0; n2 < 4; n2++) {
#pragma unroll
    for (int r = 0; r < 4; r++) {
      long row = r0 + w * 16 + (lane >> 4) * 4 + r;
      z1b[row * 128 + c0 + n2 * 16 + fr] = __float2bfloat16(acc[n2][r]);
    }
  }
}

// ---- MFMA z2 pass: C = BN1ReLU(z1b) @ w2^T, 64x64 tile, 4 waves ------------
template <int EPI>
__global__ __launch_bounds__(256) void gemm2_mfma_kernel(
    const __hip_bfloat16* __restrict__ z1b, const float* __restrict__ w2,
    const float* __restrict__ sc1, const float* __restrict__ sh1,
    const float* __restrict__ sc2, const float* __restrict__ sh2,
    float* __restrict__ feat, double* __restrict__ st) {
  __shared__ unsigned short As[64 * 136];
  __shared__ unsigned short Bs[64 * 136];
  __shared__ float scs[128], shs[128];
  __shared__ float Sred[4 * 64], Qred[4 * 64];
  int tid = threadIdx.x;
  int lane = tid & 63, w = tid >> 6;
  int cb = blockIdx.x;
  long r0 = (long)blockIdx.y * 64;
  int c0 = cb * 64;
  if (tid < 128) { scs[tid] = sc1[tid]; shs[tid] = sh1[tid]; }
  __syncthreads();
  {
    int row = tid >> 2, kb = (tid & 3) * 32;
    const __hip_bfloat16* zp = &z1b[(r0 + row) * 128 + kb];
    unsigned short* ap = &As[row * 136 + kb];
    const float* wp = &w2[(long)(c0 + row) * 128 + kb];
    unsigned short* bp = &Bs[row * 136 + kb];
#pragma unroll
    for (int h = 0; h < 4; h++) {
      union { unsigned short u[8]; uint4 v; } in, oa, ob;
      in.v = *reinterpret_cast<const uint4*>(zp + h * 8);
#pragma unroll
      for (int j = 0; j < 8; j++) {
        int k = kb + h * 8 + j;
        float f = __bfloat162float(__ushort_as_bfloat16(in.u[j]));
        float v = fmaxf(0.f, fmaf(f, scs[k], shs[k]));
        oa.u[j] = __bfloat16_as_ushort(__float2bfloat16(v));
        ob.u[j] = __bfloat16_as_ushort(__float2bfloat16(wp[h * 8 + j]));
      }
      *reinterpret_cast<uint4*>(ap + h * 8) = oa.v;
      *reinterpret_cast<uint4*>(bp + h * 8) = ob.v;
    }
  }
  __syncthreads();

  int fr = lane & 15, fk = (lane >> 4) * 8;
  bf16x8 a[4];
#pragma unroll
  for (int kk = 0; kk < 4; kk++)
    a[kk] = *reinterpret_cast<const bf16x8*>(&As[(w * 16 + fr) * 136 + kk * 32 + fk]);
  f32x4 acc[4];
#pragma unroll
  for (int n2 = 0; n2 < 4; n2++) {
    acc[n2] = (f32x4){0.f, 0.f, 0.f, 0.f};
#pragma unroll
    for (int kk = 0; kk < 4; kk++) {
      bf16x8 bfrag = *reinterpret_cast<const bf16x8*>(&Bs[(n2 * 16 + fr) * 136 + kk * 32 + fk]);
      acc[n2] = __builtin_amdgcn_mfma_f32_16x16x32_bf16(a[kk], bfrag, acc[n2], 0, 0, 0);
    }
  }

  if (EPI == 4) {
#pragma unroll
    for (int n2 = 0; n2 < 4; n2++) {
      float s = 0.f, q = 0.f;
#pragma unroll
      for (int r = 0; r < 4; r++) { s += acc[n2][r]; q += acc[n2][r] * acc[n2][r]; }
      s += __shfl_xor(s, 16); s += __shfl_xor(s, 32);
      q += __shfl_xor(q, 16); q += __shfl_xor(q, 32);
      if (lane < 16) { Sred[w * 64 + n2 * 16 + fr] = s; Qred[w * 64 + n2 * 16 + fr] = q; }
    }
    __syncthreads();
    if (tid < 64) {
      float S = Sred[tid] + Sred[64 + tid] + Sred[128 + tid] + Sred[192 + tid];
      float Q = Qred[tid] + Qred[64 + tid] + Qred[128 + tid] + Qred[192 + tid];
      atomicAdd(&st[c0 + tid], (double)S);
      atomicAdd(&st[256 + c0 + tid], (double)Q);
    }
  } else {
    int bn = (int)(r0 >> 4) + w;
#pragma unroll
    for (int n2 = 0; n2 < 4; n2++) {
      int c = c0 + n2 * 16 + fr;
      float scv = sc2[c], shv = sh2[c];
      float mx = -1e30f, sm = 0.f;
#pragma unroll
      for (int r = 0; r < 4; r++) {
        float v = fmaxf(0.f, fmaf(acc[n2][r], scv, shv));
        mx = fmaxf(mx, v);
        sm += v;
      }
      mx = fmaxf(mx, __shfl_xor(mx, 16)); mx = fmaxf(mx, __shfl_xor(mx, 32));
      sm += __shfl_xor(sm, 16); sm += __shfl_xor(sm, 32);
      if (lane < 16) {
        feat[(long)bn * 512 + c] = mx;
        feat[(long)bn * 512 + 256 + c] = sm * (1.f / 16.f);
      }
    }
  }
}

// ------------- tiled GEMM: out = act(X) * W^T (+epilogues), f32 accum -------
template <int EPI, int XM, bool BN>
__global__ __launch_bounds__(256) void gemm_kernel(
    const void* __restrict__ Xv, const float* __restrict__ W, float* __restrict__ out,
    int K, int CO, const float* __restrict__ bias, const float* __restrict__ sc,
    const float* __restrict__ sh, const float* __restrict__ res,
    __hip_bfloat16* __restrict__ obf, const float* __restrict__ A1,
    const int* __restrict__ idxp, double* __restrict__ st) {
  __shared__ float S[2][32 * 68];
  int tid = threadIdx.x;
  int tx = tid & 15, ty = tid >> 4;
  int cb = blockIdx.x;
  long r0 = (long)blockIdx.y * 64;
  int c0 = cb * 64;
  float acc[4][4];
#pragma unroll
  for (int i = 0; i < 4; i++)
#pragma unroll
    for (int j = 0; j < 4; j++) acc[i][j] = 0.f;

  for (int k0 = 0; k0 < K; k0 += 32) {
    if (XM != 1) {
      int c = tid & 31, rr = tid >> 5;
      float scv = 0.f, shv = 0.f;
      if (BN) { scv = sc[k0 + c]; shv = sh[k0 + c]; }
#pragma unroll
      for (int i = 0; i < 8; i++) {
        int r = rr + i * 8;
        long g = r0 + r;
        float v;
        if (XM == 0) {
          v = ((const float*)Xv)[g * K + k0 + c];
        } else {
          v = __bfloat162float(((const __hip_bfloat16*)Xv)[g * K + k0 + c]);
        }
        if (BN) v = fmaxf(0.f, fmaf(v, scv, shv));
        S[0][c * 68 + r] = v;
      }
    } else {
      int m = tid & 63, cc = tid >> 6;
      long b = r0 >> 12;
      long mg = (r0 & 4095) + m;
#pragma unroll
      for (int i = 0; i < 8; i++) {
        int c = cc + i * 4;
        S[0][c * 68 + m] = ((const float*)Xv)[(b * K + k0 + c) * 4096 + mg];
      }
    }
    {
      int c = tid & 31, oo = tid >> 5;
#pragma unroll
      for (int i = 0; i < 8; i++) {
        int o = oo + i * 8;
        S[1][c * 68 + o] = W[(long)(c0 + o) * K + k0 + c];
      }
    }
    __syncthreads();
#pragma unroll
    for (int kk = 0; kk < 32; kk++) {
      float4 a = *reinterpret_cast<const float4*>(&S[0][kk * 68 + ty * 4]);
      float4 bv = *reinterpret_cast<const float4*>(&S[1][kk * 68 + tx * 4]);
      float av[4] = {a.x, a.y, a.z, a.w};
      float bw[4] = {bv.x, bv.y, bv.z, bv.w};
#pragma unroll
      for (int i = 0; i < 4; i++)
#pragma unroll
        for (int j = 0; j < 4; j++) acc[i][j] = fmaf(av[i], bw[j], acc[i][j]);
    }
    __syncthreads();
  }

  if (EPI == 1) {
    long b = r0 >> 12;
    long nn = (r0 & 4095) + ty * 4;
    const float4 b4 = *reinterpret_cast<const float4*>(&bias[c0 + tx * 4]);
    float* Ob = out + ((b * (CO >> 6) + cb) * 4096L) * 64;
#pragma unroll
    for (int i = 0; i < 4; i++) {
      float4 o4 = make_float4(acc[i][0] + b4.x, acc[i][1] + b4.y, acc[i][2] + b4.z,
                              acc[i][3] + b4.w);
      *reinterpret_cast<float4*>(&Ob[(nn + i) * 64 + tx * 4]) = o4;
    }
  } else if (EPI == 2) {
    const float4 b4 = *reinterpret_cast<const float4*>(&bias[c0 + tx * 4]);
#pragma unroll
    for (int i = 0; i < 4; i++) {
      long r = r0 + ty * 4 + i;
      float4 f4 = *reinterpret_cast<const float4*>(&res[r * CO + c0 + tx * 4]);
      float4 o4 = make_float4(acc[i][0] + b4.x + f4.x, acc[i][1] + b4.y + f4.y,
                              acc[i][2] + b4.z + f4.z, acc[i][3] + b4.w + f4.w);
      *reinterpret_cast<float4*>(&out[r * CO + c0 + tx * 4]) = o4;
    }
  } else if (EPI == 3) {
    float* Sf = &S[0][0];
#pragma unroll
    for (int j = 0; j < 4; j++) {
      float bj = bias[c0 + tx * 4 + j];
      float4 colv = make_float4(acc[0][j] + bj, acc[1][j] + bj, acc[2][j] + bj,
                                acc[3][j] + bj);
      *reinterpret_cast<float4*>(&Sf[(tx * 4 + j) * 68 + ty * 4]) = colv;
    }
    __syncthreads();
    long b = r0 >> 12;
    long n0 = (r0 & 4095);
    int n = tid & 63, oo = tid >> 6;
#pragma unroll
    for (int i = 0; i < 16; i++) {
      int o = oo + i * 4;
      out[(b * CO + c0 + o) * 4096L + n0 + n] = Sf[o * 68 + n];
    }
  }
}

// ------- MFMA flash attention: 64-key tiles, V transposed+swizzled ----------
__global__ __launch_bounds__(256) void flash_mfma_kernel(const float* __restrict__ Q,
                                                         const float* __restrict__ Kb,
                                                         const float* __restrict__ Vb,
                                                         float* __restrict__ O) {
  __shared__ unsigned short Ks[64 * 72];
  __shared__ unsigned short Vt[64 * 72];
  __shared__ unsigned short Ps[4][16 * 72];
  int tid = threadIdx.x;
  int lane = tid & 63, w = tid >> 6;
  int bh = blockIdx.x >> 6;
  int qt = blockIdx.x & 63;
  long base = (long)bh * 4096 * 64;
  int row0 = qt * 64 + w * 16;
  int fr = lane & 15;
  int fk = (lane >> 4) * 8;

  bf16x8 aq[2];
#pragma unroll
  for (int kk = 0; kk < 2; kk++) {
    const float* qp = &Q[base + (long)(row0 + fr) * 64 + kk * 32 + fk];
#pragma unroll
    for (int j = 0; j < 8; j++) aq[kk][j] = (__bf16)qp[j];
  }

  f32x4 o[4];
#pragma unroll
  for (int i = 0; i < 4; i++) o[i] = (f32x4){0.f, 0.f, 0.f, 0.f};
  float m_run[4], l_run[4];
#pragma unroll
  for (int r = 0; r < 4; r++) { m_run[r] = -3.0e38f; l_run[r] = 0.f; }

  int skey = tid >> 2, sdc = (tid & 3) * 16;
  int vd = tid & 63, vkg = tid >> 6;
  int vsw = (vd ^ (vd >> 3)) & 7;

  for (int m0 = 0; m0 < 4096; m0 += 64) {
    __syncthreads();
    {
      const float* kp = &Kb[base + (long)(m0 + skey) * 64 + sdc];
      union { unsigned short u[8]; uint4 v; } pk;
#pragma unroll
      for (int h = 0; h < 2; h++) {
#pragma unroll
        for (int j = 0; j < 8; j++)
          pk.u[j] = __bfloat16_as_ushort(__float2bfloat16(kp[h * 8 + j]));
        *reinterpret_cast<uint4*>(&Ks[skey * 72 + sdc + h * 8]) = pk.v;
      }
#pragma unroll
      for (int j = 0; j < 16; j++) {
        int k = vkg * 16 + j;
        float v = Vb[base + (long)(m0 + k) * 64 + vd];
        int kb = k >> 3, ko = k & 7;
        Vt[vd * 72 + ((kb ^ vsw) << 3) + ko] = __bfloat16_as_ushort(__float2bfloat16(v));
      }
    }
    __syncthreads();

    f32x4 s[4];
#pragma unroll
    for (int n = 0; n < 4; n++) {
      s[n] = (f32x4){0.f, 0.f, 0.f, 0.f};
#pragma unroll
      for (int kk = 0; kk < 2; kk++) {
        bf16x8 bk = *reinterpret_cast<const bf16x8*>(&Ks[(n * 16 + fr) * 72 + kk * 32 + fk]);
        s[n] = __builtin_amdgcn_mfma_f32_16x16x32_bf16(aq[kk], bk, s[n], 0, 0, 0);
      }
    }

    float p[4][4];
#pragma unroll
    for (int r = 0; r < 4; r++) {
      float sv0 = s[0][r] * 0.125f, sv1 = s[1][r] * 0.125f;
      float sv2 = s[2][r] * 0.125f, sv3 = s[3][r] * 0.125f;
      float mx = fmaxf(fmaxf(sv0, sv1), fmaxf(sv2, sv3));
      mx = fmaxf(mx, __shfl_xor(mx, 1));
      mx = fmaxf(mx, __shfl_xor(mx, 2));
      mx = fmaxf(mx, __shfl_xor(mx, 4));
      mx = fmaxf(mx, __shfl_xor(mx, 8));
      float mn = fmaxf(m_run[r], mx);
      float fac = __expf(m_run[r] - mn);
      p[0][r] = __expf(sv0 - mn);
      p[1][r] = __expf(sv1 - mn);
      p[2][r] = __expf(sv2 - mn);
      p[3][r] = __expf(sv3 - mn);
      float rs = (p[0][r] + p[1][r]) + (p[2][r] + p[3][r]);
      rs += __shfl_xor(rs, 1);
      rs += __shfl_xor(rs, 2);
      rs += __shfl_xor(rs, 4);
      rs += __shfl_xor(rs, 8);
      l_run[r] = l_run[r] * fac + rs;
      m_run[r] = mn;
#pragma unroll
      for (int n2 = 0; n2 < 4; n2++) o[n2][r] *= fac;
    }

    unsigned short* pw = &Ps[w][0];
#pragma unroll
    for (int r = 0; r < 4; r++) {
      int prow = (lane >> 4) * 4 + r;
#pragma unroll
      for (int n = 0; n < 4; n++)
        pw[prow * 72 + n * 16 + fr] = __bfloat16_as_ushort(__float2bfloat16(p[n][r]));
    }
    bf16x8 ap[2];
#pragma unroll
    for (int kk = 0; kk < 2; kk++)
      ap[kk] = *reinterpret_cast<const bf16x8*>(&pw[fr * 72 + kk * 32 + fk]);

#pragma unroll
    for (int n2 = 0; n2 < 4; n2++) {
      int d = n2 * 16 + fr;
      int dsw = (d ^ (d >> 3)) & 7;
#pragma unroll
      for (int kk = 0; kk < 2; kk++) {
        int kb = kk * 4 + (lane >> 4);
        bf16x8 bv = *reinterpret_cast<const bf16x8*>(&Vt[d * 72 + ((kb ^ dsw) << 3)]);
        o[n2] = __builtin_amdgcn_mfma_f32_16x16x32_bf16(ap[kk], bv, o[n2], 0, 0, 0);
      }
    }
  }

  int b = bh >> 2, h = bh & 3;
#pragma unroll
  for (int r = 0; r < 4; r++) {
    float inv = 1.f / l_run[r];
    long nrow = (long)(b * 4096 + qt * 64 + w * 16 + (lane >> 4) * 4 + r);
#pragma unroll
    for (int n2 = 0; n2 < 4; n2++) {
      O[nrow * 256 + h * 64 + n2 * 16 + fr] = o[n2][r] * inv;
    }
  }
}

// ------------- LayerNorm over 512 (one row per block) -----------------------
__global__ __launch_bounds__(256) void ln_kernel(float* __restrict__ y,
                                                 const float* __restrict__ lng,
                                                 const float* __restrict__ lnb) {
  long r = blockIdx.x;
  int tid = threadIdx.x;
  float v0 = y[r * 512 + tid];
  float v1 = y[r * 512 + 256 + tid];
  float s = v0 + v1;
  float q = v0 * v0 + v1 * v1;
#pragma unroll
  for (int off = 1; off < 64; off <<= 1) {
    s += __shfl_xor(s, off);
    q += __shfl_xor(q, off);
  }
  __shared__ float red[8];
  __shared__ float mv[2];
  int w = tid >> 6;
  if ((tid & 63) == 0) { red[w] = s; red[4 + w] = q; }
  __syncthreads();
  if (tid == 0) {
    float S = red[0] + red[1] + red[2] + red[3];
    float Q2 = red[4] + red[5] + red[6] + red[7];
    float mu = S * (1.f / 512.f);
    float var = Q2 * (1.f / 512.f) - mu * mu;
    mv[0] = mu;
    mv[1] = rsqrtf(var + 1e-5f);
  }
  __syncthreads();
  float mu = mv[0], rstd = mv[1];
  y[r * 512 + tid] = (v0 - mu) * rstd * lng[tid] + lnb[tid];
  y[r * 512 + 256 + tid] = (v1 - mu) * rstd * lng[256 + tid] + lnb[256 + tid];
}

// ------------- output 0: pos1 passthrough, f32 -> f32 ------------------------
__global__ void poscopy_kernel(const float* __restrict__ p, float* __restrict__ o) {
  int i = blockIdx.x * 256 + threadIdx.x;
  o[i] = p[i];
}

extern "C" void kernel_launch(void* const* d_in, const int* in_sizes, int n_in,
                              void* d_out, int out_size, void* d_ws, size_t ws_size,
                              hipStream_t stream) {
  (void)in_sizes; (void)n_in; (void)out_size; (void)ws_size;
  const float* pos1 = (const float*)d_in[0];
  const float* pos2 = (const float*)d_in[1];
  const float* f1 = (const float*)d_in[2];
  const float* f2 = (const float*)d_in[3];
  const float* w0 = (const float*)d_in[4];
  const float* g0 = (const float*)d_in[5];
  const float* b0 = (const float*)d_in[6];
  const float* w1 = (const float*)d_in[7];
  const float* g1 = (const float*)d_in[8];
  const float* b1 = (const float*)d_in[9];
  const float* w2 = (const float*)d_in[10];
  const float* g2 = (const float*)d_in[11];
  const float* b2 = (const float*)d_in[12];
  const float* qw = (const float*)d_in[13];
  const float* qb = (const float*)d_in[14];
  const float* kw = (const float*)d_in[15];
  const float* kb = (const float*)d_in[16];
  const float* vw = (const float*)d_in[17];
  const float* vb = (const float*)d_in[18];
  const float* ow = (const float*)d_in[19];
  const float* obv = (const float*)d_in[20];
  const float* lng = (const float*)d_in[21];
  const float* lnb = (const float*)d_in[22];
  const float* fw = (const float*)d_in[23];
  const float* fb = (const float*)d_in[24];

  // ws layout identical to passing R19/R21 (proven locations).
  char* ws = (char*)d_ws;
  __hip_bfloat16* z1b = (__hip_bfloat16*)(ws);
  float* Qb = (float*)(ws);
  float* Kbuf = (float*)(ws + (8ull << 20));
  float* Vbuf = (float*)(ws + (16ull << 20));
  float* attno = (float*)(ws + (24ull << 20));
  float* y0 = (float*)(ws);
  int* idx = (int*)(ws + (32ull << 20));
  float* A1 = (float*)(ws + (33ull << 20));
  float* A2 = (float*)(ws + (37ull << 20));
  float* feat = (float*)(ws + (32ull << 20));
  char* statp = ws + (48ull << 20);
  float* pd = (float*)(ws + (56ull << 20));
  int* pi = (int*)(ws + (64ull << 20));
  double* st0 = (double*)(statp);
  double* st1 = (double*)(statp + 2048);
  double* st2 = (double*)(statp + 4096);
  float* sc0 = (float*)(statp + 8192);
  float* sh0 = (float*)(statp + 8704);
  float* sc1 = (float*)(statp + 9216);
  float* sh1 = (float*)(statp + 9728);
  float* sc2 = (float*)(statp + 10240);
  float* sh2 = (float*)(statp + 11264);

  float* out0 = (float*)d_out;
  float* out1 = out0 + 24576;

  hipMemsetAsync(statp, 0, 8192, stream);

  knn_part_kernel<<<dim3(32, 16), 256, 0, stream>>>(pos1, pos2, pd, pi);
  knn_merge_kernel<<<32, 256, 0, stream>>>(pd, pi, idx);
  g131_kernel<<<512, 128, 0, stream>>>(pos2, f2, w0, A2, 1.f, 3);
  g131_kernel<<<512, 128, 0, stream>>>(pos1, f1, w0, A1, -1.f, 131);
  z0stats_kernel<<<256, 256, 0, stream>>>(idx, A1, A2, st0);
  bnfin_kernel<<<1, 256, 0, stream>>>(st0, g0, b0, sc0, sh0, 128, 1.0 / 131072.0);
  gemm1_mfma_kernel<<<dim3(2, 2048), 256, 0, stream>>>(
      A2, A1, idx, w1, sc0, sh0, z1b);
  statsb_kernel<<<512, 256, 0, stream>>>(z1b, 131072L, st1);
  bnfin_kernel<<<1, 256, 0, stream>>>(st1, g1, b1, sc1, sh1, 128, 1.0 / 131072.0);
  gemm2_mfma_kernel<4><<<dim3(4, 2048), 256, 0, stream>>>(
      z1b, w2, sc1, sh1, nullptr, nullptr, nullptr, st2);
  bnfin_kernel<<<1, 256, 0, stream>>>(st2, g2, b2, sc2, sh2, 256, 1.0 / 131072.0);
  gemm2_mfma_kernel<5><<<dim3(4, 2048), 256, 0, stream>>>(
      z1b, w2, sc1, sh1, sc2, sh2, feat, nullptr);
  gemm_kernel<1, 0, false><<<dim3(4, 128), 256, 0, stream>>>(
      feat, qw, Qb, 512, 256, qb, nullptr, nullptr, nullptr, nullptr, nullptr, nullptr, nullptr);
  gemm_kernel<1, 1, false><<<dim3(4, 128), 256, 0, stream>>>(
      f2, kw, Kbuf, 128, 256, kb, nullptr, nullptr, nullptr, nullptr, nullptr, nullptr, nullptr);
  gemm_kernel<1, 1, false><<<dim3(4, 128), 256, 0, stream>>>(
      f2, vw, Vbuf, 128, 256, vb, nullptr, nullptr, nullptr, nullptr, nullptr, nullptr, nullptr);
  flash_mfma_kernel<<<512, 256, 0, stream>>>(Qb, Kbuf, Vbuf, attno);
  gemm_kernel<2, 0, false><<<dim3(8, 128), 256, 0, stream>>>(
      attno, ow, y0, 256, 512, obv, nullptr, nullptr, feat, nullptr, nullptr, nullptr, nullptr);
  ln_kernel<<<8192, 256, 0, stream>>>(y0, lng, lnb);
  gemm_kernel<3, 0, false><<<dim3(4, 128), 256, 0, stream>>>(
      y0, fw, out1, 512, 256, fb, nullptr, nullptr, nullptr, nullptr, nullptr, nullptr, nullptr);
  poscopy_kernel<<<96, 256, 0, stream>>>(pos1, out0);
}

// Round 23
// 804.575 us; speedup vs baseline: 3.5924x; 1.0409x over previous
//
#include <hip/hip_runtime.h>
#include <hip/hip_bf16.h>

constexpr int B_ = 2, N_ = 4096, M_ = 4096, C_ = 128;

typedef __attribute__((ext_vector_type(8))) __bf16 bf16x8;
typedef __attribute__((ext_vector_type(4))) float f32x4;

// ---- KNN phase 1: per-(query, 256-candidate segment) register top-16 -------
// FROZEN selection semantics (R17/R19) with x8 ILP unroll (R22, verified).
__global__ __launch_bounds__(256) void knn_part_kernel(const float* __restrict__ pos1,
                                                       const float* __restrict__ pos2,
                                                       float* __restrict__ pd,
                                                       int* __restrict__ pi) {
  __shared__ float tX[256], tY[256], tZ[256], tS[256];
  int tid = threadIdx.x;
  int bn = blockIdx.x * 256 + tid;
  int b = bn >> 12, n = bn & 4095;
  int seg = blockIdx.y;
  const float* p1 = pos1 + (long)b * 3 * N_;
  float qx = p1[n], qy = p1[N_ + n], qz = p1[2 * N_ + n];
  float s1 = __fadd_rn(__fadd_rn(__fmul_rn(qx, qx), __fmul_rn(qy, qy)), __fmul_rn(qz, qz));
  const float* p2 = pos2 + (long)b * 3 * M_ + seg * 256;
  {
    float x = p2[tid], y = p2[M_ + tid], z = p2[2 * M_ + tid];
    tX[tid] = x; tY[tid] = y; tZ[tid] = z;
    tS[tid] = __fadd_rn(__fadd_rn(__fmul_rn(x, x), __fmul_rn(y, y)), __fmul_rn(z, z));
  }
  __syncthreads();
  float rd[16]; int ri[16];
#pragma unroll
  for (int k = 0; k < 16; k++) { rd[k] = 3.0e38f; ri[k] = 0; }
  for (int mm = 0; mm < 256; mm += 8) {
    float dv[8];
#pragma unroll
    for (int u = 0; u < 8; u++) {
      float e = __fmaf_rn(qz, tZ[mm + u],
                          __fmaf_rn(qy, tY[mm + u], __fmul_rn(qx, tX[mm + u])));
      dv[u] = __fadd_rn(__fsub_rn(s1, __fadd_rn(e, e)), tS[mm + u]);
    }
    float thr = rd[15];
    bool any = false;
#pragma unroll
    for (int u = 0; u < 8; u++) any = any || (dv[u] < thr);
    if (any) {
#pragma unroll
      for (int u = 0; u < 8; u++) {
        float d = dv[u];
        if (d < rd[15]) {
          float cd = d; int ci = seg * 256 + mm + u;
#pragma unroll
          for (int k = 0; k < 16; k++) {
            bool lt = cd < rd[k];
            float td = lt ? rd[k] : cd;
            int ti = lt ? ri[k] : ci;
            rd[k] = lt ? cd : rd[k];
            ri[k] = lt ? ci : ri[k];
            cd = td; ci = ti;
          }
        }
      }
    }
  }
  long base = (long)seg * 16 * 8192 + bn;
#pragma unroll
  for (int k = 0; k < 16; k++) {
    pd[base + (long)k * 8192] = rd[k];
    pi[base + (long)k * 8192] = ri[k];
  }
}

// ---- KNN phase 2: merge 16 sorted lists of 16 per query (frozen) -----------
__global__ __launch_bounds__(256) void knn_merge_kernel(const float* __restrict__ pd,
                                                        const int* __restrict__ pi,
                                                        int* __restrict__ idx) {
  int bn = blockIdx.x * 256 + threadIdx.x;
  float rd[16]; int ri[16];
#pragma unroll
  for (int k = 0; k < 16; k++) { rd[k] = 3.0e38f; ri[k] = 0; }
  for (int seg = 0; seg < 16; seg++) {
    for (int k = 0; k < 16; k++) {
      float d = pd[((long)seg * 16 + k) * 8192 + bn];
      if (d >= rd[15]) break;
      int ci = pi[((long)seg * 16 + k) * 8192 + bn];
      float cd = d;
#pragma unroll
      for (int j = 0; j < 16; j++) {
        bool lt = cd < rd[j];
        float td = lt ? rd[j] : cd;
        int ti = lt ? ri[j] : ci;
        rd[j] = lt ? cd : rd[j];
        ri[j] = lt ? ci : ri[j];
        cd = td; ci = ti;
      }
    }
  }
#pragma unroll
  for (int k = 0; k < 16; k++) idx[(long)bn * 16 + k] = ri[k];
}

// ------------- layer0 decomposition: 131-wide GEMM over points --------------
__global__ __launch_bounds__(128) void g131_kernel(const float* __restrict__ pos,
                                                   const float* __restrict__ feat,
                                                   const float* __restrict__ w0,
                                                   float* __restrict__ out,
                                                   float sign, int woff) {
  __shared__ float Xs[131 * 16];
  int tid = threadIdx.x;
  long b = blockIdx.x >> 8;
  int i0 = (blockIdx.x & 255) * 16;
  for (int e = tid; e < 131 * 16; e += 128) {
    int r = e & 15, c = e >> 4;
    float v = (c < 3) ? sign * pos[b * 3 * N_ + (long)c * N_ + i0 + r]
                      : feat[b * C_ * N_ + (long)(c - 3) * N_ + i0 + r];
    Xs[c * 16 + r] = v;
  }
  __syncthreads();
  int o = tid;
  float acc[16];
#pragma unroll
  for (int r = 0; r < 16; r++) acc[r] = 0.f;
  for (int c = 0; c < 131; c++) {
    float wv = w0[(long)o * 259 + (c < 3 ? c : (woff + c - 3))];
    const float* xr = &Xs[c * 16];
#pragma unroll
    for (int r = 0; r < 16; r++) acc[r] = fmaf(xr[r], wv, acc[r]);
  }
#pragma unroll
  for (int r = 0; r < 16; r++) out[((b << 12) + i0 + r) * 128 + o] = acc[r];
}

// ------------- BN0 stats from (idx, A1, A2), no z0 store --------------------
__global__ __launch_bounds__(256) void z0stats_kernel(const int* __restrict__ idx,
                                                      const float* __restrict__ A1,
                                                      const float* __restrict__ A2,
                                                      double* __restrict__ st) {
  int tid = threadIdx.x;
  int o = tid & 127, half = tid >> 7;
  float sum = 0.f, sq = 0.f;
  int g0 = blockIdx.x * 32;
  for (int gi = 0; gi < 32; gi++) {
    int bn = g0 + gi;
    long b = bn >> 12;
    float a1 = A1[(long)bn * 128 + o];
    for (int k = half; k < 16; k += 2) {
      int m = idx[bn * 16 + k];
      float v = A2[(b * 4096 + m) * 128 + o] + a1;
      sum += v;
      sq += v * v;
    }
  }
  __shared__ float ls[256], lq[256];
  ls[tid] = sum; lq[tid] = sq;
  __syncthreads();
  if (tid < 128) {
    atomicAdd(&st[o], (double)(ls[tid] + ls[tid + 128]));
    atomicAdd(&st[128 + o], (double)(lq[tid] + lq[tid + 128]));
  }
}

// ------------- per-channel stats over bf16 (nrows x 128) --------------------
__global__ __launch_bounds__(256) void statsb_kernel(const __hip_bfloat16* __restrict__ Z,
                                                     long nrows, double* __restrict__ st) {
  int tid = threadIdx.x;
  int c = tid & 127, sub = tid >> 7;
  long slot = (long)blockIdx.x * 2 + sub;
  long stride = (long)gridDim.x * 2;
  float sum = 0.f, sq = 0.f;
  for (long r = slot; r < nrows; r += stride) {
    float v = __bfloat162float(Z[r * 128 + c]);
    sum += v;
    sq += v * v;
  }
  __shared__ float ls[256], lq[256];
  ls[tid] = sum; lq[tid] = sq;
  __syncthreads();
  if (tid < 128) {
    atomicAdd(&st[c], (double)(ls[tid] + ls[tid + 128]));
    atomicAdd(&st[128 + c], (double)(lq[tid] + lq[tid + 128]));
  }
}

// ------------- BN finalize: fold mean/var/g/b into scale+shift --------------
__global__ void bnfin_kernel(const double* __restrict__ st, const float* __restrict__ g,
                             const float* __restrict__ bb, float* __restrict__ sc,
                             float* __restrict__ sh, int CO, double inv) {
  int c = threadIdx.x;
  if (c < CO) {
    double mu = st[c] * inv;
    double var = st[CO + c] * inv - mu * mu;
    double rstd = 1.0 / sqrt(var + 1e-5);
    double scv = (double)g[c] * rstd;
    sc[c] = (float)scv;
    sh[c] = (float)((double)bb[c] - mu * scv);
  }
}

// ---- MFMA z1 pass: z1 = BN0ReLU(gather(A2)+A1) @ w1^T -> bf16 --------------
__global__ __launch_bounds__(256) void gemm1_mfma_kernel(
    const float* __restrict__ A2, const float* __restrict__ A1,
    const int* __restrict__ idxp, const float* __restrict__ w1,
    const float* __restrict__ sc0, const float* __restrict__ sh0,
    __hip_bfloat16* __restrict__ z1b) {
  __shared__ unsigned short As[64 * 136];
  __shared__ unsigned short Bs[64 * 136];
  __shared__ float scs[128], shs[128];
  int tid = threadIdx.x;
  int lane = tid & 63, w = tid >> 6;
  int cb = blockIdx.x;
  long r0 = (long)blockIdx.y * 64;
  int c0 = cb * 64;
  if (tid < 128) { scs[tid] = sc0[tid]; shs[tid] = sh0[tid]; }
  __syncthreads();
  {
    int row = tid >> 2, kb = (tid & 3) * 32;
    long g = r0 + row;
    int m = idxp[g];
    const float* a2p = &A2[(((g >> 16) << 12) + m) * 128 + kb];
    const float* a1p = &A1[(g >> 4) * 128 + kb];
    unsigned short* ap = &As[row * 136 + kb];
    const float* wp = &w1[(long)(c0 + row) * 128 + kb];
    unsigned short* bp = &Bs[row * 136 + kb];
#pragma unroll
    for (int h = 0; h < 4; h++) {
      union { unsigned short u[8]; uint4 v; } oa, ob;
#pragma unroll
      for (int j = 0; j < 8; j++) {
        int k = kb + h * 8 + j;
        float raw = a2p[h * 8 + j] + a1p[h * 8 + j];
        float v = fmaxf(0.f, fmaf(raw, scs[k], shs[k]));
        oa.u[j] = __bfloat16_as_ushort(__float2bfloat16(v));
        ob.u[j] = __bfloat16_as_ushort(__float2bfloat16(wp[h * 8 + j]));
      }
      *reinterpret_cast<uint4*>(ap + h * 8) = oa.v;
      *reinterpret_cast<uint4*>(bp + h * 8) = ob.v;
    }
  }
  __syncthreads();

  int fr = lane & 15, fk = (lane >> 4) * 8;
  bf16x8 a[4];
#pragma unroll
  for (int kk = 0; kk < 4; kk++)
    a[kk] = *reinterpret_cast<const bf16x8*>(&As[(w * 16 + fr) * 136 + kk * 32 + fk]);
  f32x4 acc[4];
#pragma unroll
  for (int n2 = 0; n2 < 4; n2++) {
    acc[n2] = (f32x4){0.f, 0.f, 0.f, 0.f};
#pragma unroll
    for (int kk = 0; kk < 4; kk++) {
      bf16x8 bfrag = *reinterpret_cast<const bf16x8*>(&Bs[(n2 * 16 + fr) * 136 + kk * 32 + fk]);
      acc[n2] = __builtin_amdgcn_mfma_f32_16x16x32_bf16(a[kk], bfrag, acc[n2], 0, 0, 0);
    }
  }
#pragma unroll
  for (int n2 = 0; n2 < 4; n2++) {
#pragma unroll
    for (int r = 0; r < 4; r++) {
      long row = r0 + w * 16 + (lane >> 4) * 4 + r;
      z1b[row * 128 + c0 + n2 * 16 + fr] = __float2bfloat16(acc[n2][r]);
    }
  }
}

// ---- MFMA z2 pass: C = BN1ReLU(z1b) @ w2^T, 64x64 tile, 4 waves ------------
template <int EPI>
__global__ __launch_bounds__(256) void gemm2_mfma_kernel(
    const __hip_bfloat16* __restrict__ z1b, const float* __restrict__ w2,
    const float* __restrict__ sc1, const float* __restrict__ sh1,
    const float* __restrict__ sc2, const float* __restrict__ sh2,
    float* __restrict__ feat, double* __restrict__ st) {
  __shared__ unsigned short As[64 * 136];
  __shared__ unsigned short Bs[64 * 136];
  __shared__ float scs[128], shs[128];
  __shared__ float Sred[4 * 64], Qred[4 * 64];
  int tid = threadIdx.x;
  int lane = tid & 63, w = tid >> 6;
  int cb = blockIdx.x;
  long r0 = (long)blockIdx.y * 64;
  int c0 = cb * 64;
  if (tid < 128) { scs[tid] = sc1[tid]; shs[tid] = sh1[tid]; }
  __syncthreads();
  {
    int row = tid >> 2, kb = (tid & 3) * 32;
    const __hip_bfloat16* zp = &z1b[(r0 + row) * 128 + kb];
    unsigned short* ap = &As[row * 136 + kb];
    const float* wp = &w2[(long)(c0 + row) * 128 + kb];
    unsigned short* bp = &Bs[row * 136 + kb];
#pragma unroll
    for (int h = 0; h < 4; h++) {
      union { unsigned short u[8]; uint4 v; } in, oa, ob;
      in.v = *reinterpret_cast<const uint4*>(zp + h * 8);
#pragma unroll
      for (int j = 0; j < 8; j++) {
        int k = kb + h * 8 + j;
        float f = __bfloat162float(__ushort_as_bfloat16(in.u[j]));
        float v = fmaxf(0.f, fmaf(f, scs[k], shs[k]));
        oa.u[j] = __bfloat16_as_ushort(__float2bfloat16(v));
        ob.u[j] = __bfloat16_as_ushort(__float2bfloat16(wp[h * 8 + j]));
      }
      *reinterpret_cast<uint4*>(ap + h * 8) = oa.v;
      *reinterpret_cast<uint4*>(bp + h * 8) = ob.v;
    }
  }
  __syncthreads();

  int fr = lane & 15, fk = (lane >> 4) * 8;
  bf16x8 a[4];
#pragma unroll
  for (int kk = 0; kk < 4; kk++)
    a[kk] = *reinterpret_cast<const bf16x8*>(&As[(w * 16 + fr) * 136 + kk * 32 + fk]);
  f32x4 acc[4];
#pragma unroll
  for (int n2 = 0; n2 < 4; n2++) {
    acc[n2] = (f32x4){0.f, 0.f, 0.f, 0.f};
#pragma unroll
    for (int kk = 0; kk < 4; kk++) {
      bf16x8 bfrag = *reinterpret_cast<const bf16x8*>(&Bs[(n2 * 16 + fr) * 136 + kk * 32 + fk]);
      acc[n2] = __builtin_amdgcn_mfma_f32_16x16x32_bf16(a[kk], bfrag, acc[n2], 0, 0, 0);
    }
  }

  if (EPI == 4) {
#pragma unroll
    for (int n2 = 0; n2 < 4; n2++) {
      float s = 0.f, q = 0.f;
#pragma unroll
      for (int r = 0; r < 4; r++) { s += acc[n2][r]; q += acc[n2][r] * acc[n2][r]; }
      s += __shfl_xor(s, 16); s += __shfl_xor(s, 32);
      q += __shfl_xor(q, 16); q += __shfl_xor(q, 32);
      if (lane < 16) { Sred[w * 64 + n2 * 16 + fr] = s; Qred[w * 64 + n2 * 16 + fr] = q; }
    }
    __syncthreads();
    if (tid < 64) {
      float S = Sred[tid] + Sred[64 + tid] + Sred[128 + tid] + Sred[192 + tid];
      float Q = Qred[tid] + Qred[64 + tid] + Qred[128 + tid] + Qred[192 + tid];
      atomicAdd(&st[c0 + tid], (double)S);
      atomicAdd(&st[256 + c0 + tid], (double)Q);
    }
  } else {
    int bn = (int)(r0 >> 4) + w;
#pragma unroll
    for (int n2 = 0; n2 < 4; n2++) {
      int c = c0 + n2 * 16 + fr;
      float scv = sc2[c], shv = sh2[c];
      float mx = -1e30f, sm = 0.f;
#pragma unroll
      for (int r = 0; r < 4; r++) {
        float v = fmaxf(0.f, fmaf(acc[n2][r], scv, shv));
        mx = fmaxf(mx, v);
        sm += v;
      }
      mx = fmaxf(mx, __shfl_xor(mx, 16)); mx = fmaxf(mx, __shfl_xor(mx, 32));
      sm += __shfl_xor(sm, 16); sm += __shfl_xor(sm, 32);
      if (lane < 16) {
        feat[(long)bn * 512 + c] = mx;
        feat[(long)bn * 512 + 256 + c] = sm * (1.f / 16.f);
      }
    }
  }
}

// ------------- tiled GEMM: out = act(X) * W^T (+epilogues), f32 accum -------
// EPI 2: +bias +res -> f32 ; EPI 3: +bias -> f32 transposed (B,CO,4096)
// EPI 7: +bias -> bf16 scatter (b,h,n,64)  [Q,K]
// EPI 8: +bias -> bf16 TRANSPOSED per head (b,h,64,4096)  [V]
template <int EPI, int XM, bool BN>
__global__ __launch_bounds__(256) void gemm_kernel(
    const void* __restrict__ Xv, const float* __restrict__ W, float* __restrict__ out,
    int K, int CO, const float* __restrict__ bias, const float* __restrict__ sc,
    const float* __restrict__ sh, const float* __restrict__ res,
    __hip_bfloat16* __restrict__ obf, const float* __restrict__ A1,
    const int* __restrict__ idxp, double* __restrict__ st) {
  __shared__ float S[2][32 * 68];
  int tid = threadIdx.x;
  int tx = tid & 15, ty = tid >> 4;
  int cb = blockIdx.x;
  long r0 = (long)blockIdx.y * 64;
  int c0 = cb * 64;
  float acc[4][4];
#pragma unroll
  for (int i = 0; i < 4; i++)
#pragma unroll
    for (int j = 0; j < 4; j++) acc[i][j] = 0.f;

  for (int k0 = 0; k0 < K; k0 += 32) {
    if (XM != 1) {
      int c = tid & 31, rr = tid >> 5;
      float scv = 0.f, shv = 0.f;
      if (BN) { scv = sc[k0 + c]; shv = sh[k0 + c]; }
#pragma unroll
      for (int i = 0; i < 8; i++) {
        int r = rr + i * 8;
        long g = r0 + r;
        float v = ((const float*)Xv)[g * K + k0 + c];
        if (BN) v = fmaxf(0.f, fmaf(v, scv, shv));
        S[0][c * 68 + r] = v;
      }
    } else {
      int m = tid & 63, cc = tid >> 6;
      long b = r0 >> 12;
      long mg = (r0 & 4095) + m;
#pragma unroll
      for (int i = 0; i < 8; i++) {
        int c = cc + i * 4;
        S[0][c * 68 + m] = ((const float*)Xv)[(b * K + k0 + c) * 4096 + mg];
      }
    }
    {
      int c = tid & 31, oo = tid >> 5;
#pragma unroll
      for (int i = 0; i < 8; i++) {
        int o = oo + i * 8;
        S[1][c * 68 + o] = W[(long)(c0 + o) * K + k0 + c];
      }
    }
    __syncthreads();
#pragma unroll
    for (int kk = 0; kk < 32; kk++) {
      float4 a = *reinterpret_cast<const float4*>(&S[0][kk * 68 + ty * 4]);
      float4 bv = *reinterpret_cast<const float4*>(&S[1][kk * 68 + tx * 4]);
      float av[4] = {a.x, a.y, a.z, a.w};
      float bw[4] = {bv.x, bv.y, bv.z, bv.w};
#pragma unroll
      for (int i = 0; i < 4; i++)
#pragma unroll
        for (int j = 0; j < 4; j++) acc[i][j] = fmaf(av[i], bw[j], acc[i][j]);
    }
    __syncthreads();
  }

  if (EPI == 2) {
    const float4 b4 = *reinterpret_cast<const float4*>(&bias[c0 + tx * 4]);
#pragma unroll
    for (int i = 0; i < 4; i++) {
      long r = r0 + ty * 4 + i;
      float4 f4 = *reinterpret_cast<const float4*>(&res[r * CO + c0 + tx * 4]);
      float4 o4 = make_float4(acc[i][0] + b4.x + f4.x, acc[i][1] + b4.y + f4.y,
                              acc[i][2] + b4.z + f4.z, acc[i][3] + b4.w + f4.w);
      *reinterpret_cast<float4*>(&out[r * CO + c0 + tx * 4]) = o4;
    }
  } else if (EPI == 3) {
    float* Sf = &S[0][0];
#pragma unroll
    for (int j = 0; j < 4; j++) {
      float bj = bias[c0 + tx * 4 + j];
      float4 colv = make_float4(acc[0][j] + bj, acc[1][j] + bj, acc[2][j] + bj,
                                acc[3][j] + bj);
      *reinterpret_cast<float4*>(&Sf[(tx * 4 + j) * 68 + ty * 4]) = colv;
    }
    __syncthreads();
    long b = r0 >> 12;
    long n0 = (r0 & 4095);
    int n = tid & 63, oo = tid >> 6;
#pragma unroll
    for (int i = 0; i < 16; i++) {
      int o = oo + i * 4;
      out[(b * CO + c0 + o) * 4096L + n0 + n] = Sf[o * 68 + n];
    }
  } else if (EPI == 7) {
    long b = r0 >> 12;
    long nn = (r0 & 4095) + ty * 4;
    const float4 b4 = *reinterpret_cast<const float4*>(&bias[c0 + tx * 4]);
    __hip_bfloat16* Ob = obf + ((b * (CO >> 6) + cb) * 4096L) * 64;
#pragma unroll
    for (int i = 0; i < 4; i++) {
      union { unsigned short u[4]; uint2 v; } pk;
      pk.u[0] = __bfloat16_as_ushort(__float2bfloat16(acc[i][0] + b4.x));
      pk.u[1] = __bfloat16_as_ushort(__float2bfloat16(acc[i][1] + b4.y));
      pk.u[2] = __bfloat16_as_ushort(__float2bfloat16(acc[i][2] + b4.z));
      pk.u[3] = __bfloat16_as_ushort(__float2bfloat16(acc[i][3] + b4.w));
      *reinterpret_cast<uint2*>(&Ob[(nn + i) * 64 + tx * 4]) = pk.v;
    }
  } else if (EPI == 8) {
    float* Sf = &S[0][0];
#pragma unroll
    for (int j = 0; j < 4; j++) {
      float bj = bias[c0 + tx * 4 + j];
      float4 colv = make_float4(acc[0][j] + bj, acc[1][j] + bj, acc[2][j] + bj,
                                acc[3][j] + bj);
      *reinterpret_cast<float4*>(&Sf[(tx * 4 + j) * 68 + ty * 4]) = colv;
    }
    __syncthreads();
    long b = r0 >> 12;
    long n0 = (r0 & 4095);
    int n = tid & 63, oo = tid >> 6;
#pragma unroll
    for (int i = 0; i < 16; i++) {
      int o = oo + i * 4;
      obf[((b * 4 + cb) * 64 + o) * 4096L + n0 + n] = __float2bfloat16(Sf[o * 68 + n]);
    }
  }
}

// ------- MFMA flash attention: bf16 inputs, V pre-transposed -----------------
__global__ __launch_bounds__(256) void flash_mfma_kernel(
    const __hip_bfloat16* __restrict__ Q, const __hip_bfloat16* __restrict__ Kb,
    const __hip_bfloat16* __restrict__ Vtg, float* __restrict__ O) {
  __shared__ unsigned short Ks[64 * 72];
  __shared__ unsigned short Vt[64 * 72];
  __shared__ unsigned short Ps[4][16 * 72];
  int tid = threadIdx.x;
  int lane = tid & 63, w = tid >> 6;
  int bh = blockIdx.x >> 6;
  int qt = blockIdx.x & 63;
  long base = (long)bh * 4096 * 64;
  int row0 = qt * 64 + w * 16;
  int fr = lane & 15;
  int fk = (lane >> 4) * 8;

  bf16x8 aq[2];
#pragma unroll
  for (int kk = 0; kk < 2; kk++)
    aq[kk] = *reinterpret_cast<const bf16x8*>(&Q[base + (long)(row0 + fr) * 64 + kk * 32 + fk]);

  f32x4 o[4];
#pragma unroll
  for (int i = 0; i < 4; i++) o[i] = (f32x4){0.f, 0.f, 0.f, 0.f};
  float m_run[4], l_run[4];
#pragma unroll
  for (int r = 0; r < 4; r++) { m_run[r] = -3.0e38f; l_run[r] = 0.f; }

  int skey = tid >> 2, sdc = (tid & 3) * 16;
  int vd = tid & 63, vkg = tid >> 6;
  int vsw = (vd ^ (vd >> 3)) & 7;

  for (int m0 = 0; m0 < 4096; m0 += 64) {
    __syncthreads();
    {  // K rows: 2x16B copies; V^T rows: 2x16B copies into swizzled blocks
      const __hip_bfloat16* kp = &Kb[base + (long)(m0 + skey) * 64 + sdc];
      *reinterpret_cast<uint4*>(&Ks[skey * 72 + sdc]) =
          *reinterpret_cast<const uint4*>(kp);
      *reinterpret_cast<uint4*>(&Ks[skey * 72 + sdc + 8]) =
          *reinterpret_cast<const uint4*>(kp + 8);
#pragma unroll
      for (int j8 = 0; j8 < 2; j8++) {
        int k0 = vkg * 16 + j8 * 8;
        int kb = k0 >> 3;
        *reinterpret_cast<uint4*>(&Vt[vd * 72 + ((kb ^ vsw) << 3)]) =
            *reinterpret_cast<const uint4*>(&Vtg[base + (long)vd * 4096 + m0 + k0]);
      }
    }
    __syncthreads();

    f32x4 s[4];
#pragma unroll
    for (int n = 0; n < 4; n++) {
      s[n] = (f32x4){0.f, 0.f, 0.f, 0.f};
#pragma unroll
      for (int kk = 0; kk < 2; kk++) {
        bf16x8 bk = *reinterpret_cast<const bf16x8*>(&Ks[(n * 16 + fr) * 72 + kk * 32 + fk]);
        s[n] = __builtin_amdgcn_mfma_f32_16x16x32_bf16(aq[kk], bk, s[n], 0, 0, 0);
      }
    }

    float p[4][4];
#pragma unroll
    for (int r = 0; r < 4; r++) {
      float sv0 = s[0][r] * 0.125f, sv1 = s[1][r] * 0.125f;
      float sv2 = s[2][r] * 0.125f, sv3 = s[3][r] * 0.125f;
      float mx = fmaxf(fmaxf(sv0, sv1), fmaxf(sv2, sv3));
      mx = fmaxf(mx, __shfl_xor(mx, 1));
      mx = fmaxf(mx, __shfl_xor(mx, 2));
      mx = fmaxf(mx, __shfl_xor(mx, 4));
      mx = fmaxf(mx, __shfl_xor(mx, 8));
      float mn = fmaxf(m_run[r], mx);
      float fac = __expf(m_run[r] - mn);
      p[0][r] = __expf(sv0 - mn);
      p[1][r] = __expf(sv1 - mn);
      p[2][r] = __expf(sv2 - mn);
      p[3][r] = __expf(sv3 - mn);
      float rs = (p[0][r] + p[1][r]) + (p[2][r] + p[3][r]);
      rs += __shfl_xor(rs, 1);
      rs += __shfl_xor(rs, 2);
      rs += __shfl_xor(rs, 4);
      rs += __shfl_xor(rs, 8);
      l_run[r] = l_run[r] * fac + rs;
      m_run[r] = mn;
#pragma unroll
      for (int n2 = 0; n2 < 4; n2++) o[n2][r] *= fac;
    }

    unsigned short* pw = &Ps[w][0];
#pragma unroll
    for (int r = 0; r < 4; r++) {
      int prow = (lane >> 4) * 4 + r;
#pragma unroll
      for (int n = 0; n < 4; n++)
        pw[prow * 72 + n * 16 + fr] = __bfloat16_as_ushort(__float2bfloat16(p[n][r]));
    }
    bf16x8 ap[2];
#pragma unroll
    for (int kk = 0; kk < 2; kk++)
      ap[kk] = *reinterpret_cast<const bf16x8*>(&pw[fr * 72 + kk * 32 + fk]);

#pragma unroll
    for (int n2 = 0; n2 < 4; n2++) {
      int d = n2 * 16 + fr;
      int dsw = (d ^ (d >> 3)) & 7;
#pragma unroll
      for (int kk = 0; kk < 2; kk++) {
        int kb = kk * 4 + (lane >> 4);
        bf16x8 bv = *reinterpret_cast<const bf16x8*>(&Vt[d * 72 + ((kb ^ dsw) << 3)]);
        o[n2] = __builtin_amdgcn_mfma_f32_16x16x32_bf16(ap[kk], bv, o[n2], 0, 0, 0);
      }
    }
  }

  int b = bh >> 2, h = bh & 3;
#pragma unroll
  for (int r = 0; r < 4; r++) {
    float inv = 1.f / l_run[r];
    long nrow = (long)(b * 4096 + qt * 64 + w * 16 + (lane >> 4) * 4 + r);
#pragma unroll
    for (int n2 = 0; n2 < 4; n2++) {
      O[nrow * 256 + h * 64 + n2 * 16 + fr] = o[n2][r] * inv;
    }
  }
}

// ------------- LayerNorm over 512 (one row per block) -----------------------
__global__ __launch_bounds__(256) void ln_kernel(float* __restrict__ y,
                                                 const float* __restrict__ lng,
                                                 const float* __restrict__ lnb) {
  long r = blockIdx.x;
  int tid = threadIdx.x;
  float v0 = y[r * 512 + tid];
  float v1 = y[r * 512 + 256 + tid];
  float s = v0 + v1;
  float q = v0 * v0 + v1 * v1;
#pragma unroll
  for (int off = 1; off < 64; off <<= 1) {
    s += __shfl_xor(s, off);
    q += __shfl_xor(q, off);
  }
  __shared__ float red[8];
  __shared__ float mv[2];
  int w = tid >> 6;
  if ((tid & 63) == 0) { red[w] = s; red[4 + w] = q; }
  __syncthreads();
  if (tid == 0) {
    float S = red[0] + red[1] + red[2] + red[3];
    float Q2 = red[4] + red[5] + red[6] + red[7];
    float mu = S * (1.f / 512.f);
    float var = Q2 * (1.f / 512.f) - mu * mu;
    mv[0] = mu;
    mv[1] = rsqrtf(var + 1e-5f);
  }
  __syncthreads();
  float mu = mv[0], rstd = mv[1];
  y[r * 512 + tid] = (v0 - mu) * rstd * lng[tid] + lnb[tid];
  y[r * 512 + 256 + tid] = (v1 - mu) * rstd * lng[256 + tid] + lnb[256 + tid];
}

// ------------- output 0: pos1 passthrough, f32 -> f32 ------------------------
__global__ void poscopy_kernel(const float* __restrict__ p, float* __restrict__ o) {
  int i = blockIdx.x * 256 + threadIdx.x;
  o[i] = p[i];
}

extern "C" void kernel_launch(void* const* d_in, const int* in_sizes, int n_in,
                              void* d_out, int out_size, void* d_ws, size_t ws_size,
                              hipStream_t stream) {
  (void)in_sizes; (void)n_in; (void)out_size; (void)ws_size;
  const float* pos1 = (const float*)d_in[0];
  const float* pos2 = (const float*)d_in[1];
  const float* f1 = (const float*)d_in[2];
  const float* f2 = (const float*)d_in[3];
  const float* w0 = (const float*)d_in[4];
  const float* g0 = (const float*)d_in[5];
  const float* b0 = (const float*)d_in[6];
  const float* w1 = (const float*)d_in[7];
  const float* g1 = (const float*)d_in[8];
  const float* b1 = (const float*)d_in[9];
  const float* w2 = (const float*)d_in[10];
  const float* g2 = (const float*)d_in[11];
  const float* b2 = (const float*)d_in[12];
  const float* qw = (const float*)d_in[13];
  const float* qb = (const float*)d_in[14];
  const float* kw = (const float*)d_in[15];
  const float* kb = (const float*)d_in[16];
  const float* vw = (const float*)d_in[17];
  const float* vb = (const float*)d_in[18];
  const float* ow = (const float*)d_in[19];
  const float* obv = (const float*)d_in[20];
  const float* lng = (const float*)d_in[21];
  const float* lnb = (const float*)d_in[22];
  const float* fw = (const float*)d_in[23];
  const float* fb = (const float*)d_in[24];

  // ws layout (proven <=72MB):
  // phase A: z1b bf16 [0,32MB) ; idx 32MB ; A1 33MB ; A2 37MB ; stats 48MB ;
  //          pd [56,64) ; pi [64,72)
  // phase B (post-gemm2): Qbf [0,4) ; Kbf [8,12) ; Vtg [16,20) ; attno [24,32) f32 ;
  //          feat [32,48) f32 ; y0 [0,16) f32 after flash.
  char* ws = (char*)d_ws;
  __hip_bfloat16* z1b = (__hip_bfloat16*)(ws);
  __hip_bfloat16* Qbf = (__hip_bfloat16*)(ws);
  __hip_bfloat16* Kbf = (__hip_bfloat16*)(ws + (8ull << 20));
  __hip_bfloat16* Vtg = (__hip_bfloat16*)(ws + (16ull << 20));
  float* attno = (float*)(ws + (24ull << 20));
  float* y0 = (float*)(ws);
  int* idx = (int*)(ws + (32ull << 20));
  float* A1 = (float*)(ws + (33ull << 20));
  float* A2 = (float*)(ws + (37ull << 20));
  float* feat = (float*)(ws + (32ull << 20));
  char* statp = ws + (48ull << 20);
  float* pd = (float*)(ws + (56ull << 20));
  int* pi = (int*)(ws + (64ull << 20));
  double* st0 = (double*)(statp);
  double* st1 = (double*)(statp + 2048);
  double* st2 = (double*)(statp + 4096);
  float* sc0 = (float*)(statp + 8192);
  float* sh0 = (float*)(statp + 8704);
  float* sc1 = (float*)(statp + 9216);
  float* sh1 = (float*)(statp + 9728);
  float* sc2 = (float*)(statp + 10240);
  float* sh2 = (float*)(statp + 11264);

  float* out0 = (float*)d_out;
  float* out1 = out0 + 24576;

  hipMemsetAsync(statp, 0, 8192, stream);

  knn_part_kernel<<<dim3(32, 16), 256, 0, stream>>>(pos1, pos2, pd, pi);
  knn_merge_kernel<<<32, 256, 0, stream>>>(pd, pi, idx);
  g131_kernel<<<512, 128, 0, stream>>>(pos2, f2, w0, A2, 1.f, 3);
  g131_kernel<<<512, 128, 0, stream>>>(pos1, f1, w0, A1, -1.f, 131);
  z0stats_kernel<<<256, 256, 0, stream>>>(idx, A1, A2, st0);
  bnfin_kernel<<<1, 256, 0, stream>>>(st0, g0, b0, sc0, sh0, 128, 1.0 / 131072.0);
  gemm1_mfma_kernel<<<dim3(2, 2048), 256, 0, stream>>>(
      A2, A1, idx, w1, sc0, sh0, z1b);
  statsb_kernel<<<512, 256, 0, stream>>>(z1b, 131072L, st1);
  bnfin_kernel<<<1, 256, 0, stream>>>(st1, g1, b1, sc1, sh1, 128, 1.0 / 131072.0);
  gemm2_mfma_kernel<4><<<dim3(4, 2048), 256, 0, stream>>>(
      z1b, w2, sc1, sh1, nullptr, nullptr, nullptr, st2);
  bnfin_kernel<<<1, 256, 0, stream>>>(st2, g2, b2, sc2, sh2, 256, 1.0 / 131072.0);
  gemm2_mfma_kernel<5><<<dim3(4, 2048), 256, 0, stream>>>(
      z1b, w2, sc1, sh1, sc2, sh2, feat, nullptr);
  gemm_kernel<7, 0, false><<<dim3(4, 128), 256, 0, stream>>>(
      feat, qw, nullptr, 512, 256, qb, nullptr, nullptr, nullptr, Qbf, nullptr, nullptr, nullptr);
  gemm_kernel<7, 1, false><<<dim3(4, 128), 256, 0, stream>>>(
      f2, kw, nullptr, 128, 256, kb, nullptr, nullptr, nullptr, Kbf, nullptr, nullptr, nullptr);
  gemm_kernel<8, 1, false><<<dim3(4, 128), 256, 0, stream>>>(
      f2, vw, nullptr, 128, 256, vb, nullptr, nullptr, nullptr, Vtg, nullptr, nullptr, nullptr);
  flash_mfma_kernel<<<512, 256, 0, stream>>>(Qbf, Kbf, Vtg, attno);
  gemm_kernel<2, 0, false><<<dim3(8, 128), 256, 0, stream>>>(
      attno, ow, y0, 256, 512, obv, nullptr, nullptr, feat, nullptr, nullptr, nullptr, nullptr);
  ln_kernel<<<8192, 256, 0, stream>>>(y0, lng, lnb);
  gemm_kernel<3, 0, false><<<dim3(4, 128), 256, 0, stream>>>(
      y0, fw, out1, 512, 256, fb, nullptr, nullptr, nullptr, nullptr, nullptr, nullptr, nullptr);
  poscopy_kernel<<<96, 256, 0, stream>>>(pos1, out0);
}

// Round 24
// 792.528 us; speedup vs baseline: 3.6470x; 1.0152x over previous
//
#include <hip/hip_runtime.h>
#include <hip/hip_bf16.h>

constexpr int B_ = 2, N_ = 4096, M_ = 4096, C_ = 128;

typedef __attribute__((ext_vector_type(8))) __bf16 bf16x8;
typedef __attribute__((ext_vector_type(4))) float f32x4;

// ---- KNN phase 1: per-(query, 256-candidate segment) register top-16 -------
// FROZEN selection semantics (R17/R19) with x8 ILP unroll (R22, verified).
__global__ __launch_bounds__(256) void knn_part_kernel(const float* __restrict__ pos1,
                                                       const float* __restrict__ pos2,
                                                       float* __restrict__ pd,
                                                       int* __restrict__ pi) {
  __shared__ float tX[256], tY[256], tZ[256], tS[256];
  int tid = threadIdx.x;
  int bn = blockIdx.x * 256 + tid;
  int b = bn >> 12, n = bn & 4095;
  int seg = blockIdx.y;
  const float* p1 = pos1 + (long)b * 3 * N_;
  float qx = p1[n], qy = p1[N_ + n], qz = p1[2 * N_ + n];
  float s1 = __fadd_rn(__fadd_rn(__fmul_rn(qx, qx), __fmul_rn(qy, qy)), __fmul_rn(qz, qz));
  const float* p2 = pos2 + (long)b * 3 * M_ + seg * 256;
  {
    float x = p2[tid], y = p2[M_ + tid], z = p2[2 * M_ + tid];
    tX[tid] = x; tY[tid] = y; tZ[tid] = z;
    tS[tid] = __fadd_rn(__fadd_rn(__fmul_rn(x, x), __fmul_rn(y, y)), __fmul_rn(z, z));
  }
  __syncthreads();
  float rd[16]; int ri[16];
#pragma unroll
  for (int k = 0; k < 16; k++) { rd[k] = 3.0e38f; ri[k] = 0; }
  for (int mm = 0; mm < 256; mm += 8) {
    float dv[8];
#pragma unroll
    for (int u = 0; u < 8; u++) {
      float e = __fmaf_rn(qz, tZ[mm + u],
                          __fmaf_rn(qy, tY[mm + u], __fmul_rn(qx, tX[mm + u])));
      dv[u] = __fadd_rn(__fsub_rn(s1, __fadd_rn(e, e)), tS[mm + u]);
    }
    float thr = rd[15];
    bool any = false;
#pragma unroll
    for (int u = 0; u < 8; u++) any = any || (dv[u] < thr);
    if (any) {
#pragma unroll
      for (int u = 0; u < 8; u++) {
        float d = dv[u];
        if (d < rd[15]) {
          float cd = d; int ci = seg * 256 + mm + u;
#pragma unroll
          for (int k = 0; k < 16; k++) {
            bool lt = cd < rd[k];
            float td = lt ? rd[k] : cd;
            int ti = lt ? ri[k] : ci;
            rd[k] = lt ? cd : rd[k];
            ri[k] = lt ? ci : ri[k];
            cd = td; ci = ti;
          }
        }
      }
    }
  }
  long base = (long)seg * 16 * 8192 + bn;
#pragma unroll
  for (int k = 0; k < 16; k++) {
    pd[base + (long)k * 8192] = rd[k];
    pi[base + (long)k * 8192] = ri[k];
  }
}

// ---- KNN phase 2: merge 16 sorted lists of 16 per query (frozen) -----------
__global__ __launch_bounds__(256) void knn_merge_kernel(const float* __restrict__ pd,
                                                        const int* __restrict__ pi,
                                                        int* __restrict__ idx) {
  int bn = blockIdx.x * 256 + threadIdx.x;
  float rd[16]; int ri[16];
#pragma unroll
  for (int k = 0; k < 16; k++) { rd[k] = 3.0e38f; ri[k] = 0; }
  for (int seg = 0; seg < 16; seg++) {
    for (int k = 0; k < 16; k++) {
      float d = pd[((long)seg * 16 + k) * 8192 + bn];
      if (d >= rd[15]) break;
      int ci = pi[((long)seg * 16 + k) * 8192 + bn];
      float cd = d;
#pragma unroll
      for (int j = 0; j < 16; j++) {
        bool lt = cd < rd[j];
        float td = lt ? rd[j] : cd;
        int ti = lt ? ri[j] : ci;
        rd[j] = lt ? cd : rd[j];
        ri[j] = lt ? ci : ri[j];
        cd = td; ci = ti;
      }
    }
  }
#pragma unroll
  for (int k = 0; k < 16; k++) idx[(long)bn * 16 + k] = ri[k];
}

// ------------- layer0 decomposition: 131-wide GEMM over points --------------
__global__ __launch_bounds__(128) void g131_kernel(const float* __restrict__ pos,
                                                   const float* __restrict__ feat,
                                                   const float* __restrict__ w0,
                                                   float* __restrict__ out,
                                                   float sign, int woff) {
  __shared__ float Xs[131 * 16];
  int tid = threadIdx.x;
  long b = blockIdx.x >> 8;
  int i0 = (blockIdx.x & 255) * 16;
  for (int e = tid; e < 131 * 16; e += 128) {
    int r = e & 15, c = e >> 4;
    float v = (c < 3) ? sign * pos[b * 3 * N_ + (long)c * N_ + i0 + r]
                      : feat[b * C_ * N_ + (long)(c - 3) * N_ + i0 + r];
    Xs[c * 16 + r] = v;
  }
  __syncthreads();
  int o = tid;
  float acc[16];
#pragma unroll
  for (int r = 0; r < 16; r++) acc[r] = 0.f;
  for (int c = 0; c < 131; c++) {
    float wv = w0[(long)o * 259 + (c < 3 ? c : (woff + c - 3))];
    const float* xr = &Xs[c * 16];
#pragma unroll
    for (int r = 0; r < 16; r++) acc[r] = fmaf(xr[r], wv, acc[r]);
  }
#pragma unroll
  for (int r = 0; r < 16; r++) out[((b << 12) + i0 + r) * 128 + o] = acc[r];
}

// ------------- BN0 stats from (idx, A1, A2), no z0 store --------------------
__global__ __launch_bounds__(256) void z0stats_kernel(const int* __restrict__ idx,
                                                      const float* __restrict__ A1,
                                                      const float* __restrict__ A2,
                                                      double* __restrict__ st) {
  int tid = threadIdx.x;
  int o = tid & 127, half = tid >> 7;
  float sum = 0.f, sq = 0.f;
  int g0 = blockIdx.x * 32;
  for (int gi = 0; gi < 32; gi++) {
    int bn = g0 + gi;
    long b = bn >> 12;
    float a1 = A1[(long)bn * 128 + o];
    for (int k = half; k < 16; k += 2) {
      int m = idx[bn * 16 + k];
      float v = A2[(b * 4096 + m) * 128 + o] + a1;
      sum += v;
      sq += v * v;
    }
  }
  __shared__ float ls[256], lq[256];
  ls[tid] = sum; lq[tid] = sq;
  __syncthreads();
  if (tid < 128) {
    atomicAdd(&st[o], (double)(ls[tid] + ls[tid + 128]));
    atomicAdd(&st[128 + o], (double)(lq[tid] + lq[tid + 128]));
  }
}

// ------------- per-channel stats over bf16 (nrows x 128) --------------------
__global__ __launch_bounds__(256) void statsb_kernel(const __hip_bfloat16* __restrict__ Z,
                                                     long nrows, double* __restrict__ st) {
  int tid = threadIdx.x;
  int c = tid & 127, sub = tid >> 7;
  long slot = (long)blockIdx.x * 2 + sub;
  long stride = (long)gridDim.x * 2;
  float sum = 0.f, sq = 0.f;
  for (long r = slot; r < nrows; r += stride) {
    float v = __bfloat162float(Z[r * 128 + c]);
    sum += v;
    sq += v * v;
  }
  __shared__ float ls[256], lq[256];
  ls[tid] = sum; lq[tid] = sq;
  __syncthreads();
  if (tid < 128) {
    atomicAdd(&st[c], (double)(ls[tid] + ls[tid + 128]));
    atomicAdd(&st[128 + c], (double)(lq[tid] + lq[tid + 128]));
  }
}

// ------------- BN finalize: fold mean/var/g/b into scale+shift --------------
__global__ void bnfin_kernel(const double* __restrict__ st, const float* __restrict__ g,
                             const float* __restrict__ bb, float* __restrict__ sc,
                             float* __restrict__ sh, int CO, double inv) {
  int c = threadIdx.x;
  if (c < CO) {
    double mu = st[c] * inv;
    double var = st[CO + c] * inv - mu * mu;
    double rstd = 1.0 / sqrt(var + 1e-5);
    double scv = (double)g[c] * rstd;
    sc[c] = (float)scv;
    sh[c] = (float)((double)bb[c] - mu * scv);
  }
}

// ---- MFMA z1 pass: z1 = BN0ReLU(gather(A2)+A1) @ w1^T -> bf16 --------------
__global__ __launch_bounds__(256) void gemm1_mfma_kernel(
    const float* __restrict__ A2, const float* __restrict__ A1,
    const int* __restrict__ idxp, const float* __restrict__ w1,
    const float* __restrict__ sc0, const float* __restrict__ sh0,
    __hip_bfloat16* __restrict__ z1b) {
  __shared__ unsigned short As[64 * 136];
  __shared__ unsigned short Bs[64 * 136];
  __shared__ float scs[128], shs[128];
  int tid = threadIdx.x;
  int lane = tid & 63, w = tid >> 6;
  int cb = blockIdx.x;
  long r0 = (long)blockIdx.y * 64;
  int c0 = cb * 64;
  if (tid < 128) { scs[tid] = sc0[tid]; shs[tid] = sh0[tid]; }
  __syncthreads();
  {
    int row = tid >> 2, kb = (tid & 3) * 32;
    long g = r0 + row;
    int m = idxp[g];
    const float* a2p = &A2[(((g >> 16) << 12) + m) * 128 + kb];
    const float* a1p = &A1[(g >> 4) * 128 + kb];
    unsigned short* ap = &As[row * 136 + kb];
    const float* wp = &w1[(long)(c0 + row) * 128 + kb];
    unsigned short* bp = &Bs[row * 136 + kb];
#pragma unroll
    for (int h = 0; h < 4; h++) {
      union { unsigned short u[8]; uint4 v; } oa, ob;
#pragma unroll
      for (int j = 0; j < 8; j++) {
        int k = kb + h * 8 + j;
        float raw = a2p[h * 8 + j] + a1p[h * 8 + j];
        float v = fmaxf(0.f, fmaf(raw, scs[k], shs[k]));
        oa.u[j] = __bfloat16_as_ushort(__float2bfloat16(v));
        ob.u[j] = __bfloat16_as_ushort(__float2bfloat16(wp[h * 8 + j]));
      }
      *reinterpret_cast<uint4*>(ap + h * 8) = oa.v;
      *reinterpret_cast<uint4*>(bp + h * 8) = ob.v;
    }
  }
  __syncthreads();

  int fr = lane & 15, fk = (lane >> 4) * 8;
  bf16x8 a[4];
#pragma unroll
  for (int kk = 0; kk < 4; kk++)
    a[kk] = *reinterpret_cast<const bf16x8*>(&As[(w * 16 + fr) * 136 + kk * 32 + fk]);
  f32x4 acc[4];
#pragma unroll
  for (int n2 = 0; n2 < 4; n2++) {
    acc[n2] = (f32x4){0.f, 0.f, 0.f, 0.f};
#pragma unroll
    for (int kk = 0; kk < 4; kk++) {
      bf16x8 bfrag = *reinterpret_cast<const bf16x8*>(&Bs[(n2 * 16 + fr) * 136 + kk * 32 + fk]);
      acc[n2] = __builtin_amdgcn_mfma_f32_16x16x32_bf16(a[kk], bfrag, acc[n2], 0, 0, 0);
    }
  }
#pragma unroll
  for (int n2 = 0; n2 < 4; n2++) {
#pragma unroll
    for (int r = 0; r < 4; r++) {
      long row = r0 + w * 16 + (lane >> 4) * 4 + r;
      z1b[row * 128 + c0 + n2 * 16 + fr] = __float2bfloat16(acc[n2][r]);
    }
  }
}

// ---- MFMA z2 pass: C = BN1ReLU(z1b) @ w2^T, 64x64 tile, 4 waves ------------
template <int EPI>
__global__ __launch_bounds__(256) void gemm2_mfma_kernel(
    const __hip_bfloat16* __restrict__ z1b, const float* __restrict__ w2,
    const float* __restrict__ sc1, const float* __restrict__ sh1,
    const float* __restrict__ sc2, const float* __restrict__ sh2,
    float* __restrict__ feat, double* __restrict__ st) {
  __shared__ unsigned short As[64 * 136];
  __shared__ unsigned short Bs[64 * 136];
  __shared__ float scs[128], shs[128];
  __shared__ float Sred[4 * 64], Qred[4 * 64];
  int tid = threadIdx.x;
  int lane = tid & 63, w = tid >> 6;
  int cb = blockIdx.x;
  long r0 = (long)blockIdx.y * 64;
  int c0 = cb * 64;
  if (tid < 128) { scs[tid] = sc1[tid]; shs[tid] = sh1[tid]; }
  __syncthreads();
  {
    int row = tid >> 2, kb = (tid & 3) * 32;
    const __hip_bfloat16* zp = &z1b[(r0 + row) * 128 + kb];
    unsigned short* ap = &As[row * 136 + kb];
    const float* wp = &w2[(long)(c0 + row) * 128 + kb];
    unsigned short* bp = &Bs[row * 136 + kb];
#pragma unroll
    for (int h = 0; h < 4; h++) {
      union { unsigned short u[8]; uint4 v; } in, oa, ob;
      in.v = *reinterpret_cast<const uint4*>(zp + h * 8);
#pragma unroll
      for (int j = 0; j < 8; j++) {
        int k = kb + h * 8 + j;
        float f = __bfloat162float(__ushort_as_bfloat16(in.u[j]));
        float v = fmaxf(0.f, fmaf(f, scs[k], shs[k]));
        oa.u[j] = __bfloat16_as_ushort(__float2bfloat16(v));
        ob.u[j] = __bfloat16_as_ushort(__float2bfloat16(wp[h * 8 + j]));
      }
      *reinterpret_cast<uint4*>(ap + h * 8) = oa.v;
      *reinterpret_cast<uint4*>(bp + h * 8) = ob.v;
    }
  }
  __syncthreads();

  int fr = lane & 15, fk = (lane >> 4) * 8;
  bf16x8 a[4];
#pragma unroll
  for (int kk = 0; kk < 4; kk++)
    a[kk] = *reinterpret_cast<const bf16x8*>(&As[(w * 16 + fr) * 136 + kk * 32 + fk]);
  f32x4 acc[4];
#pragma unroll
  for (int n2 = 0; n2 < 4; n2++) {
    acc[n2] = (f32x4){0.f, 0.f, 0.f, 0.f};
#pragma unroll
    for (int kk = 0; kk < 4; kk++) {
      bf16x8 bfrag = *reinterpret_cast<const bf16x8*>(&Bs[(n2 * 16 + fr) * 136 + kk * 32 + fk]);
      acc[n2] = __builtin_amdgcn_mfma_f32_16x16x32_bf16(a[kk], bfrag, acc[n2], 0, 0, 0);
    }
  }

  if (EPI == 4) {
#pragma unroll
    for (int n2 = 0; n2 < 4; n2++) {
      float s = 0.f, q = 0.f;
#pragma unroll
      for (int r = 0; r < 4; r++) { s += acc[n2][r]; q += acc[n2][r] * acc[n2][r]; }
      s += __shfl_xor(s, 16); s += __shfl_xor(s, 32);
      q += __shfl_xor(q, 16); q += __shfl_xor(q, 32);
      if (lane < 16) { Sred[w * 64 + n2 * 16 + fr] = s; Qred[w * 64 + n2 * 16 + fr] = q; }
    }
    __syncthreads();
    if (tid < 64) {
      float S = Sred[tid] + Sred[64 + tid] + Sred[128 + tid] + Sred[192 + tid];
      float Q = Qred[tid] + Qred[64 + tid] + Qred[128 + tid] + Qred[192 + tid];
      atomicAdd(&st[c0 + tid], (double)S);
      atomicAdd(&st[256 + c0 + tid], (double)Q);
    }
  } else {
    int bn = (int)(r0 >> 4) + w;
#pragma unroll
    for (int n2 = 0; n2 < 4; n2++) {
      int c = c0 + n2 * 16 + fr;
      float scv = sc2[c], shv = sh2[c];
      float mx = -1e30f, sm = 0.f;
#pragma unroll
      for (int r = 0; r < 4; r++) {
        float v = fmaxf(0.f, fmaf(acc[n2][r], scv, shv));
        mx = fmaxf(mx, v);
        sm += v;
      }
      mx = fmaxf(mx, __shfl_xor(mx, 16)); mx = fmaxf(mx, __shfl_xor(mx, 32));
      sm += __shfl_xor(sm, 16); sm += __shfl_xor(sm, 32);
      if (lane < 16) {
        feat[(long)bn * 512 + c] = mx;
        feat[(long)bn * 512 + 256 + c] = sm * (1.f / 16.f);
      }
    }
  }
}

// ------------- tiled GEMM: out = act(X) * W^T (+epilogues), f32 accum -------
template <int EPI, int XM, bool BN>
__global__ __launch_bounds__(256) void gemm_kernel(
    const void* __restrict__ Xv, const float* __restrict__ W, float* __restrict__ out,
    int K, int CO, const float* __restrict__ bias, const float* __restrict__ sc,
    const float* __restrict__ sh, const float* __restrict__ res,
    __hip_bfloat16* __restrict__ obf, const float* __restrict__ A1,
    const int* __restrict__ idxp, double* __restrict__ st) {
  __shared__ float S[2][32 * 68];
  int tid = threadIdx.x;
  int tx = tid & 15, ty = tid >> 4;
  int cb = blockIdx.x;
  long r0 = (long)blockIdx.y * 64;
  int c0 = cb * 64;
  float acc[4][4];
#pragma unroll
  for (int i = 0; i < 4; i++)
#pragma unroll
    for (int j = 0; j < 4; j++) acc[i][j] = 0.f;

  for (int k0 = 0; k0 < K; k0 += 32) {
    if (XM != 1) {
      int c = tid & 31, rr = tid >> 5;
      float scv = 0.f, shv = 0.f;
      if (BN) { scv = sc[k0 + c]; shv = sh[k0 + c]; }
#pragma unroll
      for (int i = 0; i < 8; i++) {
        int r = rr + i * 8;
        long g = r0 + r;
        float v = ((const float*)Xv)[g * K + k0 + c];
        if (BN) v = fmaxf(0.f, fmaf(v, scv, shv));
        S[0][c * 68 + r] = v;
      }
    } else {
      int m = tid & 63, cc = tid >> 6;
      long b = r0 >> 12;
      long mg = (r0 & 4095) + m;
#pragma unroll
      for (int i = 0; i < 8; i++) {
        int c = cc + i * 4;
        S[0][c * 68 + m] = ((const float*)Xv)[(b * K + k0 + c) * 4096 + mg];
      }
    }
    {
      int c = tid & 31, oo = tid >> 5;
#pragma unroll
      for (int i = 0; i < 8; i++) {
        int o = oo + i * 8;
        S[1][c * 68 + o] = W[(long)(c0 + o) * K + k0 + c];
      }
    }
    __syncthreads();
#pragma unroll
    for (int kk = 0; kk < 32; kk++) {
      float4 a = *reinterpret_cast<const float4*>(&S[0][kk * 68 + ty * 4]);
      float4 bv = *reinterpret_cast<const float4*>(&S[1][kk * 68 + tx * 4]);
      float av[4] = {a.x, a.y, a.z, a.w};
      float bw[4] = {bv.x, bv.y, bv.z, bv.w};
#pragma unroll
      for (int i = 0; i < 4; i++)
#pragma unroll
        for (int j = 0; j < 4; j++) acc[i][j] = fmaf(av[i], bw[j], acc[i][j]);
    }
    __syncthreads();
  }

  if (EPI == 2) {
    const float4 b4 = *reinterpret_cast<const float4*>(&bias[c0 + tx * 4]);
#pragma unroll
    for (int i = 0; i < 4; i++) {
      long r = r0 + ty * 4 + i;
      float4 f4 = *reinterpret_cast<const float4*>(&res[r * CO + c0 + tx * 4]);
      float4 o4 = make_float4(acc[i][0] + b4.x + f4.x, acc[i][1] + b4.y + f4.y,
                              acc[i][2] + b4.z + f4.z, acc[i][3] + b4.w + f4.w);
      *reinterpret_cast<float4*>(&out[r * CO + c0 + tx * 4]) = o4;
    }
  } else if (EPI == 3) {
    float* Sf = &S[0][0];
#pragma unroll
    for (int j = 0; j < 4; j++) {
      float bj = bias[c0 + tx * 4 + j];
      float4 colv = make_float4(acc[0][j] + bj, acc[1][j] + bj, acc[2][j] + bj,
                                acc[3][j] + bj);
      *reinterpret_cast<float4*>(&Sf[(tx * 4 + j) * 68 + ty * 4]) = colv;
    }
    __syncthreads();
    long b = r0 >> 12;
    long n0 = (r0 & 4095);
    int n = tid & 63, oo = tid >> 6;
#pragma unroll
    for (int i = 0; i < 16; i++) {
      int o = oo + i * 4;
      out[(b * CO + c0 + o) * 4096L + n0 + n] = Sf[o * 68 + n];
    }
  } else if (EPI == 7) {
    long b = r0 >> 12;
    long nn = (r0 & 4095) + ty * 4;
    const float4 b4 = *reinterpret_cast<const float4*>(&bias[c0 + tx * 4]);
    __hip_bfloat16* Ob = obf + ((b * (CO >> 6) + cb) * 4096L) * 64;
#pragma unroll
    for (int i = 0; i < 4; i++) {
      union { unsigned short u[4]; uint2 v; } pk;
      pk.u[0] = __bfloat16_as_ushort(__float2bfloat16(acc[i][0] + b4.x));
      pk.u[1] = __bfloat16_as_ushort(__float2bfloat16(acc[i][1] + b4.y));
      pk.u[2] = __bfloat16_as_ushort(__float2bfloat16(acc[i][2] + b4.z));
      pk.u[3] = __bfloat16_as_ushort(__float2bfloat16(acc[i][3] + b4.w));
      *reinterpret_cast<uint2*>(&Ob[(nn + i) * 64 + tx * 4]) = pk.v;
    }
  } else if (EPI == 8) {
    float* Sf = &S[0][0];
#pragma unroll
    for (int j = 0; j < 4; j++) {
      float bj = bias[c0 + tx * 4 + j];
      float4 colv = make_float4(acc[0][j] + bj, acc[1][j] + bj, acc[2][j] + bj,
                                acc[3][j] + bj);
      *reinterpret_cast<float4*>(&Sf[(tx * 4 + j) * 68 + ty * 4]) = colv;
    }
    __syncthreads();
    long b = r0 >> 12;
    long n0 = (r0 & 4095);
    int n = tid & 63, oo = tid >> 6;
#pragma unroll
    for (int i = 0; i < 16; i++) {
      int o = oo + i * 4;
      obf[((b * 4 + cb) * 64 + o) * 4096L + n0 + n] = __float2bfloat16(Sf[o * 68 + n]);
    }
  }
}

// ------- MFMA flash attention, key-split: each block does 2048 keys ---------
__global__ __launch_bounds__(256) void flash_mfma_kernel(
    const __hip_bfloat16* __restrict__ Q, const __hip_bfloat16* __restrict__ Kb,
    const __hip_bfloat16* __restrict__ Vtg, float* __restrict__ Opart,
    float* __restrict__ mbuf, float* __restrict__ lbuf) {
  __shared__ unsigned short Ks[64 * 72];
  __shared__ unsigned short Vt[64 * 72];
  __shared__ unsigned short Ps[4][16 * 72];
  int tid = threadIdx.x;
  int lane = tid & 63, w = tid >> 6;
  int bh = blockIdx.x >> 6;
  int qt = blockIdx.x & 63;
  int half = blockIdx.y;
  long base = (long)bh * 4096 * 64;
  int row0 = qt * 64 + w * 16;
  int fr = lane & 15;
  int fk = (lane >> 4) * 8;

  bf16x8 aq[2];
#pragma unroll
  for (int kk = 0; kk < 2; kk++)
    aq[kk] = *reinterpret_cast<const bf16x8*>(&Q[base + (long)(row0 + fr) * 64 + kk * 32 + fk]);

  f32x4 o[4];
#pragma unroll
  for (int i = 0; i < 4; i++) o[i] = (f32x4){0.f, 0.f, 0.f, 0.f};
  float m_run[4], l_run[4];
#pragma unroll
  for (int r = 0; r < 4; r++) { m_run[r] = -3.0e38f; l_run[r] = 0.f; }

  int skey = tid >> 2, sdc = (tid & 3) * 16;
  int vd = tid & 63, vkg = tid >> 6;
  int vsw = (vd ^ (vd >> 3)) & 7;

  int mstart = half * 2048;
  for (int m0 = mstart; m0 < mstart + 2048; m0 += 64) {
    __syncthreads();
    {
      const __hip_bfloat16* kp = &Kb[base + (long)(m0 + skey) * 64 + sdc];
      *reinterpret_cast<uint4*>(&Ks[skey * 72 + sdc]) =
          *reinterpret_cast<const uint4*>(kp);
      *reinterpret_cast<uint4*>(&Ks[skey * 72 + sdc + 8]) =
          *reinterpret_cast<const uint4*>(kp + 8);
#pragma unroll
      for (int j8 = 0; j8 < 2; j8++) {
        int k0 = vkg * 16 + j8 * 8;
        int kb = k0 >> 3;
        *reinterpret_cast<uint4*>(&Vt[vd * 72 + ((kb ^ vsw) << 3)]) =
            *reinterpret_cast<const uint4*>(&Vtg[base + (long)vd * 4096 + m0 + k0]);
      }
    }
    __syncthreads();

    f32x4 s[4];
#pragma unroll
    for (int n = 0; n < 4; n++) {
      s[n] = (f32x4){0.f, 0.f, 0.f, 0.f};
#pragma unroll
      for (int kk = 0; kk < 2; kk++) {
        bf16x8 bk = *reinterpret_cast<const bf16x8*>(&Ks[(n * 16 + fr) * 72 + kk * 32 + fk]);
        s[n] = __builtin_amdgcn_mfma_f32_16x16x32_bf16(aq[kk], bk, s[n], 0, 0, 0);
      }
    }

    float p[4][4];
#pragma unroll
    for (int r = 0; r < 4; r++) {
      float sv0 = s[0][r] * 0.125f, sv1 = s[1][r] * 0.125f;
      float sv2 = s[2][r] * 0.125f, sv3 = s[3][r] * 0.125f;
      float mx = fmaxf(fmaxf(sv0, sv1), fmaxf(sv2, sv3));
      mx = fmaxf(mx, __shfl_xor(mx, 1));
      mx = fmaxf(mx, __shfl_xor(mx, 2));
      mx = fmaxf(mx, __shfl_xor(mx, 4));
      mx = fmaxf(mx, __shfl_xor(mx, 8));
      float mn = fmaxf(m_run[r], mx);
      float fac = __expf(m_run[r] - mn);
      p[0][r] = __expf(sv0 - mn);
      p[1][r] = __expf(sv1 - mn);
      p[2][r] = __expf(sv2 - mn);
      p[3][r] = __expf(sv3 - mn);
      float rs = (p[0][r] + p[1][r]) + (p[2][r] + p[3][r]);
      rs += __shfl_xor(rs, 1);
      rs += __shfl_xor(rs, 2);
      rs += __shfl_xor(rs, 4);
      rs += __shfl_xor(rs, 8);
      l_run[r] = l_run[r] * fac + rs;
      m_run[r] = mn;
#pragma unroll
      for (int n2 = 0; n2 < 4; n2++) o[n2][r] *= fac;
    }

    unsigned short* pw = &Ps[w][0];
#pragma unroll
    for (int r = 0; r < 4; r++) {
      int prow = (lane >> 4) * 4 + r;
#pragma unroll
      for (int n = 0; n < 4; n++)
        pw[prow * 72 + n * 16 + fr] = __bfloat16_as_ushort(__float2bfloat16(p[n][r]));
    }
    bf16x8 ap[2];
#pragma unroll
    for (int kk = 0; kk < 2; kk++)
      ap[kk] = *reinterpret_cast<const bf16x8*>(&pw[fr * 72 + kk * 32 + fk]);

#pragma unroll
    for (int n2 = 0; n2 < 4; n2++) {
      int d = n2 * 16 + fr;
      int dsw = (d ^ (d >> 3)) & 7;
#pragma unroll
      for (int kk = 0; kk < 2; kk++) {
        int kb = kk * 4 + (lane >> 4);
        bf16x8 bv = *reinterpret_cast<const bf16x8*>(&Vt[d * 72 + ((kb ^ dsw) << 3)]);
        o[n2] = __builtin_amdgcn_mfma_f32_16x16x32_bf16(ap[kk], bv, o[n2], 0, 0, 0);
      }
    }
  }

  int b = bh >> 2, h = bh & 3;
  float* Op = Opart + (long)half * 2097152;  // 8192*256 f32 per half
#pragma unroll
  for (int r = 0; r < 4; r++) {
    float inv = 1.f / l_run[r];
    int qrow = qt * 64 + w * 16 + (lane >> 4) * 4 + r;
    long nrow = (long)(b * 4096 + qrow);
#pragma unroll
    for (int n2 = 0; n2 < 4; n2++) {
      Op[nrow * 256 + h * 64 + n2 * 16 + fr] = o[n2][r] * inv;
    }
    if (fr == 0) {
      long mlrow = ((long)(half * 8 + bh)) * 4096 + qrow;
      mbuf[mlrow] = m_run[r];
      lbuf[mlrow] = l_run[r];
    }
  }
}

// ---- flash merge: combine 2 key-halves (exact online-softmax algebra) ------
__global__ __launch_bounds__(256) void flash_merge_kernel(
    const float* __restrict__ Opart, const float* __restrict__ mbuf,
    const float* __restrict__ lbuf, float* __restrict__ O) {
  long r = blockIdx.x;              // 0..8191 (b*4096+n)
  int c = threadIdx.x;              // 0..255
  int b = (int)(r >> 12);
  int n = (int)(r & 4095);
  int h = c >> 6;
  int bh = b * 4 + h;
  long ml0 = ((long)(0 * 8 + bh)) * 4096 + n;
  long ml1 = ((long)(1 * 8 + bh)) * 4096 + n;
  float m0 = mbuf[ml0], l0 = lbuf[ml0];
  float m1 = mbuf[ml1], l1 = lbuf[ml1];
  float M = fmaxf(m0, m1);
  float w0 = l0 * __expf(m0 - M);
  float w1 = l1 * __expf(m1 - M);
  float invden = 1.f / (w0 + w1);
  float o0 = Opart[r * 256 + c];
  float o1 = Opart[2097152 + r * 256 + c];
  O[r * 256 + c] = (o0 * w0 + o1 * w1) * invden;
}

// ------------- LayerNorm over 512 (one row per block) -----------------------
__global__ __launch_bounds__(256) void ln_kernel(float* __restrict__ y,
                                                 const float* __restrict__ lng,
                                                 const float* __restrict__ lnb) {
  long r = blockIdx.x;
  int tid = threadIdx.x;
  float v0 = y[r * 512 + tid];
  float v1 = y[r * 512 + 256 + tid];
  float s = v0 + v1;
  float q = v0 * v0 + v1 * v1;
#pragma unroll
  for (int off = 1; off < 64; off <<= 1) {
    s += __shfl_xor(s, off);
    q += __shfl_xor(q, off);
  }
  __shared__ float red[8];
  __shared__ float mv[2];
  int w = tid >> 6;
  if ((tid & 63) == 0) { red[w] = s; red[4 + w] = q; }
  __syncthreads();
  if (tid == 0) {
    float S = red[0] + red[1] + red[2] + red[3];
    float Q2 = red[4] + red[5] + red[6] + red[7];
    float mu = S * (1.f / 512.f);
    float var = Q2 * (1.f / 512.f) - mu * mu;
    mv[0] = mu;
    mv[1] = rsqrtf(var + 1e-5f);
  }
  __syncthreads();
  float mu = mv[0], rstd = mv[1];
  y[r * 512 + tid] = (v0 - mu) * rstd * lng[tid] + lnb[tid];
  y[r * 512 + 256 + tid] = (v1 - mu) * rstd * lng[256 + tid] + lnb[256 + tid];
}

// ------------- output 0: pos1 passthrough, f32 -> f32 ------------------------
__global__ void poscopy_kernel(const float* __restrict__ p, float* __restrict__ o) {
  int i = blockIdx.x * 256 + threadIdx.x;
  o[i] = p[i];
}

extern "C" void kernel_launch(void* const* d_in, const int* in_sizes, int n_in,
                              void* d_out, int out_size, void* d_ws, size_t ws_size,
                              hipStream_t stream) {
  (void)in_sizes; (void)n_in; (void)out_size; (void)ws_size;
  const float* pos1 = (const float*)d_in[0];
  const float* pos2 = (const float*)d_in[1];
  const float* f1 = (const float*)d_in[2];
  const float* f2 = (const float*)d_in[3];
  const float* w0 = (const float*)d_in[4];
  const float* g0 = (const float*)d_in[5];
  const float* b0 = (const float*)d_in[6];
  const float* w1 = (const float*)d_in[7];
  const float* g1 = (const float*)d_in[8];
  const float* b1 = (const float*)d_in[9];
  const float* w2 = (const float*)d_in[10];
  const float* g2 = (const float*)d_in[11];
  const float* b2 = (const float*)d_in[12];
  const float* qw = (const float*)d_in[13];
  const float* qb = (const float*)d_in[14];
  const float* kw = (const float*)d_in[15];
  const float* kb = (const float*)d_in[16];
  const float* vw = (const float*)d_in[17];
  const float* vb = (const float*)d_in[18];
  const float* ow = (const float*)d_in[19];
  const float* obv = (const float*)d_in[20];
  const float* lng = (const float*)d_in[21];
  const float* lnb = (const float*)d_in[22];
  const float* fw = (const float*)d_in[23];
  const float* fb = (const float*)d_in[24];

  // ws layout (proven <=72MB):
  // phase A: z1b bf16 [0,32MB) ; idx 32MB ; A1 33MB ; A2 37MB ; stats 48MB ;
  //          pd [56,64) ; pi [64,72)
  // phase B: Qbf [0,4) ; Kbf [8,12) ; Vtg [16,20) ; attno [24,32) f32 ;
  //          feat [32,48) f32 ; mbuf 49MB ; lbuf 50MB ; Opart [56,72) f32 ;
  //          y0 [0,16) after flash.
  char* ws = (char*)d_ws;
  __hip_bfloat16* z1b = (__hip_bfloat16*)(ws);
  __hip_bfloat16* Qbf = (__hip_bfloat16*)(ws);
  __hip_bfloat16* Kbf = (__hip_bfloat16*)(ws + (8ull << 20));
  __hip_bfloat16* Vtg = (__hip_bfloat16*)(ws + (16ull << 20));
  float* attno = (float*)(ws + (24ull << 20));
  float* y0 = (float*)(ws);
  int* idx = (int*)(ws + (32ull << 20));
  float* A1 = (float*)(ws + (33ull << 20));
  float* A2 = (float*)(ws + (37ull << 20));
  float* feat = (float*)(ws + (32ull << 20));
  char* statp = ws + (48ull << 20);
  float* mbuf = (float*)(ws + (49ull << 20));
  float* lbuf = (float*)(ws + (50ull << 20));
  float* pd = (float*)(ws + (56ull << 20));
  int* pi = (int*)(ws + (64ull << 20));
  float* Opart = (float*)(ws + (56ull << 20));   // reuses pd/pi region (dead)
  double* st0 = (double*)(statp);
  double* st1 = (double*)(statp + 2048);
  double* st2 = (double*)(statp + 4096);
  float* sc0 = (float*)(statp + 8192);
  float* sh0 = (float*)(statp + 8704);
  float* sc1 = (float*)(statp + 9216);
  float* sh1 = (float*)(statp + 9728);
  float* sc2 = (float*)(statp + 10240);
  float* sh2 = (float*)(statp + 11264);

  float* out0 = (float*)d_out;
  float* out1 = out0 + 24576;

  hipMemsetAsync(statp, 0, 8192, stream);

  knn_part_kernel<<<dim3(32, 16), 256, 0, stream>>>(pos1, pos2, pd, pi);
  knn_merge_kernel<<<32, 256, 0, stream>>>(pd, pi, idx);
  g131_kernel<<<512, 128, 0, stream>>>(pos2, f2, w0, A2, 1.f, 3);
  g131_kernel<<<512, 128, 0, stream>>>(pos1, f1, w0, A1, -1.f, 131);
  z0stats_kernel<<<256, 256, 0, stream>>>(idx, A1, A2, st0);
  bnfin_kernel<<<1, 256, 0, stream>>>(st0, g0, b0, sc0, sh0, 128, 1.0 / 131072.0);
  gemm1_mfma_kernel<<<dim3(2, 2048), 256, 0, stream>>>(
      A2, A1, idx, w1, sc0, sh0, z1b);
  statsb_kernel<<<512, 256, 0, stream>>>(z1b, 131072L, st1);
  bnfin_kernel<<<1, 256, 0, stream>>>(st1, g1, b1, sc1, sh1, 128, 1.0 / 131072.0);
  gemm2_mfma_kernel<4><<<dim3(4, 2048), 256, 0, stream>>>(
      z1b, w2, sc1, sh1, nullptr, nullptr, nullptr, st2);
  bnfin_kernel<<<1, 256, 0, stream>>>(st2, g2, b2, sc2, sh2, 256, 1.0 / 131072.0);
  gemm2_mfma_kernel<5><<<dim3(4, 2048), 256, 0, stream>>>(
      z1b, w2, sc1, sh1, sc2, sh2, feat, nullptr);
  gemm_kernel<7, 0, false><<<dim3(4, 128), 256, 0, stream>>>(
      feat, qw, nullptr, 512, 256, qb, nullptr, nullptr, nullptr, Qbf, nullptr, nullptr, nullptr);
  gemm_kernel<7, 1, false><<<dim3(4, 128), 256, 0, stream>>>(
      f2, kw, nullptr, 128, 256, kb, nullptr, nullptr, nullptr, Kbf, nullptr, nullptr, nullptr);
  gemm_kernel<8, 1, false><<<dim3(4, 128), 256, 0, stream>>>(
      f2, vw, nullptr, 128, 256, vb, nullptr, nullptr, nullptr, Vtg, nullptr, nullptr, nullptr);
  flash_mfma_kernel<<<dim3(512, 2), 256, 0, stream>>>(Qbf, Kbf, Vtg, Opart, mbuf, lbuf);
  flash_merge_kernel<<<8192, 256, 0, stream>>>(Opart, mbuf, lbuf, attno);
  gemm_kernel<2, 0, false><<<dim3(8, 128), 256, 0, stream>>>(
      attno, ow, y0, 256, 512, obv, nullptr, nullptr, feat, nullptr, nullptr, nullptr, nullptr);
  ln_kernel<<<8192, 256, 0, stream>>>(y0, lng, lnb);
  gemm_kernel<3, 0, false><<<dim3(4, 128), 256, 0, stream>>>(
      y0, fw, out1, 512, 256, fb, nullptr, nullptr, nullptr, nullptr, nullptr, nullptr, nullptr);
  poscopy_kernel<<<96, 256, 0, stream>>>(pos1, out0);
}

// Round 25
// 724.089 us; speedup vs baseline: 3.9917x; 1.0945x over previous
//
#include <hip/hip_runtime.h>
#include <hip/hip_bf16.h>

constexpr int B_ = 2, N_ = 4096, M_ = 4096, C_ = 128;

typedef __attribute__((ext_vector_type(8))) __bf16 bf16x8;
typedef __attribute__((ext_vector_type(4))) float f32x4;

// ---- KNN phase 1: per-(query, 256-candidate segment) register top-16 -------
// FROZEN selection semantics (R17/R19) with x8 ILP unroll (R22, verified).
__global__ __launch_bounds__(256) void knn_part_kernel(const float* __restrict__ pos1,
                                                       const float* __restrict__ pos2,
                                                       float* __restrict__ pd,
                                                       int* __restrict__ pi) {
  __shared__ float tX[256], tY[256], tZ[256], tS[256];
  int tid = threadIdx.x;
  int bn = blockIdx.x * 256 + tid;
  int b = bn >> 12, n = bn & 4095;
  int seg = blockIdx.y;
  const float* p1 = pos1 + (long)b * 3 * N_;
  float qx = p1[n], qy = p1[N_ + n], qz = p1[2 * N_ + n];
  float s1 = __fadd_rn(__fadd_rn(__fmul_rn(qx, qx), __fmul_rn(qy, qy)), __fmul_rn(qz, qz));
  const float* p2 = pos2 + (long)b * 3 * M_ + seg * 256;
  {
    float x = p2[tid], y = p2[M_ + tid], z = p2[2 * M_ + tid];
    tX[tid] = x; tY[tid] = y; tZ[tid] = z;
    tS[tid] = __fadd_rn(__fadd_rn(__fmul_rn(x, x), __fmul_rn(y, y)), __fmul_rn(z, z));
  }
  __syncthreads();
  float rd[16]; int ri[16];
#pragma unroll
  for (int k = 0; k < 16; k++) { rd[k] = 3.0e38f; ri[k] = 0; }
  for (int mm = 0; mm < 256; mm += 8) {
    float dv[8];
#pragma unroll
    for (int u = 0; u < 8; u++) {
      float e = __fmaf_rn(qz, tZ[mm + u],
                          __fmaf_rn(qy, tY[mm + u], __fmul_rn(qx, tX[mm + u])));
      dv[u] = __fadd_rn(__fsub_rn(s1, __fadd_rn(e, e)), tS[mm + u]);
    }
    float thr = rd[15];
    bool any = false;
#pragma unroll
    for (int u = 0; u < 8; u++) any = any || (dv[u] < thr);
    if (any) {
#pragma unroll
      for (int u = 0; u < 8; u++) {
        float d = dv[u];
        if (d < rd[15]) {
          float cd = d; int ci = seg * 256 + mm + u;
#pragma unroll
          for (int k = 0; k < 16; k++) {
            bool lt = cd < rd[k];
            float td = lt ? rd[k] : cd;
            int ti = lt ? ri[k] : ci;
            rd[k] = lt ? cd : rd[k];
            ri[k] = lt ? ci : ri[k];
            cd = td; ci = ti;
          }
        }
      }
    }
  }
  long base = (long)seg * 16 * 8192 + bn;
#pragma unroll
  for (int k = 0; k < 16; k++) {
    pd[base + (long)k * 8192] = rd[k];
    pi[base + (long)k * 8192] = ri[k];
  }
}

// ---- KNN phase 2: merge 16 sorted lists of 16 per query (frozen) -----------
__global__ __launch_bounds__(256) void knn_merge_kernel(const float* __restrict__ pd,
                                                        const int* __restrict__ pi,
                                                        int* __restrict__ idx) {
  int bn = blockIdx.x * 256 + threadIdx.x;
  float rd[16]; int ri[16];
#pragma unroll
  for (int k = 0; k < 16; k++) { rd[k] = 3.0e38f; ri[k] = 0; }
  for (int seg = 0; seg < 16; seg++) {
    for (int k = 0; k < 16; k++) {
      float d = pd[((long)seg * 16 + k) * 8192 + bn];
      if (d >= rd[15]) break;
      int ci = pi[((long)seg * 16 + k) * 8192 + bn];
      float cd = d;
#pragma unroll
      for (int j = 0; j < 16; j++) {
        bool lt = cd < rd[j];
        float td = lt ? rd[j] : cd;
        int ti = lt ? ri[j] : ci;
        rd[j] = lt ? cd : rd[j];
        ri[j] = lt ? ci : ri[j];
        cd = td; ci = ti;
      }
    }
  }
#pragma unroll
  for (int k = 0; k < 16; k++) idx[(long)bn * 16 + k] = ri[k];
}

// ------------- layer0 decomposition: 131-wide GEMM over points --------------
__global__ __launch_bounds__(128) void g131_kernel(const float* __restrict__ pos,
                                                   const float* __restrict__ feat,
                                                   const float* __restrict__ w0,
                                                   float* __restrict__ out,
                                                   float sign, int woff) {
  __shared__ float Xs[131 * 16];
  int tid = threadIdx.x;
  long b = blockIdx.x >> 8;
  int i0 = (blockIdx.x & 255) * 16;
  for (int e = tid; e < 131 * 16; e += 128) {
    int r = e & 15, c = e >> 4;
    float v = (c < 3) ? sign * pos[b * 3 * N_ + (long)c * N_ + i0 + r]
                      : feat[b * C_ * N_ + (long)(c - 3) * N_ + i0 + r];
    Xs[c * 16 + r] = v;
  }
  __syncthreads();
  int o = tid;
  float acc[16];
#pragma unroll
  for (int r = 0; r < 16; r++) acc[r] = 0.f;
  for (int c = 0; c < 131; c++) {
    float wv = w0[(long)o * 259 + (c < 3 ? c : (woff + c - 3))];
    const float* xr = &Xs[c * 16];
#pragma unroll
    for (int r = 0; r < 16; r++) acc[r] = fmaf(xr[r], wv, acc[r]);
  }
#pragma unroll
  for (int r = 0; r < 16; r++) out[((b << 12) + i0 + r) * 128 + o] = acc[r];
}

// ------------- BN0 stats from (idx, A1, A2), no z0 store --------------------
__global__ __launch_bounds__(256) void z0stats_kernel(const int* __restrict__ idx,
                                                      const float* __restrict__ A1,
                                                      const float* __restrict__ A2,
                                                      double* __restrict__ st) {
  int tid = threadIdx.x;
  int o = tid & 127, half = tid >> 7;
  float sum = 0.f, sq = 0.f;
  int g0 = blockIdx.x * 32;
  for (int gi = 0; gi < 32; gi++) {
    int bn = g0 + gi;
    long b = bn >> 12;
    float a1 = A1[(long)bn * 128 + o];
    for (int k = half; k < 16; k += 2) {
      int m = idx[bn * 16 + k];
      float v = A2[(b * 4096 + m) * 128 + o] + a1;
      sum += v;
      sq += v * v;
    }
  }
  __shared__ float ls[256], lq[256];
  ls[tid] = sum; lq[tid] = sq;
  __syncthreads();
  if (tid < 128) {
    atomicAdd(&st[o], (double)(ls[tid] + ls[tid + 128]));
    atomicAdd(&st[128 + o], (double)(lq[tid] + lq[tid + 128]));
  }
}

// ------------- per-channel stats over bf16 (nrows x 128) --------------------
__global__ __launch_bounds__(256) void statsb_kernel(const __hip_bfloat16* __restrict__ Z,
                                                     long nrows, double* __restrict__ st) {
  int tid = threadIdx.x;
  int c = tid & 127, sub = tid >> 7;
  long slot = (long)blockIdx.x * 2 + sub;
  long stride = (long)gridDim.x * 2;
  float sum = 0.f, sq = 0.f;
  for (long r = slot; r < nrows; r += stride) {
    float v = __bfloat162float(Z[r * 128 + c]);
    sum += v;
    sq += v * v;
  }
  __shared__ float ls[256], lq[256];
  ls[tid] = sum; lq[tid] = sq;
  __syncthreads();
  if (tid < 128) {
    atomicAdd(&st[c], (double)(ls[tid] + ls[tid + 128]));
    atomicAdd(&st[128 + c], (double)(lq[tid] + lq[tid + 128]));
  }
}

// ------------- BN finalize: fold mean/var/g/b into scale+shift --------------
__global__ void bnfin_kernel(const double* __restrict__ st, const float* __restrict__ g,
                             const float* __restrict__ bb, float* __restrict__ sc,
                             float* __restrict__ sh, int CO, double inv) {
  int c = threadIdx.x;
  if (c < CO) {
    double mu = st[c] * inv;
    double var = st[CO + c] * inv - mu * mu;
    double rstd = 1.0 / sqrt(var + 1e-5);
    double scv = (double)g[c] * rstd;
    sc[c] = (float)scv;
    sh[c] = (float)((double)bb[c] - mu * scv);
  }
}

// ---- MFMA z1 pass: z1 = BN0ReLU(gather(A2)+A1) @ w1^T -> bf16 --------------
__global__ __launch_bounds__(256) void gemm1_mfma_kernel(
    const float* __restrict__ A2, const float* __restrict__ A1,
    const int* __restrict__ idxp, const float* __restrict__ w1,
    const float* __restrict__ sc0, const float* __restrict__ sh0,
    __hip_bfloat16* __restrict__ z1b) {
  __shared__ unsigned short As[64 * 136];
  __shared__ unsigned short Bs[64 * 136];
  __shared__ float scs[128], shs[128];
  int tid = threadIdx.x;
  int lane = tid & 63, w = tid >> 6;
  int cb = blockIdx.x;
  long r0 = (long)blockIdx.y * 64;
  int c0 = cb * 64;
  if (tid < 128) { scs[tid] = sc0[tid]; shs[tid] = sh0[tid]; }
  __syncthreads();
  {
    int row = tid >> 2, kb = (tid & 3) * 32;
    long g = r0 + row;
    int m = idxp[g];
    const float* a2p = &A2[(((g >> 16) << 12) + m) * 128 + kb];
    const float* a1p = &A1[(g >> 4) * 128 + kb];
    unsigned short* ap = &As[row * 136 + kb];
    const float* wp = &w1[(long)(c0 + row) * 128 + kb];
    unsigned short* bp = &Bs[row * 136 + kb];
#pragma unroll
    for (int h = 0; h < 4; h++) {
      union { unsigned short u[8]; uint4 v; } oa, ob;
#pragma unroll
      for (int j = 0; j < 8; j++) {
        int k = kb + h * 8 + j;
        float raw = a2p[h * 8 + j] + a1p[h * 8 + j];
        float v = fmaxf(0.f, fmaf(raw, scs[k], shs[k]));
        oa.u[j] = __bfloat16_as_ushort(__float2bfloat16(v));
        ob.u[j] = __bfloat16_as_ushort(__float2bfloat16(wp[h * 8 + j]));
      }
      *reinterpret_cast<uint4*>(ap + h * 8) = oa.v;
      *reinterpret_cast<uint4*>(bp + h * 8) = ob.v;
    }
  }
  __syncthreads();

  int fr = lane & 15, fk = (lane >> 4) * 8;
  bf16x8 a[4];
#pragma unroll
  for (int kk = 0; kk < 4; kk++)
    a[kk] = *reinterpret_cast<const bf16x8*>(&As[(w * 16 + fr) * 136 + kk * 32 + fk]);
  f32x4 acc[4];
#pragma unroll
  for (int n2 = 0; n2 < 4; n2++) {
    acc[n2] = (f32x4){0.f, 0.f, 0.f, 0.f};
#pragma unroll
    for (int kk = 0; kk < 4; kk++) {
      bf16x8 bfrag = *reinterpret_cast<const bf16x8*>(&Bs[(n2 * 16 + fr) * 136 + kk * 32 + fk]);
      acc[n2] = __builtin_amdgcn_mfma_f32_16x16x32_bf16(a[kk], bfrag, acc[n2], 0, 0, 0);
    }
  }
#pragma unroll
  for (int n2 = 0; n2 < 4; n2++) {
#pragma unroll
    for (int r = 0; r < 4; r++) {
      long row = r0 + w * 16 + (lane >> 4) * 4 + r;
      z1b[row * 128 + c0 + n2 * 16 + fr] = __float2bfloat16(acc[n2][r]);
    }
  }
}

// ---- MFMA z2 pass: C = BN1ReLU(z1b) @ w2^T, 64x64 tile, 4 waves ------------
template <int EPI>
__global__ __launch_bounds__(256) void gemm2_mfma_kernel(
    const __hip_bfloat16* __restrict__ z1b, const float* __restrict__ w2,
    const float* __restrict__ sc1, const float* __restrict__ sh1,
    const float* __restrict__ sc2, const float* __restrict__ sh2,
    float* __restrict__ feat, double* __restrict__ st) {
  __shared__ unsigned short As[64 * 136];
  __shared__ unsigned short Bs[64 * 136];
  __shared__ float scs[128], shs[128];
  __shared__ float Sred[4 * 64], Qred[4 * 64];
  int tid = threadIdx.x;
  int lane = tid & 63, w = tid >> 6;
  int cb = blockIdx.x;
  long r0 = (long)blockIdx.y * 64;
  int c0 = cb * 64;
  if (tid < 128) { scs[tid] = sc1[tid]; shs[tid] = sh1[tid]; }
  __syncthreads();
  {
    int row = tid >> 2, kb = (tid & 3) * 32;
    const __hip_bfloat16* zp = &z1b[(r0 + row) * 128 + kb];
    unsigned short* ap = &As[row * 136 + kb];
    const float* wp = &w2[(long)(c0 + row) * 128 + kb];
    unsigned short* bp = &Bs[row * 136 + kb];
#pragma unroll
    for (int h = 0; h < 4; h++) {
      union { unsigned short u[8]; uint4 v; } in, oa, ob;
      in.v = *reinterpret_cast<const uint4*>(zp + h * 8);
#pragma unroll
      for (int j = 0; j < 8; j++) {
        int k = kb + h * 8 + j;
        float f = __bfloat162float(__ushort_as_bfloat16(in.u[j]));
        float v = fmaxf(0.f, fmaf(f, scs[k], shs[k]));
        oa.u[j] = __bfloat16_as_ushort(__float2bfloat16(v));
        ob.u[j] = __bfloat16_as_ushort(__float2bfloat16(wp[h * 8 + j]));
      }
      *reinterpret_cast<uint4*>(ap + h * 8) = oa.v;
      *reinterpret_cast<uint4*>(bp + h * 8) = ob.v;
    }
  }
  __syncthreads();

  int fr = lane & 15, fk = (lane >> 4) * 8;
  bf16x8 a[4];
#pragma unroll
  for (int kk = 0; kk < 4; kk++)
    a[kk] = *reinterpret_cast<const bf16x8*>(&As[(w * 16 + fr) * 136 + kk * 32 + fk]);
  f32x4 acc[4];
#pragma unroll
  for (int n2 = 0; n2 < 4; n2++) {
    acc[n2] = (f32x4){0.f, 0.f, 0.f, 0.f};
#pragma unroll
    for (int kk = 0; kk < 4; kk++) {
      bf16x8 bfrag = *reinterpret_cast<const bf16x8*>(&Bs[(n2 * 16 + fr) * 136 + kk * 32 + fk]);
      acc[n2] = __builtin_amdgcn_mfma_f32_16x16x32_bf16(a[kk], bfrag, acc[n2], 0, 0, 0);
    }
  }

  if (EPI == 4) {
#pragma unroll
    for (int n2 = 0; n2 < 4; n2++) {
      float s = 0.f, q = 0.f;
#pragma unroll
      for (int r = 0; r < 4; r++) { s += acc[n2][r]; q += acc[n2][r] * acc[n2][r]; }
      s += __shfl_xor(s, 16); s += __shfl_xor(s, 32);
      q += __shfl_xor(q, 16); q += __shfl_xor(q, 32);
      if (lane < 16) { Sred[w * 64 + n2 * 16 + fr] = s; Qred[w * 64 + n2 * 16 + fr] = q; }
    }
    __syncthreads();
    if (tid < 64) {
      float S = Sred[tid] + Sred[64 + tid] + Sred[128 + tid] + Sred[192 + tid];
      float Q = Qred[tid] + Qred[64 + tid] + Qred[128 + tid] + Qred[192 + tid];
      atomicAdd(&st[c0 + tid], (double)S);
      atomicAdd(&st[256 + c0 + tid], (double)Q);
    }
  } else {
    int bn = (int)(r0 >> 4) + w;
#pragma unroll
    for (int n2 = 0; n2 < 4; n2++) {
      int c = c0 + n2 * 16 + fr;
      float scv = sc2[c], shv = sh2[c];
      float mx = -1e30f, sm = 0.f;
#pragma unroll
      for (int r = 0; r < 4; r++) {
        float v = fmaxf(0.f, fmaf(acc[n2][r], scv, shv));
        mx = fmaxf(mx, v);
        sm += v;
      }
      mx = fmaxf(mx, __shfl_xor(mx, 16)); mx = fmaxf(mx, __shfl_xor(mx, 32));
      sm += __shfl_xor(sm, 16); sm += __shfl_xor(sm, 32);
      if (lane < 16) {
        feat[(long)bn * 512 + c] = mx;
        feat[(long)bn * 512 + 256 + c] = sm * (1.f / 16.f);
      }
    }
  }
}

// ---- generic MFMA GEMM: C = X @ W^T (+epilogues), f32 accum ----------------
// XM: 0 = f32 row-major X ; 1 = f32 channel-first (B,K,4096)
// EPI 2: +bias +res -> f32 row-major (stride CO)
// EPI 3: +bias -> f32 transposed (B, COtot, 4096)
// EPI 7: +bias -> bf16 (b, h=cb, n, 64)
// EPI 8: +bias -> bf16 transposed (b, h=cb, 64, 4096)
template <int EPI, int XM>
__global__ __launch_bounds__(256) void gemmA_mfma_kernel(
    const float* __restrict__ X, const float* __restrict__ W, int K, int CO,
    const float* __restrict__ bias, const float* __restrict__ res,
    float* __restrict__ outf, __hip_bfloat16* __restrict__ outb) {
  __shared__ unsigned short As[64 * 136];
  __shared__ unsigned short Bs[64 * 136];
  int tid = threadIdx.x;
  int lane = tid & 63, w = tid >> 6;
  int cb = blockIdx.x;
  long r0 = (long)blockIdx.y * 64;
  int c0 = cb * 64;
  int fr = lane & 15, fk = (lane >> 4) * 8;
  f32x4 acc[4];
#pragma unroll
  for (int n2 = 0; n2 < 4; n2++) acc[n2] = (f32x4){0.f, 0.f, 0.f, 0.f};

  for (int k0 = 0; k0 < K; k0 += 64) {
    if (XM == 0) {
      int row = tid >> 2, kb = (tid & 3) * 16;
      const float* xp = &X[(r0 + row) * K + k0 + kb];
      unsigned short* ap = &As[row * 136 + kb];
#pragma unroll
      for (int h = 0; h < 2; h++) {
        union { unsigned short u[8]; uint4 v; } oa;
#pragma unroll
        for (int j = 0; j < 8; j++)
          oa.u[j] = __bfloat16_as_ushort(__float2bfloat16(xp[h * 8 + j]));
        *reinterpret_cast<uint4*>(ap + h * 8) = oa.v;
      }
    } else {
      int m = tid & 63, cc = tid >> 6;
      long b = r0 >> 12;
      long mg = (r0 & 4095) + m;
#pragma unroll
      for (int i = 0; i < 16; i++) {
        int c = cc + i * 4;
        As[m * 136 + c] =
            __bfloat16_as_ushort(__float2bfloat16(X[(b * K + k0 + c) * 4096 + mg]));
      }
    }
    {
      int row = tid >> 2, kb = (tid & 3) * 16;
      const float* wp = &W[(long)(c0 + row) * K + k0 + kb];
      unsigned short* bp = &Bs[row * 136 + kb];
#pragma unroll
      for (int h = 0; h < 2; h++) {
        union { unsigned short u[8]; uint4 v; } ob;
#pragma unroll
        for (int j = 0; j < 8; j++)
          ob.u[j] = __bfloat16_as_ushort(__float2bfloat16(wp[h * 8 + j]));
        *reinterpret_cast<uint4*>(bp + h * 8) = ob.v;
      }
    }
    __syncthreads();
    bf16x8 a[2];
#pragma unroll
    for (int kk = 0; kk < 2; kk++)
      a[kk] = *reinterpret_cast<const bf16x8*>(&As[(w * 16 + fr) * 136 + kk * 32 + fk]);
#pragma unroll
    for (int n2 = 0; n2 < 4; n2++) {
#pragma unroll
      for (int kk = 0; kk < 2; kk++) {
        bf16x8 bfrag =
            *reinterpret_cast<const bf16x8*>(&Bs[(n2 * 16 + fr) * 136 + kk * 32 + fk]);
        acc[n2] = __builtin_amdgcn_mfma_f32_16x16x32_bf16(a[kk], bfrag, acc[n2], 0, 0, 0);
      }
    }
    __syncthreads();
  }

  if (EPI == 2) {
#pragma unroll
    for (int n2 = 0; n2 < 4; n2++) {
      int col = c0 + n2 * 16 + fr;
      float bv = bias[col];
#pragma unroll
      for (int r = 0; r < 4; r++) {
        long row = r0 + w * 16 + (lane >> 4) * 4 + r;
        outf[row * CO + col] = acc[n2][r] + bv + res[row * CO + col];
      }
    }
  } else if (EPI == 7) {
    long b = r0 >> 12;
    int qbase = (int)(r0 & 4095) + w * 16 + (lane >> 4) * 4;
    __hip_bfloat16* Ob = outb + ((b * 4 + cb) * 4096L) * 64;
#pragma unroll
    for (int n2 = 0; n2 < 4; n2++) {
      float bv = bias[c0 + n2 * 16 + fr];
#pragma unroll
      for (int r = 0; r < 4; r++)
        Ob[(long)(qbase + r) * 64 + n2 * 16 + fr] = __float2bfloat16(acc[n2][r] + bv);
    }
  } else {  // EPI 3 / 8: LDS bounce then transposed store
    float* Sf = (float*)As;
#pragma unroll
    for (int n2 = 0; n2 < 4; n2++) {
      float bv = bias[c0 + n2 * 16 + fr];
#pragma unroll
      for (int r = 0; r < 4; r++)
        Sf[(n2 * 16 + fr) * 68 + w * 16 + (lane >> 4) * 4 + r] = acc[n2][r] + bv;
    }
    __syncthreads();
    long b = r0 >> 12;
    long n0 = (r0 & 4095);
    int n = tid & 63, oo = tid >> 6;
#pragma unroll
    for (int i = 0; i < 16; i++) {
      int o = oo + i * 4;
      if (EPI == 3)
        outf[(b * CO + c0 + o) * 4096L + n0 + n] = Sf[o * 68 + n];
      else
        outb[((b * 4 + cb) * 64 + o) * 4096L + n0 + n] = __float2bfloat16(Sf[o * 68 + n]);
    }
  }
}

// ------- MFMA flash attention, key-split: each block does 2048 keys ---------
__global__ __launch_bounds__(256) void flash_mfma_kernel(
    const __hip_bfloat16* __restrict__ Q, const __hip_bfloat16* __restrict__ Kb,
    const __hip_bfloat16* __restrict__ Vtg, float* __restrict__ Opart,
    float* __restrict__ mbuf, float* __restrict__ lbuf) {
  __shared__ unsigned short Ks[64 * 72];
  __shared__ unsigned short Vt[64 * 72];
  __shared__ unsigned short Ps[4][16 * 72];
  int tid = threadIdx.x;
  int lane = tid & 63, w = tid >> 6;
  int bh = blockIdx.x >> 6;
  int qt = blockIdx.x & 63;
  int half = blockIdx.y;
  long base = (long)bh * 4096 * 64;
  int row0 = qt * 64 + w * 16;
  int fr = lane & 15;
  int fk = (lane >> 4) * 8;

  bf16x8 aq[2];
#pragma unroll
  for (int kk = 0; kk < 2; kk++)
    aq[kk] = *reinterpret_cast<const bf16x8*>(&Q[base + (long)(row0 + fr) * 64 + kk * 32 + fk]);

  f32x4 o[4];
#pragma unroll
  for (int i = 0; i < 4; i++) o[i] = (f32x4){0.f, 0.f, 0.f, 0.f};
  float m_run[4], l_run[4];
#pragma unroll
  for (int r = 0; r < 4; r++) { m_run[r] = -3.0e38f; l_run[r] = 0.f; }

  int skey = tid >> 2, sdc = (tid & 3) * 16;
  int vd = tid & 63, vkg = tid >> 6;
  int vsw = (vd ^ (vd >> 3)) & 7;

  int mstart = half * 2048;
  for (int m0 = mstart; m0 < mstart + 2048; m0 += 64) {
    __syncthreads();
    {
      const __hip_bfloat16* kp = &Kb[base + (long)(m0 + skey) * 64 + sdc];
      *reinterpret_cast<uint4*>(&Ks[skey * 72 + sdc]) =
          *reinterpret_cast<const uint4*>(kp);
      *reinterpret_cast<uint4*>(&Ks[skey * 72 + sdc + 8]) =
          *reinterpret_cast<const uint4*>(kp + 8);
#pragma unroll
      for (int j8 = 0; j8 < 2; j8++) {
        int k0 = vkg * 16 + j8 * 8;
        int kb = k0 >> 3;
        *reinterpret_cast<uint4*>(&Vt[vd * 72 + ((kb ^ vsw) << 3)]) =
            *reinterpret_cast<const uint4*>(&Vtg[base + (long)vd * 4096 + m0 + k0]);
      }
    }
    __syncthreads();

    f32x4 s[4];
#pragma unroll
    for (int n = 0; n < 4; n++) {
      s[n] = (f32x4){0.f, 0.f, 0.f, 0.f};
#pragma unroll
      for (int kk = 0; kk < 2; kk++) {
        bf16x8 bk = *reinterpret_cast<const bf16x8*>(&Ks[(n * 16 + fr) * 72 + kk * 32 + fk]);
        s[n] = __builtin_amdgcn_mfma_f32_16x16x32_bf16(aq[kk], bk, s[n], 0, 0, 0);
      }
    }

    float p[4][4];
#pragma unroll
    for (int r = 0; r < 4; r++) {
      float sv0 = s[0][r] * 0.125f, sv1 = s[1][r] * 0.125f;
      float sv2 = s[2][r] * 0.125f, sv3 = s[3][r] * 0.125f;
      float mx = fmaxf(fmaxf(sv0, sv1), fmaxf(sv2, sv3));
      mx = fmaxf(mx, __shfl_xor(mx, 1));
      mx = fmaxf(mx, __shfl_xor(mx, 2));
      mx = fmaxf(mx, __shfl_xor(mx, 4));
      mx = fmaxf(mx, __shfl_xor(mx, 8));
      float mn = fmaxf(m_run[r], mx);
      float fac = __expf(m_run[r] - mn);
      p[0][r] = __expf(sv0 - mn);
      p[1][r] = __expf(sv1 - mn);
      p[2][r] = __expf(sv2 - mn);
      p[3][r] = __expf(sv3 - mn);
      float rs = (p[0][r] + p[1][r]) + (p[2][r] + p[3][r]);
      rs += __shfl_xor(rs, 1);
      rs += __shfl_xor(rs, 2);
      rs += __shfl_xor(rs, 4);
      rs += __shfl_xor(rs, 8);
      l_run[r] = l_run[r] * fac + rs;
      m_run[r] = mn;
#pragma unroll
      for (int n2 = 0; n2 < 4; n2++) o[n2][r] *= fac;
    }

    unsigned short* pw = &Ps[w][0];
#pragma unroll
    for (int r = 0; r < 4; r++) {
      int prow = (lane >> 4) * 4 + r;
#pragma unroll
      for (int n = 0; n < 4; n++)
        pw[prow * 72 + n * 16 + fr] = __bfloat16_as_ushort(__float2bfloat16(p[n][r]));
    }
    bf16x8 ap[2];
#pragma unroll
    for (int kk = 0; kk < 2; kk++)
      ap[kk] = *reinterpret_cast<const bf16x8*>(&pw[fr * 72 + kk * 32 + fk]);

#pragma unroll
    for (int n2 = 0; n2 < 4; n2++) {
      int d = n2 * 16 + fr;
      int dsw = (d ^ (d >> 3)) & 7;
#pragma unroll
      for (int kk = 0; kk < 2; kk++) {
        int kb = kk * 4 + (lane >> 4);
        bf16x8 bv = *reinterpret_cast<const bf16x8*>(&Vt[d * 72 + ((kb ^ dsw) << 3)]);
        o[n2] = __builtin_amdgcn_mfma_f32_16x16x32_bf16(ap[kk], bv, o[n2], 0, 0, 0);
      }
    }
  }

  int b = bh >> 2, h = bh & 3;
  float* Op = Opart + (long)half * 2097152;
#pragma unroll
  for (int r = 0; r < 4; r++) {
    float inv = 1.f / l_run[r];
    int qrow = qt * 64 + w * 16 + (lane >> 4) * 4 + r;
    long nrow = (long)(b * 4096 + qrow);
#pragma unroll
    for (int n2 = 0; n2 < 4; n2++) {
      Op[nrow * 256 + h * 64 + n2 * 16 + fr] = o[n2][r] * inv;
    }
    if (fr == 0) {
      long mlrow = ((long)(half * 8 + bh)) * 4096 + qrow;
      mbuf[mlrow] = m_run[r];
      lbuf[mlrow] = l_run[r];
    }
  }
}

// ---- flash merge: combine 2 key-halves (exact online-softmax algebra) ------
__global__ __launch_bounds__(256) void flash_merge_kernel(
    const float* __restrict__ Opart, const float* __restrict__ mbuf,
    const float* __restrict__ lbuf, float* __restrict__ O) {
  long r = blockIdx.x;
  int c = threadIdx.x;
  int b = (int)(r >> 12);
  int n = (int)(r & 4095);
  int h = c >> 6;
  int bh = b * 4 + h;
  long ml0 = ((long)(0 * 8 + bh)) * 4096 + n;
  long ml1 = ((long)(1 * 8 + bh)) * 4096 + n;
  float m0 = mbuf[ml0], l0 = lbuf[ml0];
  float m1 = mbuf[ml1], l1 = lbuf[ml1];
  float M = fmaxf(m0, m1);
  float w0 = l0 * __expf(m0 - M);
  float w1 = l1 * __expf(m1 - M);
  float invden = 1.f / (w0 + w1);
  float o0 = Opart[r * 256 + c];
  float o1 = Opart[2097152 + r * 256 + c];
  O[r * 256 + c] = (o0 * w0 + o1 * w1) * invden;
}

// ------------- LayerNorm over 512 (one row per block) -----------------------
__global__ __launch_bounds__(256) void ln_kernel(float* __restrict__ y,
                                                 const float* __restrict__ lng,
                                                 const float* __restrict__ lnb) {
  long r = blockIdx.x;
  int tid = threadIdx.x;
  float v0 = y[r * 512 + tid];
  float v1 = y[r * 512 + 256 + tid];
  float s = v0 + v1;
  float q = v0 * v0 + v1 * v1;
#pragma unroll
  for (int off = 1; off < 64; off <<= 1) {
    s += __shfl_xor(s, off);
    q += __shfl_xor(q, off);
  }
  __shared__ float red[8];
  __shared__ float mv[2];
  int w = tid >> 6;
  if ((tid & 63) == 0) { red[w] = s; red[4 + w] = q; }
  __syncthreads();
  if (tid == 0) {
    float S = red[0] + red[1] + red[2] + red[3];
    float Q2 = red[4] + red[5] + red[6] + red[7];
    float mu = S * (1.f / 512.f);
    float var = Q2 * (1.f / 512.f) - mu * mu;
    mv[0] = mu;
    mv[1] = rsqrtf(var + 1e-5f);
  }
  __syncthreads();
  float mu = mv[0], rstd = mv[1];
  y[r * 512 + tid] = (v0 - mu) * rstd * lng[tid] + lnb[tid];
  y[r * 512 + 256 + tid] = (v1 - mu) * rstd * lng[256 + tid] + lnb[256 + tid];
}

// ------------- output 0: pos1 passthrough, f32 -> f32 ------------------------
__global__ void poscopy_kernel(const float* __restrict__ p, float* __restrict__ o) {
  int i = blockIdx.x * 256 + threadIdx.x;
  o[i] = p[i];
}

extern "C" void kernel_launch(void* const* d_in, const int* in_sizes, int n_in,
                              void* d_out, int out_size, void* d_ws, size_t ws_size,
                              hipStream_t stream) {
  (void)in_sizes; (void)n_in; (void)out_size; (void)ws_size;
  const float* pos1 = (const float*)d_in[0];
  const float* pos2 = (const float*)d_in[1];
  const float* f1 = (const float*)d_in[2];
  const float* f2 = (const float*)d_in[3];
  const float* w0 = (const float*)d_in[4];
  const float* g0 = (const float*)d_in[5];
  const float* b0 = (const float*)d_in[6];
  const float* w1 = (const float*)d_in[7];
  const float* g1 = (const float*)d_in[8];
  const float* b1 = (const float*)d_in[9];
  const float* w2 = (const float*)d_in[10];
  const float* g2 = (const float*)d_in[11];
  const float* b2 = (const float*)d_in[12];
  const float* qw = (const float*)d_in[13];
  const float* qb = (const float*)d_in[14];
  const float* kw = (const float*)d_in[15];
  const float* kb = (const float*)d_in[16];
  const float* vw = (const float*)d_in[17];
  const float* vb = (const float*)d_in[18];
  const float* ow = (const float*)d_in[19];
  const float* obv = (const float*)d_in[20];
  const float* lng = (const float*)d_in[21];
  const float* lnb = (const float*)d_in[22];
  const float* fw = (const float*)d_in[23];
  const float* fb = (const float*)d_in[24];

  // ws layout (proven <=72MB), identical to R24.
  char* ws = (char*)d_ws;
  __hip_bfloat16* z1b = (__hip_bfloat16*)(ws);
  __hip_bfloat16* Qbf = (__hip_bfloat16*)(ws);
  __hip_bfloat16* Kbf = (__hip_bfloat16*)(ws + (8ull << 20));
  __hip_bfloat16* Vtg = (__hip_bfloat16*)(ws + (16ull << 20));
  float* attno = (float*)(ws + (24ull << 20));
  float* y0 = (float*)(ws);
  int* idx = (int*)(ws + (32ull << 20));
  float* A1 = (float*)(ws + (33ull << 20));
  float* A2 = (float*)(ws + (37ull << 20));
  float* feat = (float*)(ws + (32ull << 20));
  char* statp = ws + (48ull << 20);
  float* mbuf = (float*)(ws + (49ull << 20));
  float* lbuf = (float*)(ws + (50ull << 20));
  float* pd = (float*)(ws + (56ull << 20));
  int* pi = (int*)(ws + (64ull << 20));
  float* Opart = (float*)(ws + (56ull << 20));
  double* st0 = (double*)(statp);
  double* st1 = (double*)(statp + 2048);
  double* st2 = (double*)(statp + 4096);
  float* sc0 = (float*)(statp + 8192);
  float* sh0 = (float*)(statp + 8704);
  float* sc1 = (float*)(statp + 9216);
  float* sh1 = (float*)(statp + 9728);
  float* sc2 = (float*)(statp + 10240);
  float* sh2 = (float*)(statp + 11264);

  float* out0 = (float*)d_out;
  float* out1 = out0 + 24576;

  hipMemsetAsync(statp, 0, 8192, stream);

  knn_part_kernel<<<dim3(32, 16), 256, 0, stream>>>(pos1, pos2, pd, pi);
  knn_merge_kernel<<<32, 256, 0, stream>>>(pd, pi, idx);
  g131_kernel<<<512, 128, 0, stream>>>(pos2, f2, w0, A2, 1.f, 3);
  g131_kernel<<<512, 128, 0, stream>>>(pos1, f1, w0, A1, -1.f, 131);
  z0stats_kernel<<<256, 256, 0, stream>>>(idx, A1, A2, st0);
  bnfin_kernel<<<1, 256, 0, stream>>>(st0, g0, b0, sc0, sh0, 128, 1.0 / 131072.0);
  gemm1_mfma_kernel<<<dim3(2, 2048), 256, 0, stream>>>(
      A2, A1, idx, w1, sc0, sh0, z1b);
  statsb_kernel<<<512, 256, 0, stream>>>(z1b, 131072L, st1);
  bnfin_kernel<<<1, 256, 0, stream>>>(st1, g1, b1, sc1, sh1, 128, 1.0 / 131072.0);
  gemm2_mfma_kernel<4><<<dim3(4, 2048), 256, 0, stream>>>(
      z1b, w2, sc1, sh1, nullptr, nullptr, nullptr, st2);
  bnfin_kernel<<<1, 256, 0, stream>>>(st2, g2, b2, sc2, sh2, 256, 1.0 / 131072.0);
  gemm2_mfma_kernel<5><<<dim3(4, 2048), 256, 0, stream>>>(
      z1b, w2, sc1, sh1, sc2, sh2, feat, nullptr);
  gemmA_mfma_kernel<7, 0><<<dim3(4, 128), 256, 0, stream>>>(
      feat, qw, 512, 256, qb, nullptr, nullptr, Qbf);
  gemmA_mfma_kernel<7, 1><<<dim3(4, 128), 256, 0, stream>>>(
      f2, kw, 128, 256, kb, nullptr, nullptr, Kbf);
  gemmA_mfma_kernel<8, 1><<<dim3(4, 128), 256, 0, stream>>>(
      f2, vw, 128, 256, vb, nullptr, nullptr, Vtg);
  flash_mfma_kernel<<<dim3(512, 2), 256, 0, stream>>>(Qbf, Kbf, Vtg, Opart, mbuf, lbuf);
  flash_merge_kernel<<<8192, 256, 0, stream>>>(Opart, mbuf, lbuf, attno);
  gemmA_mfma_kernel<2, 0><<<dim3(8, 128), 256, 0, stream>>>(
      attno, ow, 256, 512, obv, feat, y0, nullptr);
  ln_kernel<<<8192, 256, 0, stream>>>(y0, lng, lnb);
  gemmA_mfma_kernel<3, 0><<<dim3(4, 128), 256, 0, stream>>>(
      y0, fw, 512, 256, fb, nullptr, out1, nullptr);
  poscopy_kernel<<<96, 256, 0, stream>>>(pos1, out0);
}